// Round 1
// 2398.232 us; speedup vs baseline: 1.2341x; 1.2341x over previous
//
#include <hip/hip_runtime.h>
#include <hip/hip_bf16.h>

#define NN 100000
#define NE 800000
#define DH 256
#define DOUT 64
#define NSPL 50000                      // GCN agg row split
#define NSO ((size_t)NSPL * DH)        // elems per half
#define NBLK 391                       // ceil(NN/256)

using bf16 = __hip_bfloat16;
typedef __attribute__((ext_vector_type(8))) short bf16x8;
typedef __attribute__((ext_vector_type(4))) float f32x4;

// ---------------- dtype helpers ----------------
__device__ __forceinline__ float bits2f(unsigned short h) {
    union { unsigned int u; float f; } c; c.u = ((unsigned int)h) << 16; return c.f;
}
__device__ __forceinline__ unsigned short f2b(float v) {
    union { float f; unsigned int u; } c; c.f = v;
    unsigned int u = c.u;
    return (unsigned short)((u + 0x7FFFu + ((u >> 16) & 1u)) >> 16);  // RNE
}
__device__ __forceinline__ unsigned short tob(float v) { return f2b(v); }
__device__ __forceinline__ unsigned short tob(bf16 v) {
    union { bf16 b; unsigned short u; } c; c.b = v; return c.u;
}
__device__ __forceinline__ float ldf(const void* p, size_t i, int isbf) {
    if (isbf) return bits2f(((const unsigned short*)p)[i]);
    return ((const float*)p)[i];
}
__device__ __forceinline__ float ldS(const float* p, size_t i) { return p[i]; }
__device__ __forceinline__ float ldS(const bf16* p, size_t i) { return __bfloat162float(p[i]); }
__device__ __forceinline__ void stS(float* p, size_t i, float v) { p[i] = v; }
__device__ __forceinline__ void stS(bf16* p, size_t i, float v) { p[i] = __float2bfloat16(v); }
__device__ __forceinline__ float4 ld4S(const float* p) { return *(const float4*)p; }
__device__ __forceinline__ float4 ld4S(const bf16* p) {
    ushort4 u = *(const ushort4*)(const void*)p;
    return make_float4(bits2f(u.x), bits2f(u.y), bits2f(u.z), bits2f(u.w));
}
// load 8 consecutive elems (16B-aligned) as bf16 bit patterns from f32 or bf16 source
__device__ __forceinline__ void ld8(const void* p, size_t idx, int isbf, ushort4& o0, ushort4& o1) {
    if (isbf) {
        const ushort4* q = (const ushort4*)((const unsigned short*)p + idx);
        o0 = q[0]; o1 = q[1];
    } else {
        const float4* q = (const float4*)((const float*)p + idx);
        float4 a = q[0], b = q[1];
        o0 = make_ushort4(f2b(a.x), f2b(a.y), f2b(a.z), f2b(a.w));
        o1 = make_ushort4(f2b(b.x), f2b(b.y), f2b(b.z), f2b(b.w));
    }
}
__device__ __forceinline__ void ld8S(const bf16* p, size_t idx, ushort4& o0, ushort4& o1) {
    const ushort4* q = (const ushort4*)((const unsigned short*)p + idx);
    o0 = q[0]; o1 = q[1];
}
__device__ __forceinline__ void ld8S(const float* p, size_t idx, ushort4& o0, ushort4& o1) {
    const float4* q = (const float4*)(p + idx);
    float4 a = q[0], b = q[1];
    o0 = make_ushort4(f2b(a.x), f2b(a.y), f2b(a.z), f2b(a.w));
    o1 = make_ushort4(f2b(b.x), f2b(b.y), f2b(b.z), f2b(b.w));
}
__device__ __forceinline__ int ld_src(const int* ei, int e, int i64) {
    return i64 ? ei[2 * (size_t)e] : ei[e];
}
__device__ __forceinline__ int ld_dst(const int* ei, int e, int i64) {
    return i64 ? ei[2 * ((size_t)NE + e)] : ei[NE + e];
}

// ---------------- dtype detector (sampled) ----------------
__global__ __launch_bounds__(256) void detect_kernel(const void* x, const int* ei, int* flags)
{
    __shared__ int s_sane[4], s_nz[4];
    int t = threadIdx.x;
    const unsigned short* xu = (const unsigned short*)x;
    int sane = 0;
    for (int i = t; i < 2048; i += 256) {
        float v = bits2f(xu[2 * i]);
        float a = fabsf(v);
        if (v == v && a > 1e-3f && a < 100.f) sane++;
    }
    int nz = 0;
    for (int i = t; i < 4096; i += 256) {
        if (ei[2 * (i * 122) + 1] != 0) nz++;
    }
#pragma unroll
    for (int off = 32; off > 0; off >>= 1) { sane += __shfl_down(sane, off); nz += __shfl_down(nz, off); }
    if ((t & 63) == 0) { s_sane[t >> 6] = sane; s_nz[t >> 6] = nz; }
    __syncthreads();
    if (t == 0) {
        flags[0] = ((s_sane[0] + s_sane[1] + s_sane[2] + s_sane[3]) > 1024) ? 1 : 0;
        flags[1] = ((s_nz[0] + s_nz[1] + s_nz[2] + s_nz[3]) == 0) ? 1 : 0;
    }
}

// ---------------- MFMA GEMM: C[M,Nc] = A[M,256] @ W[256,Nc] (+bias) ----------------
template <typename ST>
__global__ __launch_bounds__(256) void gemm_mfma(
    const void* __restrict__ A, const void* __restrict__ W,
    const void* __restrict__ bias, ST* __restrict__ C,
    int M, int Nc, const int* __restrict__ flags, int a_sel)
{
    __shared__ unsigned short Bs[64][264];   // W^T tile: Bs[n][k], all K
    __shared__ unsigned short As[64][40];    // A tile: As[m][k-k0]
    const int isbf = flags[0];
    const int abf = (a_sel == 2) ? isbf : a_sel;
    const int tid = threadIdx.x;
    const int wave = tid >> 6, lane = tid & 63;
    const int quad = lane >> 4, nl = lane & 15;
    const int m0 = blockIdx.x * 64;
    const int n0 = blockIdx.y * 64;

#pragma unroll
    for (int it = 0; it < 8; ++it) {
        int p8 = it * 256 + tid;
        int k = p8 >> 3, nb = p8 & 7;
        ushort4 w0, w1;
        ld8(W, (size_t)k * Nc + n0 + nb * 8, isbf, w0, w1);
        int nbase = nb * 8;
        Bs[nbase + 0][k] = w0.x; Bs[nbase + 1][k] = w0.y;
        Bs[nbase + 2][k] = w0.z; Bs[nbase + 3][k] = w0.w;
        Bs[nbase + 4][k] = w1.x; Bs[nbase + 5][k] = w1.y;
        Bs[nbase + 6][k] = w1.z; Bs[nbase + 7][k] = w1.w;
    }

    const int am = tid >> 2, akb = (tid & 3) * 8;
    f32x4 acc[4] = {{0.f,0.f,0.f,0.f},{0.f,0.f,0.f,0.f},{0.f,0.f,0.f,0.f},{0.f,0.f,0.f,0.f}};

    for (int k0 = 0; k0 < DH; k0 += 32) {
        __syncthreads();
        ushort4 a0, a1;
        if (m0 + am < M) ld8(A, (size_t)(m0 + am) * DH + k0 + akb, abf, a0, a1);
        else { a0 = make_ushort4(0,0,0,0); a1 = a0; }
        *(ushort4*)&As[am][akb]     = a0;
        *(ushort4*)&As[am][akb + 4] = a1;
        __syncthreads();
        bf16x8 af = *(const bf16x8*)&As[wave * 16 + nl][quad * 8];
#pragma unroll
        for (int ct = 0; ct < 4; ++ct) {
            bf16x8 bfg = *(const bf16x8*)&Bs[ct * 16 + nl][k0 + quad * 8];
            acc[ct] = __builtin_amdgcn_mfma_f32_16x16x32_bf16(af, bfg, acc[ct], 0, 0, 0);
        }
    }

#pragma unroll
    for (int ct = 0; ct < 4; ++ct) {
        int n = n0 + ct * 16 + nl;
        float bv = bias ? ldf(bias, n, isbf) : 0.f;
#pragma unroll
        for (int r = 0; r < 4; ++r) {
            int m = m0 + wave * 16 + quad * 4 + r;
            if (m < M) stS(C, (size_t)m * Nc + n, acc[ct][r] + bv);
        }
    }
}

// ---------------- MFMA kvs: D[256,256] = A^T @ B over N (split-N, atomic f32) ----------------
// call with (Vm, Km, kvs): D[j][i] = sum_n V[n][j]*K[n][i]  == kvs transposed, row-major
// Staging: each thread loads ONE contiguous 8-elem vector per matrix per 32-row chunk
// (vs 16 scalar loads before), loads issued before the barrier so they overlap the
// previous chunk's MFMA phase. Split-N widened for occupancy (launch z=64 -> 4 blk/CU).
template <typename ST>
__global__ __launch_bounds__(256) void kvs_mfma(
    const ST* __restrict__ Am, const ST* __restrict__ Bm, float* __restrict__ D)
{
    __shared__ unsigned short Ast[64][36];
    __shared__ unsigned short Bst[64][36];
    const int tid = threadIdx.x;
    const int wave = tid >> 6, lane = tid & 63;
    const int quad = lane >> 4, nl = lane & 15;
    const int i0 = blockIdx.x * 64, j0 = blockIdx.y * 64;   // i0: D rows (A cols), j0: D cols (B cols)
    const int S = gridDim.z;
    const int chunk = (NN + S - 1) / S;
    const int ns = blockIdx.z * chunk;
    const int ne = min(ns + chunk, NN);
    const int nn = tid >> 3;          // row within 32-row chunk (0..31)
    const int c0 = (tid & 7) * 8;     // col offset within 64-col tile (0,8,...,56)
    f32x4 acc[4] = {{0.f,0.f,0.f,0.f},{0.f,0.f,0.f,0.f},{0.f,0.f,0.f,0.f},{0.f,0.f,0.f,0.f}};

    for (int n0 = ns; n0 < ne; n0 += 32) {
        int n = n0 + nn;
        ushort4 a0, a1, b0, b1;
        if (n < ne) {
            ld8S(Am, (size_t)n * DH + i0 + c0, a0, a1);
            ld8S(Bm, (size_t)n * DH + j0 + c0, b0, b1);
        } else {
            a0 = make_ushort4(0, 0, 0, 0); a1 = a0; b0 = a0; b1 = a0;
        }
        __syncthreads();   // previous chunk's frag reads done; loads above stay in flight
        Ast[c0 + 0][nn] = a0.x; Ast[c0 + 1][nn] = a0.y;
        Ast[c0 + 2][nn] = a0.z; Ast[c0 + 3][nn] = a0.w;
        Ast[c0 + 4][nn] = a1.x; Ast[c0 + 5][nn] = a1.y;
        Ast[c0 + 6][nn] = a1.z; Ast[c0 + 7][nn] = a1.w;
        Bst[c0 + 0][nn] = b0.x; Bst[c0 + 1][nn] = b0.y;
        Bst[c0 + 2][nn] = b0.z; Bst[c0 + 3][nn] = b0.w;
        Bst[c0 + 4][nn] = b1.x; Bst[c0 + 5][nn] = b1.y;
        Bst[c0 + 6][nn] = b1.z; Bst[c0 + 7][nn] = b1.w;
        __syncthreads();
        bf16x8 af = *(const bf16x8*)&Ast[wave * 16 + nl][quad * 8];
#pragma unroll
        for (int ct = 0; ct < 4; ++ct) {
            bf16x8 bfg = *(const bf16x8*)&Bst[ct * 16 + nl][quad * 8];
            acc[ct] = __builtin_amdgcn_mfma_f32_16x16x32_bf16(af, bfg, acc[ct], 0, 0, 0);
        }
    }
#pragma unroll
    for (int ct = 0; ct < 4; ++ct)
#pragma unroll
        for (int r = 0; r < 4; ++r)
            atomicAdd(&D[(size_t)(i0 + wave * 16 + quad * 4 + r) * DH + j0 + ct * 16 + nl], acc[ct][r]);
}

// ---------------- MFMA attention: out = (Q@kvs*scale + N*V) / (Q.ks_sum*scale + N) ----------------
// kvsT is kvs transposed row-major: kvsT[col*DH + k] = kvs[k][col]
template <typename ST>
__global__ __launch_bounds__(256) void attn_mfma(
    const ST* __restrict__ Q, const ST* __restrict__ V,
    const float* __restrict__ kvsT, const float* __restrict__ ks_sum,
    const float* __restrict__ qss, const float* __restrict__ kss,
    ST* __restrict__ out)
{
    __shared__ unsigned short kv_s[256][36];
    __shared__ unsigned short As[64][36];
    __shared__ float ks_s[DH];
    __shared__ float nrm_s[64];
    const int tid = threadIdx.x;
    const int wave = tid >> 6, lane = tid & 63;
    const int quad = lane >> 4, nl = lane & 15;
    const int m0 = blockIdx.x * 64;

    ks_s[tid] = ks_sum[tid];

    const int am = tid >> 2, akb = (tid & 3) * 8;
    f32x4 acc[16];
#pragma unroll
    for (int i = 0; i < 16; ++i) acc[i] = (f32x4){0.f, 0.f, 0.f, 0.f};
    float nrm = 0.f;

    for (int k0 = 0; k0 < DH; k0 += 32) {
        __syncthreads();
        // stage kvsT chunk: kv_s[col][kk] = kvsT[col*DH + k0+kk] (straight copy + bf16 convert)
        for (int p = tid; p < 2048; p += 256) {
            int col = p >> 3, f4 = p & 7;
            float4 w = *(const float4*)&kvsT[(size_t)col * DH + k0 + f4 * 4];
            *(ushort4*)&kv_s[col][f4 * 4] = make_ushort4(f2b(w.x), f2b(w.y), f2b(w.z), f2b(w.w));
        }
        ushort4 a0, a1;
        int gm = m0 + am;
        if (gm < NN) ld8S(Q, (size_t)gm * DH + k0 + akb, a0, a1);
        else { a0 = make_ushort4(0,0,0,0); a1 = a0; }
        *(ushort4*)&As[am][akb]     = a0;
        *(ushort4*)&As[am][akb + 4] = a1;
        __syncthreads();
        bf16x8 af = *(const bf16x8*)&As[wave * 16 + nl][quad * 8];
#pragma unroll
        for (int j = 0; j < 8; ++j)
            nrm += bits2f(((const unsigned short*)&af)[j]) * ks_s[k0 + quad * 8 + j];
#pragma unroll
        for (int ct = 0; ct < 16; ++ct) {
            bf16x8 bfg = *(const bf16x8*)&kv_s[ct * 16 + nl][quad * 8];
            acc[ct] = __builtin_amdgcn_mfma_f32_16x16x32_bf16(af, bfg, acc[ct], 0, 0, 0);
        }
    }
    nrm += __shfl_xor(nrm, 16);
    nrm += __shfl_xor(nrm, 32);
    if (lane < 16) nrm_s[wave * 16 + lane] = nrm;
    __syncthreads();
    const float scale = rsqrtf(*qss) * rsqrtf(*kss);
#pragma unroll
    for (int r = 0; r < 4; ++r) {
        int row = m0 + wave * 16 + quad * 4 + r;
        if (row >= NN) continue;
        float den = nrm_s[wave * 16 + quad * 4 + r] * scale + (float)NN;
#pragma unroll
        for (int ct = 0; ct < 16; ++ct) {
            int col = ct * 16 + nl;
            float v = ldS(V, (size_t)row * DH + col);
            float numv = acc[ct][r] * scale + (float)NN * v;
            stS(out, (size_t)row * DH + col, numv / den);
        }
    }
}

// ---------------- LayerNorm over D=256 (optional residual mix, relu) ----------------
template <typename ST>
__global__ __launch_bounds__(256) void ln_kernel(
    const ST* __restrict__ A, const ST* __restrict__ B,
    float alpha, float beta,
    const void* __restrict__ g, const void* __restrict__ b,
    ST* __restrict__ out, int relu, const int* __restrict__ flags)
{
    __shared__ float ps[4], ps2[4];
    const int isbf = flags[0];
    const int row = blockIdx.x;
    const int t = threadIdx.x;
    size_t idx = (size_t)row * DH + t;
    float v = alpha * ldS(A, idx);
    if (B) v += beta * ldS(B, idx);
    float s = v, s2 = v * v;
#pragma unroll
    for (int off = 32; off > 0; off >>= 1) {
        s += __shfl_down(s, off);
        s2 += __shfl_down(s2, off);
    }
    if ((t & 63) == 0) { ps[t >> 6] = s; ps2[t >> 6] = s2; }
    __syncthreads();
    float S = ps[0] + ps[1] + ps[2] + ps[3];
    float S2 = ps2[0] + ps2[1] + ps2[2] + ps2[3];
    float mean = S * (1.f / DH);
    float var = S2 * (1.f / DH) - mean * mean;
    float rstd = rsqrtf(var + 1e-5f);
    float o = (v - mean) * rstd * ldf(g, t, isbf) + ldf(b, t, isbf);
    if (relu) o = fmaxf(o, 0.f);
    stS(out, idx, o);
}

// ---------------- sum of squares ----------------
template <typename ST>
__global__ __launch_bounds__(256) void sumsq_kernel(
    const ST* __restrict__ A, size_t n, float* __restrict__ out)
{
    __shared__ float ps[4];
    size_t i = (size_t)blockIdx.x * blockDim.x + threadIdx.x;
    size_t stride = (size_t)gridDim.x * blockDim.x;
    float s = 0.f;
    for (; i < n; i += stride) { float v = ldS(A, i); s += v * v; }
#pragma unroll
    for (int off = 32; off > 0; off >>= 1) s += __shfl_down(s, off);
    if ((threadIdx.x & 63) == 0) ps[threadIdx.x >> 6] = s;
    __syncthreads();
    if (threadIdx.x == 0) atomicAdd(out, ps[0] + ps[1] + ps[2] + ps[3]);
}

// ---------------- ks_sum[j] = sum_n K[n][j] (rows-per-block from gridDim) ----------------
template <typename ST>
__global__ __launch_bounds__(256) void colsum_kernel(
    const ST* __restrict__ Km, float* __restrict__ out)
{
    const int t = threadIdx.x;
    const int per = (NN + gridDim.x - 1) / gridDim.x;
    size_t r0 = (size_t)blockIdx.x * per;
    size_t r1 = r0 + per; if (r1 > NN) r1 = NN;
    float s = 0.f;
    for (size_t r = r0; r < r1; ++r) s += ldS(Km, r * DH + t);
    atomicAdd(&out[t], s);
}

// ---------------- CSR build ----------------
__global__ __launch_bounds__(256) void count_kernel(const int* __restrict__ ei, int* __restrict__ cnt,
                                                    const int* __restrict__ flags)
{
    int e = blockIdx.x * 256 + threadIdx.x;
    if (e >= NE) return;
    int d = ld_dst(ei, e, flags[1]);
    if ((unsigned)d < NN) atomicAdd(&cnt[d], 1);
}

__global__ __launch_bounds__(256) void scan_block_kernel(const int* __restrict__ cnt,
                                                         int* __restrict__ pre, int* __restrict__ bsum)
{
    __shared__ int s[256];
    int i = blockIdx.x * 256 + threadIdx.x;
    int v = (i < NN) ? cnt[i] : 0;
    s[threadIdx.x] = v;
    __syncthreads();
    for (int off = 1; off < 256; off <<= 1) {
        int t = (threadIdx.x >= off) ? s[threadIdx.x - off] : 0;
        __syncthreads();
        s[threadIdx.x] += t;
        __syncthreads();
    }
    if (i < NN) pre[i] = s[threadIdx.x] - v;
    if (threadIdx.x == 255) bsum[blockIdx.x] = s[255];
}

__global__ __launch_bounds__(512) void scan_partial_kernel(int* __restrict__ bsum, int nb)
{
    __shared__ int s[512];
    int t = threadIdx.x;
    int v = (t < nb) ? bsum[t] : 0;
    s[t] = v;
    __syncthreads();
    for (int off = 1; off < 512; off <<= 1) {
        int u = (t >= off) ? s[t - off] : 0;
        __syncthreads();
        s[t] += u;
        __syncthreads();
    }
    if (t < nb) bsum[t] = s[t] - v;
}

__global__ __launch_bounds__(256) void finalize_kernel(int* __restrict__ base, const int* __restrict__ bsum,
                                                       const int* __restrict__ cnt, int* __restrict__ cursor,
                                                       float* __restrict__ dinv)
{
    int i = blockIdx.x * 256 + threadIdx.x;
    if (i >= NN) return;
    int b = base[i] + bsum[blockIdx.x];
    base[i] = b;
    cursor[i] = b;
    dinv[i] = rsqrtf((float)cnt[i] + 1.0f);
}

__global__ __launch_bounds__(256) void scatter_kernel(const int* __restrict__ ei, int* __restrict__ cursor,
                                                      int* __restrict__ srcs, const int* __restrict__ flags)
{
    int e = blockIdx.x * 256 + threadIdx.x;
    if (e >= NE) return;
    int i64 = flags[1];
    int s = ld_src(ei, e, i64), d = ld_dst(ei, e, i64);
    if ((unsigned)s >= NN || (unsigned)d >= NN) return;
    int pos = atomicAdd(&cursor[d], 1);
    srcs[pos] = s;
}

// ---------------- CSR gather aggregate: one wave per node ----------------
template <typename ST>
__global__ __launch_bounds__(256) void gather_kernel(
    const ST* __restrict__ Hs, const int* __restrict__ base, const int* __restrict__ cnt,
    const int* __restrict__ srcs, const float* __restrict__ dinv,
    float* __restrict__ lo, float* __restrict__ hi)
{
    int node = blockIdx.x * 4 + (threadIdx.x >> 6);
    int lane = threadIdx.x & 63;
    if (node >= NN) return;
    int b0 = base[node], deg = cnt[node];
    float dd = dinv[node];
    float4 acc = make_float4(0.f, 0.f, 0.f, 0.f);
    for (int j = 0; j < deg; ++j) {
        int s = srcs[b0 + j];
        float nrm = dd * dinv[s];
        float4 h4 = ld4S(&Hs[(size_t)s * DH + lane * 4]);
        acc.x += h4.x * nrm; acc.y += h4.y * nrm;
        acc.z += h4.z * nrm; acc.w += h4.w * nrm;
    }
    float* o = (node < NSPL ? &lo[(size_t)node * DH] : &hi[(size_t)(node - NSPL) * DH]) + lane * 4;
    *(float4*)o = acc;
}

// ---------------- fallback (atomic) GCN pieces ----------------
__global__ __launch_bounds__(256) void deg_kernel(const int* __restrict__ ei, float* __restrict__ deg,
                                                  const int* __restrict__ flags)
{
    int i64 = flags[1];
    int e = blockIdx.x * 256 + threadIdx.x;
    if (e >= NE) return;
    int d = ld_dst(ei, e, i64);
    if ((unsigned)d < NN) atomicAdd(&deg[d], 1.0f);
}

__global__ __launch_bounds__(256) void dinv_kernel(float* __restrict__ deg)
{
    int i = blockIdx.x * 256 + threadIdx.x;
    if (i < NN) deg[i] = rsqrtf(deg[i] + 1.0f);
}

template <typename ST>
__global__ __launch_bounds__(256) void agg_kernel(
    const ST* __restrict__ Hs, const int* __restrict__ ei,
    const float* __restrict__ dinv, float* __restrict__ lo, float* __restrict__ hi,
    const int* __restrict__ flags)
{
    int i64 = flags[1];
    int e = blockIdx.x * 4 + (threadIdx.x >> 6);
    int lane = threadIdx.x & 63;
    if (e >= NE) return;
    int s = ld_src(ei, e, i64), d = ld_dst(ei, e, i64);
    if ((unsigned)s >= NN || (unsigned)d >= NN) return;
    float nrm = dinv[s] * dinv[d];
    const float4 h4 = ld4S(&Hs[(size_t)s * DH + lane * 4]);
    float* o = (d < NSPL ? &lo[(size_t)d * DH] : &hi[(size_t)(d - NSPL) * DH]) + lane * 4;
    atomicAdd(o + 0, h4.x * nrm);
    atomicAdd(o + 1, h4.y * nrm);
    atomicAdd(o + 2, h4.z * nrm);
    atomicAdd(o + 3, h4.w * nrm);
}

// self-loop + bias + BN(eval) + relu
template <typename ST>
__global__ __launch_bounds__(256) void gcn_epi1_kernel(
    const float* __restrict__ lo, const float* __restrict__ hi,
    const ST* __restrict__ h1, const float* __restrict__ dinv,
    const void* __restrict__ b0, const void* __restrict__ bng, const void* __restrict__ bnb,
    const int* __restrict__ flags, ST* __restrict__ out)
{
    const int isbf = flags[0];
    size_t idx = (size_t)blockIdx.x * 256 + threadIdx.x;
    if (idx >= (size_t)NN * DH) return;
    int i = (int)(idx >> 8), c = (int)(idx & 255);
    float aggv = (i < NSPL) ? lo[idx] : hi[idx - NSO];
    float di = dinv[i];
    float v = aggv + ldS(h1, idx) * di * di + ldf(b0, c, isbf);
    const float bnscale = 0.99999500003749981f;  // 1/sqrt(1+1e-5)
    v = v * (ldf(bng, c, isbf) * bnscale) + ldf(bnb, c, isbf);
    stS(out, idx, fmaxf(v, 0.f));
}

// self-loop + bias + combine: emb = 0.8*(agg + self + b1) + 0.2*x_trans
template <typename ST>
__global__ __launch_bounds__(256) void gcn_epi2_kernel(
    const float* __restrict__ lo, const float* __restrict__ hi,
    const ST* __restrict__ h2, const ST* __restrict__ Ht, const float* __restrict__ dinv,
    const void* __restrict__ b1, const int* __restrict__ flags, ST* __restrict__ out)
{
    const int isbf = flags[0];
    size_t idx = (size_t)blockIdx.x * 256 + threadIdx.x;
    if (idx >= (size_t)NN * DH) return;
    int i = (int)(idx >> 8), c = (int)(idx & 255);
    float aggv = (i < NSPL) ? lo[idx] : hi[idx - NSO];
    float di = dinv[i];
    float g = aggv + ldS(h2, idx) * di * di + ldf(b1, c, isbf);
    stS(out, idx, 0.8f * g + 0.2f * ldS(Ht, idx));
}

// ---------------- diagnostic ----------------
__global__ __launch_bounds__(256) void diag_kernel(float* out, size_t n, float val)
{
    size_t i = (size_t)blockIdx.x * 256 + threadIdx.x;
    if (i < n) out[i] = val;
}

// ---------------- pipeline ----------------
template <typename ST>
static void run_pipeline(void* const* d_in, void* d_out, char* wsb, hipStream_t stream, int use_csr)
{
    const void* x      = d_in[0];
    const int*  ei     = (const int*)d_in[1];
    const void* fc0_w  = d_in[2];  const void* fc0_b  = d_in[3];
    const void* ln0_g  = d_in[4];  const void* ln0_b  = d_in[5];
    const void* wq0_w  = d_in[6];  const void* wq0_b  = d_in[7];
    const void* wk0_w  = d_in[8];  const void* wk0_b  = d_in[9];
    const void* wv0_w  = d_in[10]; const void* wv0_b  = d_in[11];
    const void* ln1_g  = d_in[12]; const void* ln1_b  = d_in[13];
    const void* wq1_w  = d_in[14]; const void* wq1_b  = d_in[15];
    const void* wk1_w  = d_in[16]; const void* wk1_b  = d_in[17];
    const void* wv1_w  = d_in[18]; const void* wv1_b  = d_in[19];
    const void* ln2_g  = d_in[20]; const void* ln2_b  = d_in[21];
    const void* gcn_w0 = d_in[22]; const void* gcn_b0 = d_in[23];
    const void* bn_g   = d_in[24]; const void* bn_b   = d_in[25];
    const void* gcn_w1 = d_in[26]; const void* gcn_b1 = d_in[27];
    const void* fc_w   = d_in[28]; const void* fc_b   = d_in[29];

    const size_t stN = (size_t)NN * DH * sizeof(ST);
    ST* H  = (ST*)(wsb);
    ST* Qb = (ST*)(wsb + stN);
    ST* Kb = (ST*)(wsb + 2 * stN);
    ST* Vb = (ST*)(wsb + 3 * stN);
    float* aux = (float*)(wsb + 4 * stN);
    float* kvs    = aux;
    float* ks_sum = aux + 65536;
    float* qss    = aux + 65792;
    float* kss    = aux + 65793;
    float* dinv   = aux + 65808;
    int*   flags  = (int*)(aux + 65808 + NN);
    int* cnt    = (int*)(aux + 65808 + NN + 16);
    int* base   = cnt + NN;
    int* cursor = base + NN;
    int* bsum   = cursor + NN;       // 512
    int* srcs   = bsum + 512;        // NE

    const int asel = (sizeof(ST) == 2) ? 1 : 0;
    dim3 mfmaGrid((NN + 63) / 64, DH / 64);
    const size_t NELEM = (size_t)NN * DH;

    detect_kernel<<<1, 256, 0, stream>>>(x, ei, flags);

    // ---- TransConv input layer ----
    gemm_mfma<ST><<<mfmaGrid, 256, 0, stream>>>(x, fc0_w, fc0_b, Qb, NN, DH, flags, 2);
    ln_kernel<ST><<<NN, 256, 0, stream>>>(Qb, (const ST*)nullptr, 1.f, 0.f, ln0_g, ln0_b, H, 1, flags);

    // ---- two attention layers ----
    for (int layer = 0; layer < 2; ++layer) {
        const void *qw, *qb, *kw, *kb, *vw, *vb, *lg, *lb;
        if (layer == 0) { qw = wq0_w; qb = wq0_b; kw = wk0_w; kb = wk0_b; vw = wv0_w; vb = wv0_b; lg = ln1_g; lb = ln1_b; }
        else            { qw = wq1_w; qb = wq1_b; kw = wk1_w; kb = wk1_b; vw = wv1_w; vb = wv1_b; lg = ln2_g; lb = ln2_b; }
        gemm_mfma<ST><<<mfmaGrid, 256, 0, stream>>>(H, qw, qb, Qb, NN, DH, flags, asel);
        gemm_mfma<ST><<<mfmaGrid, 256, 0, stream>>>(H, kw, kb, Kb, NN, DH, flags, asel);
        gemm_mfma<ST><<<mfmaGrid, 256, 0, stream>>>(H, vw, vb, Vb, NN, DH, flags, asel);
        hipMemsetAsync(aux, 0, (65536 + 256 + 2) * sizeof(float), stream);
        sumsq_kernel<ST><<<2048, 256, 0, stream>>>(Qb, NELEM, qss);
        sumsq_kernel<ST><<<2048, 256, 0, stream>>>(Kb, NELEM, kss);
        // kvs stored TRANSPOSED: kvs[j][i] = sum_n V[n][j] K[n][i]
        kvs_mfma<ST><<<dim3(4, 4, 64), 256, 0, stream>>>(Vb, Kb, kvs);
        colsum_kernel<ST><<<800, 256, 0, stream>>>(Kb, ks_sum);
        attn_mfma<ST><<<(NN + 63) / 64, 256, 0, stream>>>(Qb, Vb, kvs, ks_sum, qss, kss, Kb);
        ln_kernel<ST><<<NN, 256, 0, stream>>>(Kb, H, 0.5f, 0.5f, lg, lb, H, 0, flags);
    }

    // ---- GCN branch ----
    float* a1lo = (float*)(wsb + 2 * stN);
    float* a1hi = a1lo + NSO;
    ST* h2; float *a2lo, *a2hi;
    if (sizeof(ST) == 4) { h2 = Vb; a2lo = (float*)(wsb + 2 * stN); a2hi = a2lo + NSO; }
    else                 { h2 = Kb; a2lo = (float*)(wsb + stN);     a2hi = (float*)(wsb + 3 * stN); }

    if (use_csr) {
        hipMemsetAsync(cnt, 0, NN * sizeof(int), stream);
        count_kernel<<<(NE + 255) / 256, 256, 0, stream>>>(ei, cnt, flags);
        scan_block_kernel<<<NBLK, 256, 0, stream>>>(cnt, base, bsum);
        scan_partial_kernel<<<1, 512, 0, stream>>>(bsum, NBLK);
        finalize_kernel<<<NBLK, 256, 0, stream>>>(base, bsum, cnt, cursor, dinv);
        scatter_kernel<<<(NE + 255) / 256, 256, 0, stream>>>(ei, cursor, srcs, flags);

        gemm_mfma<ST><<<mfmaGrid, 256, 0, stream>>>(x, gcn_w0, nullptr, Qb, NN, DH, flags, 2);
        gather_kernel<ST><<<(NN + 3) / 4, 256, 0, stream>>>(Qb, base, cnt, srcs, dinv, a1lo, a1hi);
        gcn_epi1_kernel<ST><<<(NELEM + 255) / 256, 256, 0, stream>>>(a1lo, a1hi, Qb, dinv, gcn_b0, bn_g, bn_b, flags, Qb);

        gemm_mfma<ST><<<mfmaGrid, 256, 0, stream>>>(Qb, gcn_w1, nullptr, h2, NN, DH, flags, asel);
        gather_kernel<ST><<<(NN + 3) / 4, 256, 0, stream>>>(h2, base, cnt, srcs, dinv, a2lo, a2hi);
        gcn_epi2_kernel<ST><<<(NELEM + 255) / 256, 256, 0, stream>>>(a2lo, a2hi, h2, H, dinv, gcn_b1, flags, h2);
    } else {
        hipMemsetAsync(dinv, 0, NN * sizeof(float), stream);
        deg_kernel<<<(NE + 255) / 256, 256, 0, stream>>>(ei, dinv, flags);
        dinv_kernel<<<(NN + 255) / 256, 256, 0, stream>>>(dinv);

        gemm_mfma<ST><<<mfmaGrid, 256, 0, stream>>>(x, gcn_w0, nullptr, Qb, NN, DH, flags, 2);
        hipMemsetAsync(a1lo, 0, NELEM * sizeof(float), stream);
        agg_kernel<ST><<<(NE + 3) / 4, 256, 0, stream>>>(Qb, ei, dinv, a1lo, a1hi, flags);
        gcn_epi1_kernel<ST><<<(NELEM + 255) / 256, 256, 0, stream>>>(a1lo, a1hi, Qb, dinv, gcn_b0, bn_g, bn_b, flags, Qb);

        gemm_mfma<ST><<<mfmaGrid, 256, 0, stream>>>(Qb, gcn_w1, nullptr, h2, NN, DH, flags, asel);
        hipMemsetAsync(a2lo, 0, NSO * sizeof(float), stream);
        hipMemsetAsync(a2hi, 0, NSO * sizeof(float), stream);
        agg_kernel<ST><<<(NE + 3) / 4, 256, 0, stream>>>(h2, ei, dinv, a2lo, a2hi, flags);
        gcn_epi2_kernel<ST><<<(NELEM + 255) / 256, 256, 0, stream>>>(a2lo, a2hi, h2, H, dinv, gcn_b1, flags, h2);
    }

    // ---- classifier (f32 output) ----
    gemm_mfma<float><<<dim3((NN + 63) / 64, 1), 256, 0, stream>>>(h2, fc_w, fc_b, (float*)d_out, NN, DOUT, flags, asel);
}

extern "C" void kernel_launch(void* const* d_in, const int* in_sizes, int n_in,
                              void* d_out, int out_size, void* d_ws, size_t ws_size,
                              hipStream_t stream)
{
    char* wsb = (char*)d_ws;
    const size_t AUXF  = 65808 + NN + 16;
    const size_t CSRI  = 3 * (size_t)NN + 512 + NE;
    const size_t AUXB  = AUXF * sizeof(float);
    const size_t AUXB2 = AUXB + CSRI * sizeof(int);
    const size_t needA  = 4 * ((size_t)NN * DH * 4) + AUXB;
    const size_t needA2 = 4 * ((size_t)NN * DH * 4) + AUXB2;
    const size_t needB  = 4 * ((size_t)NN * DH * 2) + AUXB;
    const size_t needB2 = 4 * ((size_t)NN * DH * 2) + AUXB2;

    if (ws_size >= needA) {
        run_pipeline<float>(d_in, d_out, wsb, stream, ws_size >= needA2);
    } else if (ws_size >= needB) {
        run_pipeline<bf16>(d_in, d_out, wsb, stream, ws_size >= needB2);
    } else {
        float mb = (float)(ws_size >> 20);
        size_t n = (size_t)out_size;
        diag_kernel<<<(n + 255) / 256, 256, 0, stream>>>((float*)d_out, n, mb);
    }
}

// Round 3
// 2372.854 us; speedup vs baseline: 1.2473x; 1.0107x over previous
//
#include <hip/hip_runtime.h>
#include <hip/hip_bf16.h>

#define NN 100000
#define NE 800000
#define DH 256
#define DOUT 64
#define NSPL 50000                      // GCN agg row split
#define NSO ((size_t)NSPL * DH)        // elems per half
#define NBLK 391                       // ceil(NN/256)

using bf16 = __hip_bfloat16;
typedef __attribute__((ext_vector_type(8))) short bf16x8;
typedef __attribute__((ext_vector_type(4))) float f32x4;

// ---------------- dtype helpers ----------------
__device__ __forceinline__ float bits2f(unsigned short h) {
    union { unsigned int u; float f; } c; c.u = ((unsigned int)h) << 16; return c.f;
}
__device__ __forceinline__ unsigned short f2b(float v) {
    union { float f; unsigned int u; } c; c.f = v;
    unsigned int u = c.u;
    return (unsigned short)((u + 0x7FFFu + ((u >> 16) & 1u)) >> 16);  // RNE
}
__device__ __forceinline__ unsigned short tob(float v) { return f2b(v); }
__device__ __forceinline__ unsigned short tob(bf16 v) {
    union { bf16 b; unsigned short u; } c; c.b = v; return c.u;
}
__device__ __forceinline__ float ldf(const void* p, size_t i, int isbf) {
    if (isbf) return bits2f(((const unsigned short*)p)[i]);
    return ((const float*)p)[i];
}
__device__ __forceinline__ float ldS(const float* p, size_t i) { return p[i]; }
__device__ __forceinline__ float ldS(const bf16* p, size_t i) { return __bfloat162float(p[i]); }
__device__ __forceinline__ void stS(float* p, size_t i, float v) { p[i] = v; }
__device__ __forceinline__ void stS(bf16* p, size_t i, float v) { p[i] = __float2bfloat16(v); }
__device__ __forceinline__ float4 ld4S(const float* p) { return *(const float4*)p; }
__device__ __forceinline__ float4 ld4S(const bf16* p) {
    ushort4 u = *(const ushort4*)(const void*)p;
    return make_float4(bits2f(u.x), bits2f(u.y), bits2f(u.z), bits2f(u.w));
}
// load 8 consecutive elems (16B-aligned) as bf16 bit patterns from f32 or bf16 source
__device__ __forceinline__ void ld8(const void* p, size_t idx, int isbf, ushort4& o0, ushort4& o1) {
    if (isbf) {
        const ushort4* q = (const ushort4*)((const unsigned short*)p + idx);
        o0 = q[0]; o1 = q[1];
    } else {
        const float4* q = (const float4*)((const float*)p + idx);
        float4 a = q[0], b = q[1];
        o0 = make_ushort4(f2b(a.x), f2b(a.y), f2b(a.z), f2b(a.w));
        o1 = make_ushort4(f2b(b.x), f2b(b.y), f2b(b.z), f2b(b.w));
    }
}
__device__ __forceinline__ void ld8S(const bf16* p, size_t idx, ushort4& o0, ushort4& o1) {
    const ushort4* q = (const ushort4*)((const unsigned short*)p + idx);
    o0 = q[0]; o1 = q[1];
}
__device__ __forceinline__ void ld8S(const float* p, size_t idx, ushort4& o0, ushort4& o1) {
    const float4* q = (const float4*)(p + idx);
    float4 a = q[0], b = q[1];
    o0 = make_ushort4(f2b(a.x), f2b(a.y), f2b(a.z), f2b(a.w));
    o1 = make_ushort4(f2b(b.x), f2b(b.y), f2b(b.z), f2b(b.w));
}
__device__ __forceinline__ int ld_src(const int* ei, int e, int i64) {
    return i64 ? ei[2 * (size_t)e] : ei[e];
}
__device__ __forceinline__ int ld_dst(const int* ei, int e, int i64) {
    return i64 ? ei[2 * ((size_t)NE + e)] : ei[NE + e];
}

// ---------------- dtype detector (sampled) ----------------
__global__ __launch_bounds__(256) void detect_kernel(const void* x, const int* ei, int* flags)
{
    __shared__ int s_sane[4], s_nz[4];
    int t = threadIdx.x;
    const unsigned short* xu = (const unsigned short*)x;
    int sane = 0;
    for (int i = t; i < 2048; i += 256) {
        float v = bits2f(xu[2 * i]);
        float a = fabsf(v);
        if (v == v && a > 1e-3f && a < 100.f) sane++;
    }
    int nz = 0;
    for (int i = t; i < 4096; i += 256) {
        if (ei[2 * (i * 122) + 1] != 0) nz++;
    }
#pragma unroll
    for (int off = 32; off > 0; off >>= 1) { sane += __shfl_down(sane, off); nz += __shfl_down(nz, off); }
    if ((t & 63) == 0) { s_sane[t >> 6] = sane; s_nz[t >> 6] = nz; }
    __syncthreads();
    if (t == 0) {
        flags[0] = ((s_sane[0] + s_sane[1] + s_sane[2] + s_sane[3]) > 1024) ? 1 : 0;
        flags[1] = ((s_nz[0] + s_nz[1] + s_nz[2] + s_nz[3]) == 0) ? 1 : 0;
    }
}

// ---------------- MFMA GEMM: C[M,Nc] = A[M,256] @ W[256,Nc] (+bias) ----------------
// B (W^T) staged to LDS ONCE; A fragments read direct from global (each lane's
// fragment is 16B contiguous; a wave consumes 16 full 64B lines per K-step, each
// byte of A read exactly once). Zero inner-loop barriers.
template <typename ST>
__global__ __launch_bounds__(256) void gemm_mfma(
    const void* __restrict__ A, const void* __restrict__ W,
    const void* __restrict__ bias, ST* __restrict__ C,
    int M, int Nc, const int* __restrict__ flags, int a_sel)
{
    __shared__ unsigned short Bs[64][264];   // W^T tile: Bs[n][k], all K
    const int isbf = flags[0];
    const int abf = (a_sel == 2) ? isbf : a_sel;
    const int tid = threadIdx.x;
    const int wave = tid >> 6, lane = tid & 63;
    const int quad = lane >> 4, nl = lane & 15;
    const int m0 = blockIdx.x * 64;
    const int n0 = blockIdx.y * 64;

#pragma unroll
    for (int it = 0; it < 8; ++it) {
        int p8 = it * 256 + tid;
        int k = p8 >> 3, nb = p8 & 7;
        ushort4 w0, w1;
        ld8(W, (size_t)k * Nc + n0 + nb * 8, isbf, w0, w1);
        int nbase = nb * 8;
        Bs[nbase + 0][k] = w0.x; Bs[nbase + 1][k] = w0.y;
        Bs[nbase + 2][k] = w0.z; Bs[nbase + 3][k] = w0.w;
        Bs[nbase + 4][k] = w1.x; Bs[nbase + 5][k] = w1.y;
        Bs[nbase + 6][k] = w1.z; Bs[nbase + 7][k] = w1.w;
    }
    __syncthreads();

    const int arow = m0 + wave * 16 + nl;         // A row this lane supplies
    const int av = (arow < M);
    const size_t abase = (size_t)arow * DH + quad * 8;
    f32x4 acc[4] = {{0.f,0.f,0.f,0.f},{0.f,0.f,0.f,0.f},{0.f,0.f,0.f,0.f},{0.f,0.f,0.f,0.f}};

#pragma unroll
    for (int k0 = 0; k0 < DH; k0 += 32) {
        ushort4 a0, a1;
        if (av) ld8(A, abase + k0, abf, a0, a1);
        else { a0 = make_ushort4(0,0,0,0); a1 = a0; }
        bf16x8 af;
        ((ushort4*)&af)[0] = a0; ((ushort4*)&af)[1] = a1;
#pragma unroll
        for (int ct = 0; ct < 4; ++ct) {
            bf16x8 bfg = *(const bf16x8*)&Bs[ct * 16 + nl][k0 + quad * 8];
            acc[ct] = __builtin_amdgcn_mfma_f32_16x16x32_bf16(af, bfg, acc[ct], 0, 0, 0);
        }
    }

#pragma unroll
    for (int ct = 0; ct < 4; ++ct) {
        int n = n0 + ct * 16 + nl;
        float bv = bias ? ldf(bias, n, isbf) : 0.f;
#pragma unroll
        for (int r = 0; r < 4; ++r) {
            int m = m0 + wave * 16 + quad * 4 + r;
            if (m < M) stS(C, (size_t)m * Nc + n, acc[ct][r] + bv);
        }
    }
}

// ---------------- MFMA kvs: D[256,256] = A^T @ B over N (split-N, atomic f32) ----------------
// call with (Vm, Km, kvs): D[j][i] = sum_n V[n][j]*K[n][i]  == kvs transposed, row-major
template <typename ST>
__global__ __launch_bounds__(256) void kvs_mfma(
    const ST* __restrict__ Am, const ST* __restrict__ Bm, float* __restrict__ D)
{
    __shared__ unsigned short Ast[64][36];
    __shared__ unsigned short Bst[64][36];
    const int tid = threadIdx.x;
    const int wave = tid >> 6, lane = tid & 63;
    const int quad = lane >> 4, nl = lane & 15;
    const int i0 = blockIdx.x * 64, j0 = blockIdx.y * 64;   // i0: D rows (A cols), j0: D cols (B cols)
    const int S = gridDim.z;
    const int chunk = (NN + S - 1) / S;
    const int ns = blockIdx.z * chunk;
    const int ne = min(ns + chunk, NN);
    const int nn = tid >> 3;          // row within 32-row chunk (0..31)
    const int c0 = (tid & 7) * 8;     // col offset within 64-col tile (0,8,...,56)
    f32x4 acc[4] = {{0.f,0.f,0.f,0.f},{0.f,0.f,0.f,0.f},{0.f,0.f,0.f,0.f},{0.f,0.f,0.f,0.f}};

    for (int n0 = ns; n0 < ne; n0 += 32) {
        int n = n0 + nn;
        ushort4 a0, a1, b0, b1;
        if (n < ne) {
            ld8S(Am, (size_t)n * DH + i0 + c0, a0, a1);
            ld8S(Bm, (size_t)n * DH + j0 + c0, b0, b1);
        } else {
            a0 = make_ushort4(0, 0, 0, 0); a1 = a0; b0 = a0; b1 = a0;
        }
        __syncthreads();   // previous chunk's frag reads done; loads above stay in flight
        Ast[c0 + 0][nn] = a0.x; Ast[c0 + 1][nn] = a0.y;
        Ast[c0 + 2][nn] = a0.z; Ast[c0 + 3][nn] = a0.w;
        Ast[c0 + 4][nn] = a1.x; Ast[c0 + 5][nn] = a1.y;
        Ast[c0 + 6][nn] = a1.z; Ast[c0 + 7][nn] = a1.w;
        Bst[c0 + 0][nn] = b0.x; Bst[c0 + 1][nn] = b0.y;
        Bst[c0 + 2][nn] = b0.z; Bst[c0 + 3][nn] = b0.w;
        Bst[c0 + 4][nn] = b1.x; Bst[c0 + 5][nn] = b1.y;
        Bst[c0 + 6][nn] = b1.z; Bst[c0 + 7][nn] = b1.w;
        __syncthreads();
        bf16x8 af = *(const bf16x8*)&Ast[wave * 16 + nl][quad * 8];
#pragma unroll
        for (int ct = 0; ct < 4; ++ct) {
            bf16x8 bfg = *(const bf16x8*)&Bst[ct * 16 + nl][quad * 8];
            acc[ct] = __builtin_amdgcn_mfma_f32_16x16x32_bf16(af, bfg, acc[ct], 0, 0, 0);
        }
    }
#pragma unroll
    for (int ct = 0; ct < 4; ++ct)
#pragma unroll
        for (int r = 0; r < 4; ++r)
            atomicAdd(&D[(size_t)(i0 + wave * 16 + quad * 4 + r) * DH + j0 + ct * 16 + nl], acc[ct][r]);
}

// ---------------- kvs f32 -> bf16 convert (once; attn re-reads it 1563x) ----------------
__global__ __launch_bounds__(256) void kvs2b_kernel(const float* __restrict__ kvs,
                                                    unsigned short* __restrict__ kvsb)
{
    int i = blockIdx.x * 256 + threadIdx.x;      // 8192 threads x 8 elems = 65536
    size_t o = (size_t)i * 8;
    float4 a = *(const float4*)(kvs + o);
    float4 b = *(const float4*)(kvs + o + 4);
    *(ushort4*)(kvsb + o)     = make_ushort4(f2b(a.x), f2b(a.y), f2b(a.z), f2b(a.w));
    *(ushort4*)(kvsb + o + 4) = make_ushort4(f2b(b.x), f2b(b.y), f2b(b.z), f2b(b.w));
}

// ---------------- MFMA attention: out = (Q@kvs*scale + N*V) / (Q.ks_sum*scale + N) ----------------
// kvsb: kvs transposed, bf16, row-major [256][256] (L2-resident, 128KB).
// No LDS staging: A and B fragments are both 16B-contiguous in global memory and
// every byte is read exactly once per wave -> fragment-direct loads, no barriers.
template <typename ST>
__global__ __launch_bounds__(256) void attn_mfma(
    const ST* __restrict__ Q, const ST* __restrict__ V,
    const unsigned short* __restrict__ kvsb, const float* __restrict__ ks_sum,
    const float* __restrict__ qss, const float* __restrict__ kss,
    ST* __restrict__ out)
{
    __shared__ float ks_s[DH];
    __shared__ float nrm_s[64];
    const int tid = threadIdx.x;
    const int wave = tid >> 6, lane = tid & 63;
    const int quad = lane >> 4, nl = lane & 15;
    const int m0 = blockIdx.x * 64;

    ks_s[tid] = ks_sum[tid];
    __syncthreads();

    const int arow = m0 + wave * 16 + nl;
    const int av = (arow < NN);
    const size_t abase = (size_t)arow * DH + quad * 8;
    f32x4 acc[16];
#pragma unroll
    for (int i = 0; i < 16; ++i) acc[i] = (f32x4){0.f, 0.f, 0.f, 0.f};
    float nrm = 0.f;

    for (int k0 = 0; k0 < DH; k0 += 32) {
        ushort4 a0, a1;
        if (av) ld8S(Q, abase + k0, a0, a1);
        else { a0 = make_ushort4(0,0,0,0); a1 = a0; }
        bf16x8 af;
        ((ushort4*)&af)[0] = a0; ((ushort4*)&af)[1] = a1;
#pragma unroll
        for (int j = 0; j < 8; ++j)
            nrm += bits2f(((const unsigned short*)&af)[j]) * ks_s[k0 + quad * 8 + j];
        const unsigned short* kb = kvsb + (size_t)nl * DH + k0 + quad * 8;
#pragma unroll
        for (int ct = 0; ct < 16; ++ct) {
            bf16x8 bfg = *(const bf16x8*)(kb + (size_t)ct * 16 * DH);
            acc[ct] = __builtin_amdgcn_mfma_f32_16x16x32_bf16(af, bfg, acc[ct], 0, 0, 0);
        }
    }
    nrm += __shfl_xor(nrm, 16);
    nrm += __shfl_xor(nrm, 32);
    if (lane < 16) nrm_s[wave * 16 + lane] = nrm;
    __syncthreads();
    const float scale = rsqrtf(*qss) * rsqrtf(*kss);
#pragma unroll
    for (int r = 0; r < 4; ++r) {
        int row = m0 + wave * 16 + quad * 4 + r;
        if (row >= NN) continue;
        float den = nrm_s[wave * 16 + quad * 4 + r] * scale + (float)NN;
#pragma unroll
        for (int ct = 0; ct < 16; ++ct) {
            int col = ct * 16 + nl;
            float v = ldS(V, (size_t)row * DH + col);
            float numv = acc[ct][r] * scale + (float)NN * v;
            stS(out, (size_t)row * DH + col, numv / den);
        }
    }
}

// ---------------- LayerNorm over D=256 (optional residual mix, relu) ----------------
template <typename ST>
__global__ __launch_bounds__(256) void ln_kernel(
    const ST* __restrict__ A, const ST* __restrict__ B,
    float alpha, float beta,
    const void* __restrict__ g, const void* __restrict__ b,
    ST* __restrict__ out, int relu, const int* __restrict__ flags)
{
    __shared__ float ps[4], ps2[4];
    const int isbf = flags[0];
    const int row = blockIdx.x;
    const int t = threadIdx.x;
    size_t idx = (size_t)row * DH + t;
    float v = alpha * ldS(A, idx);
    if (B) v += beta * ldS(B, idx);
    float s = v, s2 = v * v;
#pragma unroll
    for (int off = 32; off > 0; off >>= 1) {
        s += __shfl_down(s, off);
        s2 += __shfl_down(s2, off);
    }
    if ((t & 63) == 0) { ps[t >> 6] = s; ps2[t >> 6] = s2; }
    __syncthreads();
    float S = ps[0] + ps[1] + ps[2] + ps[3];
    float S2 = ps2[0] + ps2[1] + ps2[2] + ps2[3];
    float mean = S * (1.f / DH);
    float var = S2 * (1.f / DH) - mean * mean;
    float rstd = rsqrtf(var + 1e-5f);
    float o = (v - mean) * rstd * ldf(g, t, isbf) + ldf(b, t, isbf);
    if (relu) o = fmaxf(o, 0.f);
    stS(out, idx, o);
}

// ---------------- sum of squares ----------------
template <typename ST>
__global__ __launch_bounds__(256) void sumsq_kernel(
    const ST* __restrict__ A, size_t n, float* __restrict__ out)
{
    __shared__ float ps[4];
    size_t i = (size_t)blockIdx.x * blockDim.x + threadIdx.x;
    size_t stride = (size_t)gridDim.x * blockDim.x;
    float s = 0.f;
    for (; i < n; i += stride) { float v = ldS(A, i); s += v * v; }
#pragma unroll
    for (int off = 32; off > 0; off >>= 1) s += __shfl_down(s, off);
    if ((threadIdx.x & 63) == 0) ps[threadIdx.x >> 6] = s;
    __syncthreads();
    if (threadIdx.x == 0) atomicAdd(out, ps[0] + ps[1] + ps[2] + ps[3]);
}

// ---------------- ks_sum[j] = sum_n K[n][j] (rows-per-block from gridDim) ----------------
template <typename ST>
__global__ __launch_bounds__(256) void colsum_kernel(
    const ST* __restrict__ Km, float* __restrict__ out)
{
    const int t = threadIdx.x;
    const int per = (NN + gridDim.x - 1) / gridDim.x;
    size_t r0 = (size_t)blockIdx.x * per;
    size_t r1 = r0 + per; if (r1 > NN) r1 = NN;
    float s = 0.f;
    for (size_t r = r0; r < r1; ++r) s += ldS(Km, r * DH + t);
    atomicAdd(&out[t], s);
}

// ---------------- CSR build ----------------
__global__ __launch_bounds__(256) void count_kernel(const int* __restrict__ ei, int* __restrict__ cnt,
                                                    const int* __restrict__ flags)
{
    int e = blockIdx.x * 256 + threadIdx.x;
    if (e >= NE) return;
    int d = ld_dst(ei, e, flags[1]);
    if ((unsigned)d < NN) atomicAdd(&cnt[d], 1);
}

__global__ __launch_bounds__(256) void scan_block_kernel(const int* __restrict__ cnt,
                                                         int* __restrict__ pre, int* __restrict__ bsum)
{
    __shared__ int s[256];
    int i = blockIdx.x * 256 + threadIdx.x;
    int v = (i < NN) ? cnt[i] : 0;
    s[threadIdx.x] = v;
    __syncthreads();
    for (int off = 1; off < 256; off <<= 1) {
        int t = (threadIdx.x >= off) ? s[threadIdx.x - off] : 0;
        __syncthreads();
        s[threadIdx.x] += t;
        __syncthreads();
    }
    if (i < NN) pre[i] = s[threadIdx.x] - v;
    if (threadIdx.x == 255) bsum[blockIdx.x] = s[255];
}

__global__ __launch_bounds__(512) void scan_partial_kernel(int* __restrict__ bsum, int nb)
{
    __shared__ int s[512];
    int t = threadIdx.x;
    int v = (t < nb) ? bsum[t] : 0;
    s[t] = v;
    __syncthreads();
    for (int off = 1; off < 512; off <<= 1) {
        int u = (t >= off) ? s[t - off] : 0;
        __syncthreads();
        s[t] += u;
        __syncthreads();
    }
    if (t < nb) bsum[t] = s[t] - v;
}

__global__ __launch_bounds__(256) void finalize_kernel(int* __restrict__ base, const int* __restrict__ bsum,
                                                       const int* __restrict__ cnt, int* __restrict__ cursor,
                                                       float* __restrict__ dinv)
{
    int i = blockIdx.x * 256 + threadIdx.x;
    if (i >= NN) return;
    int b = base[i] + bsum[blockIdx.x];
    base[i] = b;
    cursor[i] = b;
    dinv[i] = rsqrtf((float)cnt[i] + 1.0f);
}

__global__ __launch_bounds__(256) void scatter_kernel(const int* __restrict__ ei, int* __restrict__ cursor,
                                                      int* __restrict__ srcs, const int* __restrict__ flags)
{
    int e = blockIdx.x * 256 + threadIdx.x;
    if (e >= NE) return;
    int i64 = flags[1];
    int s = ld_src(ei, e, i64), d = ld_dst(ei, e, i64);
    if ((unsigned)s >= NN || (unsigned)d >= NN) return;
    int pos = atomicAdd(&cursor[d], 1);
    srcs[pos] = s;
}

// ---------------- CSR gather aggregate: one wave per node ----------------
template <typename ST>
__global__ __launch_bounds__(256) void gather_kernel(
    const ST* __restrict__ Hs, const int* __restrict__ base, const int* __restrict__ cnt,
    const int* __restrict__ srcs, const float* __restrict__ dinv,
    float* __restrict__ lo, float* __restrict__ hi)
{
    int node = blockIdx.x * 4 + (threadIdx.x >> 6);
    int lane = threadIdx.x & 63;
    if (node >= NN) return;
    int b0 = base[node], deg = cnt[node];
    float dd = dinv[node];
    float4 acc = make_float4(0.f, 0.f, 0.f, 0.f);
    for (int j = 0; j < deg; ++j) {
        int s = srcs[b0 + j];
        float nrm = dd * dinv[s];
        float4 h4 = ld4S(&Hs[(size_t)s * DH + lane * 4]);
        acc.x += h4.x * nrm; acc.y += h4.y * nrm;
        acc.z += h4.z * nrm; acc.w += h4.w * nrm;
    }
    float* o = (node < NSPL ? &lo[(size_t)node * DH] : &hi[(size_t)(node - NSPL) * DH]) + lane * 4;
    *(float4*)o = acc;
}

// ---------------- fallback (atomic) GCN pieces ----------------
__global__ __launch_bounds__(256) void deg_kernel(const int* __restrict__ ei, float* __restrict__ deg,
                                                  const int* __restrict__ flags)
{
    int i64 = flags[1];
    int e = blockIdx.x * 256 + threadIdx.x;
    if (e >= NE) return;
    int d = ld_dst(ei, e, i64);
    if ((unsigned)d < NN) atomicAdd(&deg[d], 1.0f);
}

__global__ __launch_bounds__(256) void dinv_kernel(float* __restrict__ deg)
{
    int i = blockIdx.x * 256 + threadIdx.x;
    if (i < NN) deg[i] = rsqrtf(deg[i] + 1.0f);
}

template <typename ST>
__global__ __launch_bounds__(256) void agg_kernel(
    const ST* __restrict__ Hs, const int* __restrict__ ei,
    const float* __restrict__ dinv, float* __restrict__ lo, float* __restrict__ hi,
    const int* __restrict__ flags)
{
    int i64 = flags[1];
    int e = blockIdx.x * 4 + (threadIdx.x >> 6);
    int lane = threadIdx.x & 63;
    if (e >= NE) return;
    int s = ld_src(ei, e, i64), d = ld_dst(ei, e, i64);
    if ((unsigned)s >= NN || (unsigned)d >= NN) return;
    float nrm = dinv[s] * dinv[d];
    const float4 h4 = ld4S(&Hs[(size_t)s * DH + lane * 4]);
    float* o = (d < NSPL ? &lo[(size_t)d * DH] : &hi[(size_t)(d - NSPL) * DH]) + lane * 4;
    atomicAdd(o + 0, h4.x * nrm);
    atomicAdd(o + 1, h4.y * nrm);
    atomicAdd(o + 2, h4.z * nrm);
    atomicAdd(o + 3, h4.w * nrm);
}

// self-loop + bias + BN(eval) + relu
template <typename ST>
__global__ __launch_bounds__(256) void gcn_epi1_kernel(
    const float* __restrict__ lo, const float* __restrict__ hi,
    const ST* __restrict__ h1, const float* __restrict__ dinv,
    const void* __restrict__ b0, const void* __restrict__ bng, const void* __restrict__ bnb,
    const int* __restrict__ flags, ST* __restrict__ out)
{
    const int isbf = flags[0];
    size_t idx = (size_t)blockIdx.x * 256 + threadIdx.x;
    if (idx >= (size_t)NN * DH) return;
    int i = (int)(idx >> 8), c = (int)(idx & 255);
    float aggv = (i < NSPL) ? lo[idx] : hi[idx - NSO];
    float di = dinv[i];
    float v = aggv + ldS(h1, idx) * di * di + ldf(b0, c, isbf);
    const float bnscale = 0.99999500003749981f;  // 1/sqrt(1+1e-5)
    v = v * (ldf(bng, c, isbf) * bnscale) + ldf(bnb, c, isbf);
    stS(out, idx, fmaxf(v, 0.f));
}

// self-loop + bias + combine: emb = 0.8*(agg + self + b1) + 0.2*x_trans
template <typename ST>
__global__ __launch_bounds__(256) void gcn_epi2_kernel(
    const float* __restrict__ lo, const float* __restrict__ hi,
    const ST* __restrict__ h2, const ST* __restrict__ Ht, const float* __restrict__ dinv,
    const void* __restrict__ b1, const int* __restrict__ flags, ST* __restrict__ out)
{
    const int isbf = flags[0];
    size_t idx = (size_t)blockIdx.x * 256 + threadIdx.x;
    if (idx >= (size_t)NN * DH) return;
    int i = (int)(idx >> 8), c = (int)(idx & 255);
    float aggv = (i < NSPL) ? lo[idx] : hi[idx - NSO];
    float di = dinv[i];
    float g = aggv + ldS(h2, idx) * di * di + ldf(b1, c, isbf);
    stS(out, idx, 0.8f * g + 0.2f * ldS(Ht, idx));
}

// ---------------- diagnostic ----------------
__global__ __launch_bounds__(256) void diag_kernel(float* out, size_t n, float val)
{
    size_t i = (size_t)blockIdx.x * 256 + threadIdx.x;
    if (i < n) out[i] = val;
}

// ---------------- pipeline ----------------
template <typename ST>
static void run_pipeline(void* const* d_in, void* d_out, char* wsb, hipStream_t stream, int use_csr)
{
    const void* x      = d_in[0];
    const int*  ei     = (const int*)d_in[1];
    const void* fc0_w  = d_in[2];  const void* fc0_b  = d_in[3];
    const void* ln0_g  = d_in[4];  const void* ln0_b  = d_in[5];
    const void* wq0_w  = d_in[6];  const void* wq0_b  = d_in[7];
    const void* wk0_w  = d_in[8];  const void* wk0_b  = d_in[9];
    const void* wv0_w  = d_in[10]; const void* wv0_b  = d_in[11];
    const void* ln1_g  = d_in[12]; const void* ln1_b  = d_in[13];
    const void* wq1_w  = d_in[14]; const void* wq1_b  = d_in[15];
    const void* wk1_w  = d_in[16]; const void* wk1_b  = d_in[17];
    const void* wv1_w  = d_in[18]; const void* wv1_b  = d_in[19];
    const void* ln2_g  = d_in[20]; const void* ln2_b  = d_in[21];
    const void* gcn_w0 = d_in[22]; const void* gcn_b0 = d_in[23];
    const void* bn_g   = d_in[24]; const void* bn_b   = d_in[25];
    const void* gcn_w1 = d_in[26]; const void* gcn_b1 = d_in[27];
    const void* fc_w   = d_in[28]; const void* fc_b   = d_in[29];

    const size_t stN = (size_t)NN * DH * sizeof(ST);
    ST* H  = (ST*)(wsb);
    ST* Qb = (ST*)(wsb + stN);
    ST* Kb = (ST*)(wsb + 2 * stN);
    ST* Vb = (ST*)(wsb + 3 * stN);
    float* aux = (float*)(wsb + 4 * stN);
    float* kvs    = aux;
    float* ks_sum = aux + 65536;
    float* qss    = aux + 65792;
    float* kss    = aux + 65793;
    float* dinv   = aux + 65808;
    int*   flags  = (int*)(aux + 65808 + NN);
    int* cnt    = (int*)(aux + 65808 + NN + 16);
    int* base   = cnt + NN;
    int* cursor = base + NN;
    int* bsum   = cursor + NN;       // 512
    int* srcs   = bsum + 512;        // NE
    // dinv region (NN floats = 400KB) is dead until the GCN branch; borrow 128KB
    // of it for the bf16 copy of kvsT during the attention layers.
    unsigned short* kvsb = (unsigned short*)dinv;

    const int asel = (sizeof(ST) == 2) ? 1 : 0;
    dim3 mfmaGrid((NN + 63) / 64, DH / 64);
    const size_t NELEM = (size_t)NN * DH;

    detect_kernel<<<1, 256, 0, stream>>>(x, ei, flags);

    // ---- TransConv input layer ----
    gemm_mfma<ST><<<mfmaGrid, 256, 0, stream>>>(x, fc0_w, fc0_b, Qb, NN, DH, flags, 2);
    ln_kernel<ST><<<NN, 256, 0, stream>>>(Qb, (const ST*)nullptr, 1.f, 0.f, ln0_g, ln0_b, H, 1, flags);

    // ---- two attention layers ----
    for (int layer = 0; layer < 2; ++layer) {
        const void *qw, *qb, *kw, *kb, *vw, *vb, *lg, *lb;
        if (layer == 0) { qw = wq0_w; qb = wq0_b; kw = wk0_w; kb = wk0_b; vw = wv0_w; vb = wv0_b; lg = ln1_g; lb = ln1_b; }
        else            { qw = wq1_w; qb = wq1_b; kw = wk1_w; kb = wk1_b; vw = wv1_w; vb = wv1_b; lg = ln2_g; lb = ln2_b; }
        gemm_mfma<ST><<<mfmaGrid, 256, 0, stream>>>(H, qw, qb, Qb, NN, DH, flags, asel);
        gemm_mfma<ST><<<mfmaGrid, 256, 0, stream>>>(H, kw, kb, Kb, NN, DH, flags, asel);
        gemm_mfma<ST><<<mfmaGrid, 256, 0, stream>>>(H, vw, vb, Vb, NN, DH, flags, asel);
        hipMemsetAsync(aux, 0, (65536 + 256 + 2) * sizeof(float), stream);
        sumsq_kernel<ST><<<2048, 256, 0, stream>>>(Qb, NELEM, qss);
        sumsq_kernel<ST><<<2048, 256, 0, stream>>>(Kb, NELEM, kss);
        // kvs stored TRANSPOSED: kvs[j][i] = sum_n V[n][j] K[n][i]
        kvs_mfma<ST><<<dim3(4, 4, 64), 256, 0, stream>>>(Vb, Kb, kvs);
        colsum_kernel<ST><<<800, 256, 0, stream>>>(Kb, ks_sum);
        kvs2b_kernel<<<32, 256, 0, stream>>>(kvs, kvsb);
        attn_mfma<ST><<<(NN + 63) / 64, 256, 0, stream>>>(Qb, Vb, kvsb, ks_sum, qss, kss, Kb);
        ln_kernel<ST><<<NN, 256, 0, stream>>>(Kb, H, 0.5f, 0.5f, lg, lb, H, 0, flags);
    }

    // ---- GCN branch ----
    float* a1lo = (float*)(wsb + 2 * stN);
    float* a1hi = a1lo + NSO;
    ST* h2; float *a2lo, *a2hi;
    if (sizeof(ST) == 4) { h2 = Vb; a2lo = (float*)(wsb + 2 * stN); a2hi = a2lo + NSO; }
    else                 { h2 = Kb; a2lo = (float*)(wsb + stN);     a2hi = (float*)(wsb + 3 * stN); }

    if (use_csr) {
        hipMemsetAsync(cnt, 0, NN * sizeof(int), stream);
        count_kernel<<<(NE + 255) / 256, 256, 0, stream>>>(ei, cnt, flags);
        scan_block_kernel<<<NBLK, 256, 0, stream>>>(cnt, base, bsum);
        scan_partial_kernel<<<1, 512, 0, stream>>>(bsum, NBLK);
        finalize_kernel<<<NBLK, 256, 0, stream>>>(base, bsum, cnt, cursor, dinv);
        scatter_kernel<<<(NE + 255) / 256, 256, 0, stream>>>(ei, cursor, srcs, flags);

        gemm_mfma<ST><<<mfmaGrid, 256, 0, stream>>>(x, gcn_w0, nullptr, Qb, NN, DH, flags, 2);
        gather_kernel<ST><<<(NN + 3) / 4, 256, 0, stream>>>(Qb, base, cnt, srcs, dinv, a1lo, a1hi);
        gcn_epi1_kernel<ST><<<(NELEM + 255) / 256, 256, 0, stream>>>(a1lo, a1hi, Qb, dinv, gcn_b0, bn_g, bn_b, flags, Qb);

        gemm_mfma<ST><<<mfmaGrid, 256, 0, stream>>>(Qb, gcn_w1, nullptr, h2, NN, DH, flags, asel);
        gather_kernel<ST><<<(NN + 3) / 4, 256, 0, stream>>>(h2, base, cnt, srcs, dinv, a2lo, a2hi);
        gcn_epi2_kernel<ST><<<(NELEM + 255) / 256, 256, 0, stream>>>(a2lo, a2hi, h2, H, dinv, gcn_b1, flags, h2);
    } else {
        hipMemsetAsync(dinv, 0, NN * sizeof(float), stream);
        deg_kernel<<<(NE + 255) / 256, 256, 0, stream>>>(ei, dinv, flags);
        dinv_kernel<<<(NN + 255) / 256, 256, 0, stream>>>(dinv);

        gemm_mfma<ST><<<mfmaGrid, 256, 0, stream>>>(x, gcn_w0, nullptr, Qb, NN, DH, flags, 2);
        hipMemsetAsync(a1lo, 0, NELEM * sizeof(float), stream);
        agg_kernel<ST><<<(NE + 3) / 4, 256, 0, stream>>>(Qb, ei, dinv, a1lo, a1hi, flags);
        gcn_epi1_kernel<ST><<<(NELEM + 255) / 256, 256, 0, stream>>>(a1lo, a1hi, Qb, dinv, gcn_b0, bn_g, bn_b, flags, Qb);

        gemm_mfma<ST><<<mfmaGrid, 256, 0, stream>>>(Qb, gcn_w1, nullptr, h2, NN, DH, flags, asel);
        hipMemsetAsync(a2lo, 0, NSO * sizeof(float), stream);
        hipMemsetAsync(a2hi, 0, NSO * sizeof(float), stream);
        agg_kernel<ST><<<(NE + 3) / 4, 256, 0, stream>>>(h2, ei, dinv, a2lo, a2hi, flags);
        gcn_epi2_kernel<ST><<<(NELEM + 255) / 256, 256, 0, stream>>>(a2lo, a2hi, h2, H, dinv, gcn_b1, flags, h2);
    }

    // ---- classifier (f32 output) ----
    gemm_mfma<float><<<dim3((NN + 63) / 64, 1), 256, 0, stream>>>(h2, fc_w, fc_b, (float*)d_out, NN, DOUT, flags, asel);
}

extern "C" void kernel_launch(void* const* d_in, const int* in_sizes, int n_in,
                              void* d_out, int out_size, void* d_ws, size_t ws_size,
                              hipStream_t stream)
{
    char* wsb = (char*)d_ws;
    const size_t AUXF  = 65808 + NN + 16;
    const size_t CSRI  = 3 * (size_t)NN + 512 + NE;
    const size_t AUXB  = AUXF * sizeof(float);
    const size_t AUXB2 = AUXB + CSRI * sizeof(int);
    const size_t needA  = 4 * ((size_t)NN * DH * 4) + AUXB;
    const size_t needA2 = 4 * ((size_t)NN * DH * 4) + AUXB2;
    const size_t needB  = 4 * ((size_t)NN * DH * 2) + AUXB;
    const size_t needB2 = 4 * ((size_t)NN * DH * 2) + AUXB2;

    if (ws_size >= needA) {
        run_pipeline<float>(d_in, d_out, wsb, stream, ws_size >= needA2);
    } else if (ws_size >= needB) {
        run_pipeline<bf16>(d_in, d_out, wsb, stream, ws_size >= needB2);
    } else {
        float mb = (float)(ws_size >> 20);
        size_t n = (size_t)out_size;
        diag_kernel<<<(n + 255) / 256, 256, 0, stream>>>((float*)d_out, n, mb);
    }
}

// Round 4
// 2107.706 us; speedup vs baseline: 1.4042x; 1.1258x over previous
//
#include <hip/hip_runtime.h>
#include <hip/hip_bf16.h>

#define NN 100000
#define NE 800000
#define DH 256
#define DOUT 64
#define NSPL 50000                      // GCN agg row split
#define NSO ((size_t)NSPL * DH)        // elems per half
#define NBLK 391                       // ceil(NN/256)

using bf16 = __hip_bfloat16;
typedef __attribute__((ext_vector_type(8))) short bf16x8;
typedef __attribute__((ext_vector_type(4))) float f32x4;

// ---------------- dtype helpers ----------------
__device__ __forceinline__ float bits2f(unsigned short h) {
    union { unsigned int u; float f; } c; c.u = ((unsigned int)h) << 16; return c.f;
}
__device__ __forceinline__ unsigned short f2b(float v) {
    union { float f; unsigned int u; } c; c.f = v;
    unsigned int u = c.u;
    return (unsigned short)((u + 0x7FFFu + ((u >> 16) & 1u)) >> 16);  // RNE
}
__device__ __forceinline__ unsigned short tob(float v) { return f2b(v); }
__device__ __forceinline__ unsigned short tob(bf16 v) {
    union { bf16 b; unsigned short u; } c; c.b = v; return c.u;
}
__device__ __forceinline__ float ldf(const void* p, size_t i, int isbf) {
    if (isbf) return bits2f(((const unsigned short*)p)[i]);
    return ((const float*)p)[i];
}
__device__ __forceinline__ float ldS(const float* p, size_t i) { return p[i]; }
__device__ __forceinline__ float ldS(const bf16* p, size_t i) { return __bfloat162float(p[i]); }
__device__ __forceinline__ void stS(float* p, size_t i, float v) { p[i] = v; }
__device__ __forceinline__ void stS(bf16* p, size_t i, float v) { p[i] = __float2bfloat16(v); }
__device__ __forceinline__ float4 ld4S(const float* p) { return *(const float4*)p; }
__device__ __forceinline__ float4 ld4S(const bf16* p) {
    ushort4 u = *(const ushort4*)(const void*)p;
    return make_float4(bits2f(u.x), bits2f(u.y), bits2f(u.z), bits2f(u.w));
}
__device__ __forceinline__ void st4S(float* p, float4 v) { *(float4*)p = v; }
__device__ __forceinline__ void st4S(bf16* p, float4 v) {
    *(ushort4*)(void*)p = make_ushort4(f2b(v.x), f2b(v.y), f2b(v.z), f2b(v.w));
}
// load 8 consecutive elems (16B-aligned) as bf16 bit patterns from f32 or bf16 source
__device__ __forceinline__ void ld8(const void* p, size_t idx, int isbf, ushort4& o0, ushort4& o1) {
    if (isbf) {
        const ushort4* q = (const ushort4*)((const unsigned short*)p + idx);
        o0 = q[0]; o1 = q[1];
    } else {
        const float4* q = (const float4*)((const float*)p + idx);
        float4 a = q[0], b = q[1];
        o0 = make_ushort4(f2b(a.x), f2b(a.y), f2b(a.z), f2b(a.w));
        o1 = make_ushort4(f2b(b.x), f2b(b.y), f2b(b.z), f2b(b.w));
    }
}
__device__ __forceinline__ void ld8S(const bf16* p, size_t idx, ushort4& o0, ushort4& o1) {
    const ushort4* q = (const ushort4*)((const unsigned short*)p + idx);
    o0 = q[0]; o1 = q[1];
}
__device__ __forceinline__ void ld8S(const float* p, size_t idx, ushort4& o0, ushort4& o1) {
    const float4* q = (const float4*)(p + idx);
    float4 a = q[0], b = q[1];
    o0 = make_ushort4(f2b(a.x), f2b(a.y), f2b(a.z), f2b(a.w));
    o1 = make_ushort4(f2b(b.x), f2b(b.y), f2b(b.z), f2b(b.w));
}
__device__ __forceinline__ int ld_src(const int* ei, int e, int i64) {
    return i64 ? ei[2 * (size_t)e] : ei[e];
}
__device__ __forceinline__ int ld_dst(const int* ei, int e, int i64) {
    return i64 ? ei[2 * ((size_t)NE + e)] : ei[NE + e];
}

// ---------------- dtype detector (sampled) ----------------
__global__ __launch_bounds__(256) void detect_kernel(const void* x, const int* ei, int* flags)
{
    __shared__ int s_sane[4], s_nz[4];
    int t = threadIdx.x;
    const unsigned short* xu = (const unsigned short*)x;
    int sane = 0;
    for (int i = t; i < 2048; i += 256) {
        float v = bits2f(xu[2 * i]);
        float a = fabsf(v);
        if (v == v && a > 1e-3f && a < 100.f) sane++;
    }
    int nz = 0;
    for (int i = t; i < 4096; i += 256) {
        if (ei[2 * (i * 122) + 1] != 0) nz++;
    }
#pragma unroll
    for (int off = 32; off > 0; off >>= 1) { sane += __shfl_down(sane, off); nz += __shfl_down(nz, off); }
    if ((t & 63) == 0) { s_sane[t >> 6] = sane; s_nz[t >> 6] = nz; }
    __syncthreads();
    if (t == 0) {
        flags[0] = ((s_sane[0] + s_sane[1] + s_sane[2] + s_sane[3]) > 1024) ? 1 : 0;
        flags[1] = ((s_nz[0] + s_nz[1] + s_nz[2] + s_nz[3]) == 0) ? 1 : 0;
    }
}

// ---------------- MFMA GEMM: C[M,Nc] = A[M,256] @ W[256,Nc] (+bias) ----------------
// 512 threads / 128 rows per block: B (W^T) staged to LDS ONCE (33.8KB -> 4 blk/CU
// = 32 waves/CU), A fragments read direct from global. Zero inner-loop barriers.
template <typename ST>
__global__ __launch_bounds__(512) void gemm_mfma(
    const void* __restrict__ A, const void* __restrict__ W,
    const void* __restrict__ bias, ST* __restrict__ C,
    int M, int Nc, const int* __restrict__ flags, int a_sel)
{
    __shared__ unsigned short Bs[64][264];   // W^T tile: Bs[n][k], all K
    const int isbf = flags[0];
    const int abf = (a_sel == 2) ? isbf : a_sel;
    const int tid = threadIdx.x;
    const int wave = tid >> 6, lane = tid & 63;
    const int quad = lane >> 4, nl = lane & 15;
    const int m0 = blockIdx.x * 128;
    const int n0 = blockIdx.y * 64;

#pragma unroll
    for (int it = 0; it < 4; ++it) {
        int p8 = it * 512 + tid;
        int k = p8 >> 3, nb = p8 & 7;
        ushort4 w0, w1;
        ld8(W, (size_t)k * Nc + n0 + nb * 8, isbf, w0, w1);
        int nbase = nb * 8;
        Bs[nbase + 0][k] = w0.x; Bs[nbase + 1][k] = w0.y;
        Bs[nbase + 2][k] = w0.z; Bs[nbase + 3][k] = w0.w;
        Bs[nbase + 4][k] = w1.x; Bs[nbase + 5][k] = w1.y;
        Bs[nbase + 6][k] = w1.z; Bs[nbase + 7][k] = w1.w;
    }
    __syncthreads();

    const int arow = m0 + wave * 16 + nl;         // A row this lane supplies
    const int av = (arow < M);
    const size_t abase = (size_t)arow * DH + quad * 8;
    f32x4 acc[4] = {{0.f,0.f,0.f,0.f},{0.f,0.f,0.f,0.f},{0.f,0.f,0.f,0.f},{0.f,0.f,0.f,0.f}};

#pragma unroll
    for (int k0 = 0; k0 < DH; k0 += 32) {
        ushort4 a0, a1;
        if (av) ld8(A, abase + k0, abf, a0, a1);
        else { a0 = make_ushort4(0,0,0,0); a1 = a0; }
        bf16x8 af;
        ((ushort4*)&af)[0] = a0; ((ushort4*)&af)[1] = a1;
#pragma unroll
        for (int ct = 0; ct < 4; ++ct) {
            bf16x8 bfg = *(const bf16x8*)&Bs[ct * 16 + nl][k0 + quad * 8];
            acc[ct] = __builtin_amdgcn_mfma_f32_16x16x32_bf16(af, bfg, acc[ct], 0, 0, 0);
        }
    }

#pragma unroll
    for (int ct = 0; ct < 4; ++ct) {
        int n = n0 + ct * 16 + nl;
        float bv = bias ? ldf(bias, n, isbf) : 0.f;
#pragma unroll
        for (int r = 0; r < 4; ++r) {
            int m = m0 + wave * 16 + quad * 4 + r;
            if (m < M) stS(C, (size_t)m * Nc + n, acc[ct][r] + bv);
        }
    }
}

// ---------------- MFMA kvs: D[256,256] = A^T @ B over N (split-N, atomic f32) ----------------
// call with (Vm, Km, kvs): D[j][i] = sum_n V[n][j]*K[n][i]  == kvs transposed, row-major
template <typename ST>
__global__ __launch_bounds__(256) void kvs_mfma(
    const ST* __restrict__ Am, const ST* __restrict__ Bm, float* __restrict__ D)
{
    __shared__ unsigned short Ast[64][36];
    __shared__ unsigned short Bst[64][36];
    const int tid = threadIdx.x;
    const int wave = tid >> 6, lane = tid & 63;
    const int quad = lane >> 4, nl = lane & 15;
    const int i0 = blockIdx.x * 64, j0 = blockIdx.y * 64;   // i0: D rows (A cols), j0: D cols (B cols)
    const int S = gridDim.z;
    const int chunk = (NN + S - 1) / S;
    const int ns = blockIdx.z * chunk;
    const int ne = min(ns + chunk, NN);
    const int nn = tid >> 3;          // row within 32-row chunk (0..31)
    const int c0 = (tid & 7) * 8;     // col offset within 64-col tile (0,8,...,56)
    f32x4 acc[4] = {{0.f,0.f,0.f,0.f},{0.f,0.f,0.f,0.f},{0.f,0.f,0.f,0.f},{0.f,0.f,0.f,0.f}};

    for (int n0 = ns; n0 < ne; n0 += 32) {
        int n = n0 + nn;
        ushort4 a0, a1, b0, b1;
        if (n < ne) {
            ld8S(Am, (size_t)n * DH + i0 + c0, a0, a1);
            ld8S(Bm, (size_t)n * DH + j0 + c0, b0, b1);
        } else {
            a0 = make_ushort4(0, 0, 0, 0); a1 = a0; b0 = a0; b1 = a0;
        }
        __syncthreads();   // previous chunk's frag reads done; loads above stay in flight
        Ast[c0 + 0][nn] = a0.x; Ast[c0 + 1][nn] = a0.y;
        Ast[c0 + 2][nn] = a0.z; Ast[c0 + 3][nn] = a0.w;
        Ast[c0 + 4][nn] = a1.x; Ast[c0 + 5][nn] = a1.y;
        Ast[c0 + 6][nn] = a1.z; Ast[c0 + 7][nn] = a1.w;
        Bst[c0 + 0][nn] = b0.x; Bst[c0 + 1][nn] = b0.y;
        Bst[c0 + 2][nn] = b0.z; Bst[c0 + 3][nn] = b0.w;
        Bst[c0 + 4][nn] = b1.x; Bst[c0 + 5][nn] = b1.y;
        Bst[c0 + 6][nn] = b1.z; Bst[c0 + 7][nn] = b1.w;
        __syncthreads();
        bf16x8 af = *(const bf16x8*)&Ast[wave * 16 + nl][quad * 8];
#pragma unroll
        for (int ct = 0; ct < 4; ++ct) {
            bf16x8 bfg = *(const bf16x8*)&Bst[ct * 16 + nl][quad * 8];
            acc[ct] = __builtin_amdgcn_mfma_f32_16x16x32_bf16(af, bfg, acc[ct], 0, 0, 0);
        }
    }
#pragma unroll
    for (int ct = 0; ct < 4; ++ct)
#pragma unroll
        for (int r = 0; r < 4; ++r)
            atomicAdd(&D[(size_t)(i0 + wave * 16 + quad * 4 + r) * DH + j0 + ct * 16 + nl], acc[ct][r]);
}

// ---------------- kvs f32 -> bf16 convert (once; attn re-reads it 1563x) ----------------
__global__ __launch_bounds__(256) void kvs2b_kernel(const float* __restrict__ kvs,
                                                    unsigned short* __restrict__ kvsb)
{
    int i = blockIdx.x * 256 + threadIdx.x;      // 8192 threads x 8 elems = 65536
    size_t o = (size_t)i * 8;
    float4 a = *(const float4*)(kvs + o);
    float4 b = *(const float4*)(kvs + o + 4);
    *(ushort4*)(kvsb + o)     = make_ushort4(f2b(a.x), f2b(a.y), f2b(a.z), f2b(a.w));
    *(ushort4*)(kvsb + o + 4) = make_ushort4(f2b(b.x), f2b(b.y), f2b(b.z), f2b(b.w));
}

// ---------------- MFMA attention: out = (Q@kvs*scale + N*V) / (Q.ks_sum*scale + N) ----------------
// kvsb: kvs transposed, bf16, row-major [256][256] (L2-resident, 128KB).
// Col-split: gridDim.y=4, each block does 64 rows x 64 cols -> acc[4] (16 VGPRs)
// so ~8 waves/SIMD can be resident and TLP hides the L2 fragment-load latency.
template <typename ST>
__global__ __launch_bounds__(256) void attn_mfma(
    const ST* __restrict__ Q, const ST* __restrict__ V,
    const unsigned short* __restrict__ kvsb, const float* __restrict__ ks_sum,
    const float* __restrict__ qss, const float* __restrict__ kss,
    ST* __restrict__ out)
{
    __shared__ float ks_s[DH];
    __shared__ float nrm_s[64];
    const int tid = threadIdx.x;
    const int wave = tid >> 6, lane = tid & 63;
    const int quad = lane >> 4, nl = lane & 15;
    const int m0 = blockIdx.x * 64;
    const int j0 = blockIdx.y * 64;

    ks_s[tid] = ks_sum[tid];
    __syncthreads();

    const int arow = m0 + wave * 16 + nl;
    const int av = (arow < NN);
    const size_t abase = (size_t)arow * DH + quad * 8;
    f32x4 acc[4] = {{0.f,0.f,0.f,0.f},{0.f,0.f,0.f,0.f},{0.f,0.f,0.f,0.f},{0.f,0.f,0.f,0.f}};
    float nrm = 0.f;

#pragma unroll 2
    for (int k0 = 0; k0 < DH; k0 += 32) {
        ushort4 a0, a1;
        if (av) ld8S(Q, abase + k0, a0, a1);
        else { a0 = make_ushort4(0,0,0,0); a1 = a0; }
        bf16x8 af;
        ((ushort4*)&af)[0] = a0; ((ushort4*)&af)[1] = a1;
#pragma unroll
        for (int j = 0; j < 8; ++j)
            nrm += bits2f(((const unsigned short*)&af)[j]) * ks_s[k0 + quad * 8 + j];
        const unsigned short* kb = kvsb + (size_t)(j0 + nl) * DH + k0 + quad * 8;
#pragma unroll
        for (int ct = 0; ct < 4; ++ct) {
            bf16x8 bfg = *(const bf16x8*)(kb + (size_t)ct * 16 * DH);
            acc[ct] = __builtin_amdgcn_mfma_f32_16x16x32_bf16(af, bfg, acc[ct], 0, 0, 0);
        }
    }
    nrm += __shfl_xor(nrm, 16);
    nrm += __shfl_xor(nrm, 32);
    if (lane < 16) nrm_s[wave * 16 + lane] = nrm;
    __syncthreads();
    const float scale = rsqrtf(*qss) * rsqrtf(*kss);
#pragma unroll
    for (int r = 0; r < 4; ++r) {
        int row = m0 + wave * 16 + quad * 4 + r;
        if (row >= NN) continue;
        float den = nrm_s[wave * 16 + quad * 4 + r] * scale + (float)NN;
#pragma unroll
        for (int ct = 0; ct < 4; ++ct) {
            int col = j0 + ct * 16 + nl;
            float v = ldS(V, (size_t)row * DH + col);
            float numv = acc[ct][r] * scale + (float)NN * v;
            stS(out, (size_t)row * DH + col, numv / den);
        }
    }
}

// ---------------- LayerNorm over D=256: one wave per row, 4 rows/block ----------------
template <typename ST>
__global__ __launch_bounds__(256) void ln_kernel(
    const ST* __restrict__ A, const ST* __restrict__ B,
    float alpha, float beta,
    const void* __restrict__ g, const void* __restrict__ b,
    ST* __restrict__ out, int relu, const int* __restrict__ flags)
{
    const int isbf = flags[0];
    const int wave = threadIdx.x >> 6, lane = threadIdx.x & 63;
    const int row = blockIdx.x * 4 + wave;
    if (row >= NN) return;
    const size_t base = (size_t)row * DH + lane * 4;
    float4 v = ld4S(&A[base]);
    v.x *= alpha; v.y *= alpha; v.z *= alpha; v.w *= alpha;
    if (B) {
        float4 w = ld4S(&B[base]);
        v.x += beta * w.x; v.y += beta * w.y; v.z += beta * w.z; v.w += beta * w.w;
    }
    float s = v.x + v.y + v.z + v.w;
    float s2 = v.x * v.x + v.y * v.y + v.z * v.z + v.w * v.w;
#pragma unroll
    for (int off = 32; off > 0; off >>= 1) {
        s += __shfl_xor(s, off);
        s2 += __shfl_xor(s2, off);
    }
    float mean = s * (1.f / DH);
    float var = s2 * (1.f / DH) - mean * mean;
    float rstd = rsqrtf(var + 1e-5f);
    float4 o;
    o.x = (v.x - mean) * rstd * ldf(g, lane * 4 + 0, isbf) + ldf(b, lane * 4 + 0, isbf);
    o.y = (v.y - mean) * rstd * ldf(g, lane * 4 + 1, isbf) + ldf(b, lane * 4 + 1, isbf);
    o.z = (v.z - mean) * rstd * ldf(g, lane * 4 + 2, isbf) + ldf(b, lane * 4 + 2, isbf);
    o.w = (v.w - mean) * rstd * ldf(g, lane * 4 + 3, isbf) + ldf(b, lane * 4 + 3, isbf);
    if (relu) {
        o.x = fmaxf(o.x, 0.f); o.y = fmaxf(o.y, 0.f);
        o.z = fmaxf(o.z, 0.f); o.w = fmaxf(o.w, 0.f);
    }
    st4S(&out[base], o);
}

// ---------------- sum of squares ----------------
template <typename ST>
__global__ __launch_bounds__(256) void sumsq_kernel(
    const ST* __restrict__ A, size_t n, float* __restrict__ out)
{
    __shared__ float ps[4];
    size_t i = (size_t)blockIdx.x * blockDim.x + threadIdx.x;
    size_t stride = (size_t)gridDim.x * blockDim.x;
    float s = 0.f;
    for (; i < n; i += stride) { float v = ldS(A, i); s += v * v; }
#pragma unroll
    for (int off = 32; off > 0; off >>= 1) s += __shfl_down(s, off);
    if ((threadIdx.x & 63) == 0) ps[threadIdx.x >> 6] = s;
    __syncthreads();
    if (threadIdx.x == 0) atomicAdd(out, ps[0] + ps[1] + ps[2] + ps[3]);
}

// ---------------- ks_sum[j] = sum_n K[n][j] (rows-per-block from gridDim) ----------------
template <typename ST>
__global__ __launch_bounds__(256) void colsum_kernel(
    const ST* __restrict__ Km, float* __restrict__ out)
{
    const int t = threadIdx.x;
    const int per = (NN + gridDim.x - 1) / gridDim.x;
    size_t r0 = (size_t)blockIdx.x * per;
    size_t r1 = r0 + per; if (r1 > NN) r1 = NN;
    float s = 0.f;
    for (size_t r = r0; r < r1; ++r) s += ldS(Km, r * DH + t);
    atomicAdd(&out[t], s);
}

// ---------------- CSR build ----------------
__global__ __launch_bounds__(256) void count_kernel(const int* __restrict__ ei, int* __restrict__ cnt,
                                                    const int* __restrict__ flags)
{
    int e = blockIdx.x * 256 + threadIdx.x;
    if (e >= NE) return;
    int d = ld_dst(ei, e, flags[1]);
    if ((unsigned)d < NN) atomicAdd(&cnt[d], 1);
}

__global__ __launch_bounds__(256) void scan_block_kernel(const int* __restrict__ cnt,
                                                         int* __restrict__ pre, int* __restrict__ bsum)
{
    __shared__ int s[256];
    int i = blockIdx.x * 256 + threadIdx.x;
    int v = (i < NN) ? cnt[i] : 0;
    s[threadIdx.x] = v;
    __syncthreads();
    for (int off = 1; off < 256; off <<= 1) {
        int t = (threadIdx.x >= off) ? s[threadIdx.x - off] : 0;
        __syncthreads();
        s[threadIdx.x] += t;
        __syncthreads();
    }
    if (i < NN) pre[i] = s[threadIdx.x] - v;
    if (threadIdx.x == 255) bsum[blockIdx.x] = s[255];
}

__global__ __launch_bounds__(512) void scan_partial_kernel(int* __restrict__ bsum, int nb)
{
    __shared__ int s[512];
    int t = threadIdx.x;
    int v = (t < nb) ? bsum[t] : 0;
    s[t] = v;
    __syncthreads();
    for (int off = 1; off < 512; off <<= 1) {
        int u = (t >= off) ? s[t - off] : 0;
        __syncthreads();
        s[t] += u;
        __syncthreads();
    }
    if (t < nb) bsum[t] = s[t] - v;
}

__global__ __launch_bounds__(256) void finalize_kernel(int* __restrict__ base, const int* __restrict__ bsum,
                                                       const int* __restrict__ cnt, int* __restrict__ cursor,
                                                       float* __restrict__ dinv)
{
    int i = blockIdx.x * 256 + threadIdx.x;
    if (i >= NN) return;
    int b = base[i] + bsum[blockIdx.x];
    base[i] = b;
    cursor[i] = b;
    dinv[i] = rsqrtf((float)cnt[i] + 1.0f);
}

__global__ __launch_bounds__(256) void scatter_kernel(const int* __restrict__ ei, int* __restrict__ cursor,
                                                      int* __restrict__ srcs, const int* __restrict__ flags)
{
    int e = blockIdx.x * 256 + threadIdx.x;
    if (e >= NE) return;
    int i64 = flags[1];
    int s = ld_src(ei, e, i64), d = ld_dst(ei, e, i64);
    if ((unsigned)s >= NN || (unsigned)d >= NN) return;
    int pos = atomicAdd(&cursor[d], 1);
    srcs[pos] = s;
}

// ---------------- CSR gather aggregate: one wave per node ----------------
template <typename ST>
__global__ __launch_bounds__(256) void gather_kernel(
    const ST* __restrict__ Hs, const int* __restrict__ base, const int* __restrict__ cnt,
    const int* __restrict__ srcs, const float* __restrict__ dinv,
    float* __restrict__ lo, float* __restrict__ hi)
{
    int node = blockIdx.x * 4 + (threadIdx.x >> 6);
    int lane = threadIdx.x & 63;
    if (node >= NN) return;
    int b0 = base[node], deg = cnt[node];
    float dd = dinv[node];
    float4 acc = make_float4(0.f, 0.f, 0.f, 0.f);
    for (int j = 0; j < deg; ++j) {
        int s = srcs[b0 + j];
        float nrm = dd * dinv[s];
        float4 h4 = ld4S(&Hs[(size_t)s * DH + lane * 4]);
        acc.x += h4.x * nrm; acc.y += h4.y * nrm;
        acc.z += h4.z * nrm; acc.w += h4.w * nrm;
    }
    float* o = (node < NSPL ? &lo[(size_t)node * DH] : &hi[(size_t)(node - NSPL) * DH]) + lane * 4;
    *(float4*)o = acc;
}

// ---------------- fallback (atomic) GCN pieces ----------------
__global__ __launch_bounds__(256) void deg_kernel(const int* __restrict__ ei, float* __restrict__ deg,
                                                  const int* __restrict__ flags)
{
    int i64 = flags[1];
    int e = blockIdx.x * 256 + threadIdx.x;
    if (e >= NE) return;
    int d = ld_dst(ei, e, i64);
    if ((unsigned)d < NN) atomicAdd(&deg[d], 1.0f);
}

__global__ __launch_bounds__(256) void dinv_kernel(float* __restrict__ deg)
{
    int i = blockIdx.x * 256 + threadIdx.x;
    if (i < NN) deg[i] = rsqrtf(deg[i] + 1.0f);
}

template <typename ST>
__global__ __launch_bounds__(256) void agg_kernel(
    const ST* __restrict__ Hs, const int* __restrict__ ei,
    const float* __restrict__ dinv, float* __restrict__ lo, float* __restrict__ hi,
    const int* __restrict__ flags)
{
    int i64 = flags[1];
    int e = blockIdx.x * 4 + (threadIdx.x >> 6);
    int lane = threadIdx.x & 63;
    if (e >= NE) return;
    int s = ld_src(ei, e, i64), d = ld_dst(ei, e, i64);
    if ((unsigned)s >= NN || (unsigned)d >= NN) return;
    float nrm = dinv[s] * dinv[d];
    const float4 h4 = ld4S(&Hs[(size_t)s * DH + lane * 4]);
    float* o = (d < NSPL ? &lo[(size_t)d * DH] : &hi[(size_t)(d - NSPL) * DH]) + lane * 4;
    atomicAdd(o + 0, h4.x * nrm);
    atomicAdd(o + 1, h4.y * nrm);
    atomicAdd(o + 2, h4.z * nrm);
    atomicAdd(o + 3, h4.w * nrm);
}

// self-loop + bias + BN(eval) + relu
template <typename ST>
__global__ __launch_bounds__(256) void gcn_epi1_kernel(
    const float* __restrict__ lo, const float* __restrict__ hi,
    const ST* __restrict__ h1, const float* __restrict__ dinv,
    const void* __restrict__ b0, const void* __restrict__ bng, const void* __restrict__ bnb,
    const int* __restrict__ flags, ST* __restrict__ out)
{
    const int isbf = flags[0];
    size_t idx = (size_t)blockIdx.x * 256 + threadIdx.x;
    if (idx >= (size_t)NN * DH) return;
    int i = (int)(idx >> 8), c = (int)(idx & 255);
    float aggv = (i < NSPL) ? lo[idx] : hi[idx - NSO];
    float di = dinv[i];
    float v = aggv + ldS(h1, idx) * di * di + ldf(b0, c, isbf);
    const float bnscale = 0.99999500003749981f;  // 1/sqrt(1+1e-5)
    v = v * (ldf(bng, c, isbf) * bnscale) + ldf(bnb, c, isbf);
    stS(out, idx, fmaxf(v, 0.f));
}

// self-loop + bias + combine: emb = 0.8*(agg + self + b1) + 0.2*x_trans
template <typename ST>
__global__ __launch_bounds__(256) void gcn_epi2_kernel(
    const float* __restrict__ lo, const float* __restrict__ hi,
    const ST* __restrict__ h2, const ST* __restrict__ Ht, const float* __restrict__ dinv,
    const void* __restrict__ b1, const int* __restrict__ flags, ST* __restrict__ out)
{
    const int isbf = flags[0];
    size_t idx = (size_t)blockIdx.x * 256 + threadIdx.x;
    if (idx >= (size_t)NN * DH) return;
    int i = (int)(idx >> 8), c = (int)(idx & 255);
    float aggv = (i < NSPL) ? lo[idx] : hi[idx - NSO];
    float di = dinv[i];
    float g = aggv + ldS(h2, idx) * di * di + ldf(b1, c, isbf);
    stS(out, idx, 0.8f * g + 0.2f * ldS(Ht, idx));
}

// ---------------- diagnostic ----------------
__global__ __launch_bounds__(256) void diag_kernel(float* out, size_t n, float val)
{
    size_t i = (size_t)blockIdx.x * 256 + threadIdx.x;
    if (i < n) out[i] = val;
}

// ---------------- pipeline ----------------
template <typename ST>
static void run_pipeline(void* const* d_in, void* d_out, char* wsb, hipStream_t stream, int use_csr)
{
    const void* x      = d_in[0];
    const int*  ei     = (const int*)d_in[1];
    const void* fc0_w  = d_in[2];  const void* fc0_b  = d_in[3];
    const void* ln0_g  = d_in[4];  const void* ln0_b  = d_in[5];
    const void* wq0_w  = d_in[6];  const void* wq0_b  = d_in[7];
    const void* wk0_w  = d_in[8];  const void* wk0_b  = d_in[9];
    const void* wv0_w  = d_in[10]; const void* wv0_b  = d_in[11];
    const void* ln1_g  = d_in[12]; const void* ln1_b  = d_in[13];
    const void* wq1_w  = d_in[14]; const void* wq1_b  = d_in[15];
    const void* wk1_w  = d_in[16]; const void* wk1_b  = d_in[17];
    const void* wv1_w  = d_in[18]; const void* wv1_b  = d_in[19];
    const void* ln2_g  = d_in[20]; const void* ln2_b  = d_in[21];
    const void* gcn_w0 = d_in[22]; const void* gcn_b0 = d_in[23];
    const void* bn_g   = d_in[24]; const void* bn_b   = d_in[25];
    const void* gcn_w1 = d_in[26]; const void* gcn_b1 = d_in[27];
    const void* fc_w   = d_in[28]; const void* fc_b   = d_in[29];

    const size_t stN = (size_t)NN * DH * sizeof(ST);
    ST* H  = (ST*)(wsb);
    ST* Qb = (ST*)(wsb + stN);
    ST* Kb = (ST*)(wsb + 2 * stN);
    ST* Vb = (ST*)(wsb + 3 * stN);
    float* aux = (float*)(wsb + 4 * stN);
    float* kvs    = aux;
    float* ks_sum = aux + 65536;
    float* qss    = aux + 65792;
    float* kss    = aux + 65793;
    float* dinv   = aux + 65808;
    int*   flags  = (int*)(aux + 65808 + NN);
    int* cnt    = (int*)(aux + 65808 + NN + 16);
    int* base   = cnt + NN;
    int* cursor = base + NN;
    int* bsum   = cursor + NN;       // 512
    int* srcs   = bsum + 512;        // NE
    // dinv region (NN floats = 400KB) is dead until the GCN branch; borrow 128KB
    // of it for the bf16 copy of kvsT during the attention layers.
    unsigned short* kvsb = (unsigned short*)dinv;

    const int asel = (sizeof(ST) == 2) ? 1 : 0;
    dim3 mfmaGrid((NN + 127) / 128, DH / 64);
    const size_t NELEM = (size_t)NN * DH;

    detect_kernel<<<1, 256, 0, stream>>>(x, ei, flags);

    // ---- TransConv input layer ----
    gemm_mfma<ST><<<mfmaGrid, 512, 0, stream>>>(x, fc0_w, fc0_b, Qb, NN, DH, flags, 2);
    ln_kernel<ST><<<(NN + 3) / 4, 256, 0, stream>>>(Qb, (const ST*)nullptr, 1.f, 0.f, ln0_g, ln0_b, H, 1, flags);

    // ---- two attention layers ----
    for (int layer = 0; layer < 2; ++layer) {
        const void *qw, *qb, *kw, *kb, *vw, *vb, *lg, *lb;
        if (layer == 0) { qw = wq0_w; qb = wq0_b; kw = wk0_w; kb = wk0_b; vw = wv0_w; vb = wv0_b; lg = ln1_g; lb = ln1_b; }
        else            { qw = wq1_w; qb = wq1_b; kw = wk1_w; kb = wk1_b; vw = wv1_w; vb = wv1_b; lg = ln2_g; lb = ln2_b; }
        gemm_mfma<ST><<<mfmaGrid, 512, 0, stream>>>(H, qw, qb, Qb, NN, DH, flags, asel);
        gemm_mfma<ST><<<mfmaGrid, 512, 0, stream>>>(H, kw, kb, Kb, NN, DH, flags, asel);
        gemm_mfma<ST><<<mfmaGrid, 512, 0, stream>>>(H, vw, vb, Vb, NN, DH, flags, asel);
        hipMemsetAsync(aux, 0, (65536 + 256 + 2) * sizeof(float), stream);
        sumsq_kernel<ST><<<2048, 256, 0, stream>>>(Qb, NELEM, qss);
        sumsq_kernel<ST><<<2048, 256, 0, stream>>>(Kb, NELEM, kss);
        // kvs stored TRANSPOSED: kvs[j][i] = sum_n V[n][j] K[n][i]
        kvs_mfma<ST><<<dim3(4, 4, 64), 256, 0, stream>>>(Vb, Kb, kvs);
        colsum_kernel<ST><<<800, 256, 0, stream>>>(Kb, ks_sum);
        kvs2b_kernel<<<32, 256, 0, stream>>>(kvs, kvsb);
        attn_mfma<ST><<<dim3((NN + 63) / 64, 4), 256, 0, stream>>>(Qb, Vb, kvsb, ks_sum, qss, kss, Kb);
        ln_kernel<ST><<<(NN + 3) / 4, 256, 0, stream>>>(Kb, H, 0.5f, 0.5f, lg, lb, H, 0, flags);
    }

    // ---- GCN branch ----
    float* a1lo = (float*)(wsb + 2 * stN);
    float* a1hi = a1lo + NSO;
    ST* h2; float *a2lo, *a2hi;
    if (sizeof(ST) == 4) { h2 = Vb; a2lo = (float*)(wsb + 2 * stN); a2hi = a2lo + NSO; }
    else                 { h2 = Kb; a2lo = (float*)(wsb + stN);     a2hi = (float*)(wsb + 3 * stN); }

    if (use_csr) {
        hipMemsetAsync(cnt, 0, NN * sizeof(int), stream);
        count_kernel<<<(NE + 255) / 256, 256, 0, stream>>>(ei, cnt, flags);
        scan_block_kernel<<<NBLK, 256, 0, stream>>>(cnt, base, bsum);
        scan_partial_kernel<<<1, 512, 0, stream>>>(bsum, NBLK);
        finalize_kernel<<<NBLK, 256, 0, stream>>>(base, bsum, cnt, cursor, dinv);
        scatter_kernel<<<(NE + 255) / 256, 256, 0, stream>>>(ei, cursor, srcs, flags);

        gemm_mfma<ST><<<mfmaGrid, 512, 0, stream>>>(x, gcn_w0, nullptr, Qb, NN, DH, flags, 2);
        gather_kernel<ST><<<(NN + 3) / 4, 256, 0, stream>>>(Qb, base, cnt, srcs, dinv, a1lo, a1hi);
        gcn_epi1_kernel<ST><<<(NELEM + 255) / 256, 256, 0, stream>>>(a1lo, a1hi, Qb, dinv, gcn_b0, bn_g, bn_b, flags, Qb);

        gemm_mfma<ST><<<mfmaGrid, 512, 0, stream>>>(Qb, gcn_w1, nullptr, h2, NN, DH, flags, asel);
        gather_kernel<ST><<<(NN + 3) / 4, 256, 0, stream>>>(h2, base, cnt, srcs, dinv, a2lo, a2hi);
        gcn_epi2_kernel<ST><<<(NELEM + 255) / 256, 256, 0, stream>>>(a2lo, a2hi, h2, H, dinv, gcn_b1, flags, h2);
    } else {
        hipMemsetAsync(dinv, 0, NN * sizeof(float), stream);
        deg_kernel<<<(NE + 255) / 256, 256, 0, stream>>>(ei, dinv, flags);
        dinv_kernel<<<(NN + 255) / 256, 256, 0, stream>>>(dinv);

        gemm_mfma<ST><<<mfmaGrid, 512, 0, stream>>>(x, gcn_w0, nullptr, Qb, NN, DH, flags, 2);
        hipMemsetAsync(a1lo, 0, NELEM * sizeof(float), stream);
        agg_kernel<ST><<<(NE + 3) / 4, 256, 0, stream>>>(Qb, ei, dinv, a1lo, a1hi, flags);
        gcn_epi1_kernel<ST><<<(NELEM + 255) / 256, 256, 0, stream>>>(a1lo, a1hi, Qb, dinv, gcn_b0, bn_g, bn_b, flags, Qb);

        gemm_mfma<ST><<<mfmaGrid, 512, 0, stream>>>(Qb, gcn_w1, nullptr, h2, NN, DH, flags, asel);
        hipMemsetAsync(a2lo, 0, NSO * sizeof(float), stream);
        hipMemsetAsync(a2hi, 0, NSO * sizeof(float), stream);
        agg_kernel<ST><<<(NE + 3) / 4, 256, 0, stream>>>(h2, ei, dinv, a2lo, a2hi, flags);
        gcn_epi2_kernel<ST><<<(NELEM + 255) / 256, 256, 0, stream>>>(a2lo, a2hi, h2, H, dinv, gcn_b1, flags, h2);
    }

    // ---- classifier (f32 output) ----
    gemm_mfma<float><<<dim3((NN + 127) / 128, 1), 512, 0, stream>>>(h2, fc_w, fc_b, (float*)d_out, NN, DOUT, flags, asel);
}

extern "C" void kernel_launch(void* const* d_in, const int* in_sizes, int n_in,
                              void* d_out, int out_size, void* d_ws, size_t ws_size,
                              hipStream_t stream)
{
    char* wsb = (char*)d_ws;
    const size_t AUXF  = 65808 + NN + 16;
    const size_t CSRI  = 3 * (size_t)NN + 512 + NE;
    const size_t AUXB  = AUXF * sizeof(float);
    const size_t AUXB2 = AUXB + CSRI * sizeof(int);
    const size_t needA  = 4 * ((size_t)NN * DH * 4) + AUXB;
    const size_t needA2 = 4 * ((size_t)NN * DH * 4) + AUXB2;
    const size_t needB  = 4 * ((size_t)NN * DH * 2) + AUXB;
    const size_t needB2 = 4 * ((size_t)NN * DH * 2) + AUXB2;

    if (ws_size >= needA) {
        run_pipeline<float>(d_in, d_out, wsb, stream, ws_size >= needA2);
    } else if (ws_size >= needB) {
        run_pipeline<bf16>(d_in, d_out, wsb, stream, ws_size >= needB2);
    } else {
        float mb = (float)(ws_size >> 20);
        size_t n = (size_t)out_size;
        diag_kernel<<<(n + 255) / 256, 256, 0, stream>>>((float*)d_out, n, mb);
    }
}

// Round 5
// 1953.735 us; speedup vs baseline: 1.5149x; 1.0788x over previous
//
#include <hip/hip_runtime.h>
#include <hip/hip_bf16.h>

#define NN 100000
#define NE 800000
#define DH 256
#define DOUT 64
#define NSPL 50000                      // GCN agg row split
#define NSO ((size_t)NSPL * DH)        // elems per half
#define NBLK 391                       // ceil(NN/256)

using bf16 = __hip_bfloat16;
typedef __attribute__((ext_vector_type(8))) short bf16x8;
typedef __attribute__((ext_vector_type(4))) float f32x4;

// ---------------- dtype helpers ----------------
__device__ __forceinline__ float bits2f(unsigned short h) {
    union { unsigned int u; float f; } c; c.u = ((unsigned int)h) << 16; return c.f;
}
__device__ __forceinline__ unsigned short f2b(float v) {
    union { float f; unsigned int u; } c; c.f = v;
    unsigned int u = c.u;
    return (unsigned short)((u + 0x7FFFu + ((u >> 16) & 1u)) >> 16);  // RNE
}
__device__ __forceinline__ unsigned short tob(float v) { return f2b(v); }
__device__ __forceinline__ unsigned short tob(bf16 v) {
    union { bf16 b; unsigned short u; } c; c.b = v; return c.u;
}
__device__ __forceinline__ float ldf(const void* p, size_t i, int isbf) {
    if (isbf) return bits2f(((const unsigned short*)p)[i]);
    return ((const float*)p)[i];
}
__device__ __forceinline__ float ldS(const float* p, size_t i) { return p[i]; }
__device__ __forceinline__ float ldS(const bf16* p, size_t i) { return __bfloat162float(p[i]); }
__device__ __forceinline__ void stS(float* p, size_t i, float v) { p[i] = v; }
__device__ __forceinline__ void stS(bf16* p, size_t i, float v) { p[i] = __float2bfloat16(v); }
__device__ __forceinline__ float4 ld4S(const float* p) { return *(const float4*)p; }
__device__ __forceinline__ float4 ld4S(const bf16* p) {
    ushort4 u = *(const ushort4*)(const void*)p;
    return make_float4(bits2f(u.x), bits2f(u.y), bits2f(u.z), bits2f(u.w));
}
__device__ __forceinline__ void st4S(float* p, float4 v) { *(float4*)p = v; }
__device__ __forceinline__ void st4S(bf16* p, float4 v) {
    *(ushort4*)(void*)p = make_ushort4(f2b(v.x), f2b(v.y), f2b(v.z), f2b(v.w));
}
// load 8 consecutive elems (16B-aligned) as bf16 bit patterns from f32 or bf16 source
__device__ __forceinline__ void ld8(const void* p, size_t idx, int isbf, ushort4& o0, ushort4& o1) {
    if (isbf) {
        const ushort4* q = (const ushort4*)((const unsigned short*)p + idx);
        o0 = q[0]; o1 = q[1];
    } else {
        const float4* q = (const float4*)((const float*)p + idx);
        float4 a = q[0], b = q[1];
        o0 = make_ushort4(f2b(a.x), f2b(a.y), f2b(a.z), f2b(a.w));
        o1 = make_ushort4(f2b(b.x), f2b(b.y), f2b(b.z), f2b(b.w));
    }
}
__device__ __forceinline__ void ld8S(const bf16* p, size_t idx, ushort4& o0, ushort4& o1) {
    const ushort4* q = (const ushort4*)((const unsigned short*)p + idx);
    o0 = q[0]; o1 = q[1];
}
__device__ __forceinline__ void ld8S(const float* p, size_t idx, ushort4& o0, ushort4& o1) {
    const float4* q = (const float4*)(p + idx);
    float4 a = q[0], b = q[1];
    o0 = make_ushort4(f2b(a.x), f2b(a.y), f2b(a.z), f2b(a.w));
    o1 = make_ushort4(f2b(b.x), f2b(b.y), f2b(b.z), f2b(b.w));
}
__device__ __forceinline__ int ld_src(const int* ei, int e, int i64) {
    return i64 ? ei[2 * (size_t)e] : ei[e];
}
__device__ __forceinline__ int ld_dst(const int* ei, int e, int i64) {
    return i64 ? ei[2 * ((size_t)NE + e)] : ei[NE + e];
}

// ---------------- dtype detector (sampled) ----------------
__global__ __launch_bounds__(256) void detect_kernel(const void* x, const int* ei, int* flags)
{
    __shared__ int s_sane[4], s_nz[4];
    int t = threadIdx.x;
    const unsigned short* xu = (const unsigned short*)x;
    int sane = 0;
    for (int i = t; i < 2048; i += 256) {
        float v = bits2f(xu[2 * i]);
        float a = fabsf(v);
        if (v == v && a > 1e-3f && a < 100.f) sane++;
    }
    int nz = 0;
    for (int i = t; i < 4096; i += 256) {
        if (ei[2 * (i * 122) + 1] != 0) nz++;
    }
#pragma unroll
    for (int off = 32; off > 0; off >>= 1) { sane += __shfl_down(sane, off); nz += __shfl_down(nz, off); }
    if ((t & 63) == 0) { s_sane[t >> 6] = sane; s_nz[t >> 6] = nz; }
    __syncthreads();
    if (t == 0) {
        flags[0] = ((s_sane[0] + s_sane[1] + s_sane[2] + s_sane[3]) > 1024) ? 1 : 0;
        flags[1] = ((s_nz[0] + s_nz[1] + s_nz[2] + s_nz[3]) == 0) ? 1 : 0;
    }
}

// ---------------- MFMA GEMM: C[M,Nc] = A[M,256] @ W[256,Nc] (+bias) ----------------
// 512 threads / 128 rows per block: B (W^T) staged to LDS ONCE, A fragments read
// direct from global. Zero inner-loop barriers.
template <typename ST>
__global__ __launch_bounds__(512) void gemm_mfma(
    const void* __restrict__ A, const void* __restrict__ W,
    const void* __restrict__ bias, ST* __restrict__ C,
    int M, int Nc, const int* __restrict__ flags, int a_sel)
{
    __shared__ unsigned short Bs[64][264];   // W^T tile: Bs[n][k], all K
    const int isbf = flags[0];
    const int abf = (a_sel == 2) ? isbf : a_sel;
    const int tid = threadIdx.x;
    const int wave = tid >> 6, lane = tid & 63;
    const int quad = lane >> 4, nl = lane & 15;
    const int m0 = blockIdx.x * 128;
    const int n0 = blockIdx.y * 64;

#pragma unroll
    for (int it = 0; it < 4; ++it) {
        int p8 = it * 512 + tid;
        int k = p8 >> 3, nb = p8 & 7;
        ushort4 w0, w1;
        ld8(W, (size_t)k * Nc + n0 + nb * 8, isbf, w0, w1);
        int nbase = nb * 8;
        Bs[nbase + 0][k] = w0.x; Bs[nbase + 1][k] = w0.y;
        Bs[nbase + 2][k] = w0.z; Bs[nbase + 3][k] = w0.w;
        Bs[nbase + 4][k] = w1.x; Bs[nbase + 5][k] = w1.y;
        Bs[nbase + 6][k] = w1.z; Bs[nbase + 7][k] = w1.w;
    }
    __syncthreads();

    const int arow = m0 + wave * 16 + nl;         // A row this lane supplies
    const int av = (arow < M);
    const size_t abase = (size_t)arow * DH + quad * 8;
    f32x4 acc[4] = {{0.f,0.f,0.f,0.f},{0.f,0.f,0.f,0.f},{0.f,0.f,0.f,0.f},{0.f,0.f,0.f,0.f}};

#pragma unroll
    for (int k0 = 0; k0 < DH; k0 += 32) {
        ushort4 a0, a1;
        if (av) ld8(A, abase + k0, abf, a0, a1);
        else { a0 = make_ushort4(0,0,0,0); a1 = a0; }
        bf16x8 af;
        ((ushort4*)&af)[0] = a0; ((ushort4*)&af)[1] = a1;
#pragma unroll
        for (int ct = 0; ct < 4; ++ct) {
            bf16x8 bfg = *(const bf16x8*)&Bs[ct * 16 + nl][k0 + quad * 8];
            acc[ct] = __builtin_amdgcn_mfma_f32_16x16x32_bf16(af, bfg, acc[ct], 0, 0, 0);
        }
    }

#pragma unroll
    for (int ct = 0; ct < 4; ++ct) {
        int n = n0 + ct * 16 + nl;
        float bv = bias ? ldf(bias, n, isbf) : 0.f;
#pragma unroll
        for (int r = 0; r < 4; ++r) {
            int m = m0 + wave * 16 + quad * 4 + r;
            if (m < M) stS(C, (size_t)m * Nc + n, acc[ct][r] + bv);
        }
    }
}

// ---------------- MFMA kvs: D[256,256] = A^T @ B over N (split-N, atomic f32) ----------------
// call with (Vm, Km, kvs): D[j][i] = sum_n V[n][j]*K[n][i]  == kvs transposed, row-major
template <typename ST>
__global__ __launch_bounds__(256) void kvs_mfma(
    const ST* __restrict__ Am, const ST* __restrict__ Bm, float* __restrict__ D)
{
    __shared__ unsigned short Ast[64][36];
    __shared__ unsigned short Bst[64][36];
    const int tid = threadIdx.x;
    const int wave = tid >> 6, lane = tid & 63;
    const int quad = lane >> 4, nl = lane & 15;
    const int i0 = blockIdx.x * 64, j0 = blockIdx.y * 64;   // i0: D rows (A cols), j0: D cols (B cols)
    const int S = gridDim.z;
    const int chunk = (NN + S - 1) / S;
    const int ns = blockIdx.z * chunk;
    const int ne = min(ns + chunk, NN);
    const int nn = tid >> 3;          // row within 32-row chunk (0..31)
    const int c0 = (tid & 7) * 8;     // col offset within 64-col tile (0,8,...,56)
    f32x4 acc[4] = {{0.f,0.f,0.f,0.f},{0.f,0.f,0.f,0.f},{0.f,0.f,0.f,0.f},{0.f,0.f,0.f,0.f}};

    for (int n0 = ns; n0 < ne; n0 += 32) {
        int n = n0 + nn;
        ushort4 a0, a1, b0, b1;
        if (n < ne) {
            ld8S(Am, (size_t)n * DH + i0 + c0, a0, a1);
            ld8S(Bm, (size_t)n * DH + j0 + c0, b0, b1);
        } else {
            a0 = make_ushort4(0, 0, 0, 0); a1 = a0; b0 = a0; b1 = a0;
        }
        __syncthreads();   // previous chunk's frag reads done; loads above stay in flight
        Ast[c0 + 0][nn] = a0.x; Ast[c0 + 1][nn] = a0.y;
        Ast[c0 + 2][nn] = a0.z; Ast[c0 + 3][nn] = a0.w;
        Ast[c0 + 4][nn] = a1.x; Ast[c0 + 5][nn] = a1.y;
        Ast[c0 + 6][nn] = a1.z; Ast[c0 + 7][nn] = a1.w;
        Bst[c0 + 0][nn] = b0.x; Bst[c0 + 1][nn] = b0.y;
        Bst[c0 + 2][nn] = b0.z; Bst[c0 + 3][nn] = b0.w;
        Bst[c0 + 4][nn] = b1.x; Bst[c0 + 5][nn] = b1.y;
        Bst[c0 + 6][nn] = b1.z; Bst[c0 + 7][nn] = b1.w;
        __syncthreads();
        bf16x8 af = *(const bf16x8*)&Ast[wave * 16 + nl][quad * 8];
#pragma unroll
        for (int ct = 0; ct < 4; ++ct) {
            bf16x8 bfg = *(const bf16x8*)&Bst[ct * 16 + nl][quad * 8];
            acc[ct] = __builtin_amdgcn_mfma_f32_16x16x32_bf16(af, bfg, acc[ct], 0, 0, 0);
        }
    }
#pragma unroll
    for (int ct = 0; ct < 4; ++ct)
#pragma unroll
        for (int r = 0; r < 4; ++r)
            atomicAdd(&D[(size_t)(i0 + wave * 16 + quad * 4 + r) * DH + j0 + ct * 16 + nl], acc[ct][r]);
}

// ---------------- kvs f32 -> bf16 convert (once; attn re-reads it 1563x) ----------------
__global__ __launch_bounds__(256) void kvs2b_kernel(const float* __restrict__ kvs,
                                                    unsigned short* __restrict__ kvsb)
{
    int i = blockIdx.x * 256 + threadIdx.x;      // 8192 threads x 8 elems = 65536
    size_t o = (size_t)i * 8;
    float4 a = *(const float4*)(kvs + o);
    float4 b = *(const float4*)(kvs + o + 4);
    *(ushort4*)(kvsb + o)     = make_ushort4(f2b(a.x), f2b(a.y), f2b(a.z), f2b(a.w));
    *(ushort4*)(kvsb + o + 4) = make_ushort4(f2b(b.x), f2b(b.y), f2b(b.z), f2b(b.w));
}

// ---------------- MFMA attention: out = (Q@kvs*scale + N*V) / (Q.ks_sum*scale + N) ----------------
// kvsb: kvs transposed, bf16, row-major [256][256] (L2-resident, 128KB).
// Col-split: gridDim.y=2, each block does 64 rows x 128 cols -> acc[8] (32 VGPRs);
// Q logical re-read is 2x (L3-served) while occupancy stays ~6 waves/SIMD.
template <typename ST>
__global__ __launch_bounds__(256) void attn_mfma(
    const ST* __restrict__ Q, const ST* __restrict__ V,
    const unsigned short* __restrict__ kvsb, const float* __restrict__ ks_sum,
    const float* __restrict__ qss, const float* __restrict__ kss,
    ST* __restrict__ out)
{
    __shared__ float ks_s[DH];
    __shared__ float nrm_s[64];
    const int tid = threadIdx.x;
    const int wave = tid >> 6, lane = tid & 63;
    const int quad = lane >> 4, nl = lane & 15;
    const int m0 = blockIdx.x * 64;
    const int j0 = blockIdx.y * 128;

    ks_s[tid] = ks_sum[tid];
    __syncthreads();

    const int arow = m0 + wave * 16 + nl;
    const int av = (arow < NN);
    const size_t abase = (size_t)arow * DH + quad * 8;
    f32x4 acc[8];
#pragma unroll
    for (int i = 0; i < 8; ++i) acc[i] = (f32x4){0.f, 0.f, 0.f, 0.f};
    float nrm = 0.f;

#pragma unroll 2
    for (int k0 = 0; k0 < DH; k0 += 32) {
        ushort4 a0, a1;
        if (av) ld8S(Q, abase + k0, a0, a1);
        else { a0 = make_ushort4(0,0,0,0); a1 = a0; }
        bf16x8 af;
        ((ushort4*)&af)[0] = a0; ((ushort4*)&af)[1] = a1;
#pragma unroll
        for (int j = 0; j < 8; ++j)
            nrm += bits2f(((const unsigned short*)&af)[j]) * ks_s[k0 + quad * 8 + j];
        const unsigned short* kb = kvsb + (size_t)(j0 + nl) * DH + k0 + quad * 8;
#pragma unroll
        for (int ct = 0; ct < 8; ++ct) {
            bf16x8 bfg = *(const bf16x8*)(kb + (size_t)ct * 16 * DH);
            acc[ct] = __builtin_amdgcn_mfma_f32_16x16x32_bf16(af, bfg, acc[ct], 0, 0, 0);
        }
    }
    nrm += __shfl_xor(nrm, 16);
    nrm += __shfl_xor(nrm, 32);
    if (lane < 16) nrm_s[wave * 16 + lane] = nrm;
    __syncthreads();
    const float scale = rsqrtf(*qss) * rsqrtf(*kss);
#pragma unroll
    for (int r = 0; r < 4; ++r) {
        int row = m0 + wave * 16 + quad * 4 + r;
        if (row >= NN) continue;
        float den = nrm_s[wave * 16 + quad * 4 + r] * scale + (float)NN;
#pragma unroll
        for (int ct = 0; ct < 8; ++ct) {
            int col = j0 + ct * 16 + nl;
            float v = ldS(V, (size_t)row * DH + col);
            float numv = acc[ct][r] * scale + (float)NN * v;
            stS(out, (size_t)row * DH + col, numv / den);
        }
    }
}

// ---------------- LayerNorm over D=256: one wave per row, 4 rows/block ----------------
template <typename ST>
__global__ __launch_bounds__(256) void ln_kernel(
    const ST* __restrict__ A, const ST* __restrict__ B,
    float alpha, float beta,
    const void* __restrict__ g, const void* __restrict__ b,
    ST* __restrict__ out, int relu, const int* __restrict__ flags)
{
    const int isbf = flags[0];
    const int wave = threadIdx.x >> 6, lane = threadIdx.x & 63;
    const int row = blockIdx.x * 4 + wave;
    if (row >= NN) return;
    const size_t base = (size_t)row * DH + lane * 4;
    float4 v = ld4S(&A[base]);
    v.x *= alpha; v.y *= alpha; v.z *= alpha; v.w *= alpha;
    if (B) {
        float4 w = ld4S(&B[base]);
        v.x += beta * w.x; v.y += beta * w.y; v.z += beta * w.z; v.w += beta * w.w;
    }
    float s = v.x + v.y + v.z + v.w;
    float s2 = v.x * v.x + v.y * v.y + v.z * v.z + v.w * v.w;
#pragma unroll
    for (int off = 32; off > 0; off >>= 1) {
        s += __shfl_xor(s, off);
        s2 += __shfl_xor(s2, off);
    }
    float mean = s * (1.f / DH);
    float var = s2 * (1.f / DH) - mean * mean;
    float rstd = rsqrtf(var + 1e-5f);
    float4 o;
    o.x = (v.x - mean) * rstd * ldf(g, lane * 4 + 0, isbf) + ldf(b, lane * 4 + 0, isbf);
    o.y = (v.y - mean) * rstd * ldf(g, lane * 4 + 1, isbf) + ldf(b, lane * 4 + 1, isbf);
    o.z = (v.z - mean) * rstd * ldf(g, lane * 4 + 2, isbf) + ldf(b, lane * 4 + 2, isbf);
    o.w = (v.w - mean) * rstd * ldf(g, lane * 4 + 3, isbf) + ldf(b, lane * 4 + 3, isbf);
    if (relu) {
        o.x = fmaxf(o.x, 0.f); o.y = fmaxf(o.y, 0.f);
        o.z = fmaxf(o.z, 0.f); o.w = fmaxf(o.w, 0.f);
    }
    st4S(&out[base], o);
}

// ---------------- sum of squares ----------------
template <typename ST>
__global__ __launch_bounds__(256) void sumsq_kernel(
    const ST* __restrict__ A, size_t n, float* __restrict__ out)
{
    __shared__ float ps[4];
    size_t i = (size_t)blockIdx.x * blockDim.x + threadIdx.x;
    size_t stride = (size_t)gridDim.x * blockDim.x;
    float s = 0.f;
    for (; i < n; i += stride) { float v = ldS(A, i); s += v * v; }
#pragma unroll
    for (int off = 32; off > 0; off >>= 1) s += __shfl_down(s, off);
    if ((threadIdx.x & 63) == 0) ps[threadIdx.x >> 6] = s;
    __syncthreads();
    if (threadIdx.x == 0) atomicAdd(out, ps[0] + ps[1] + ps[2] + ps[3]);
}

// ---------------- ks_sum[j] = sum_n K[n][j] (rows-per-block from gridDim) ----------------
template <typename ST>
__global__ __launch_bounds__(256) void colsum_kernel(
    const ST* __restrict__ Km, float* __restrict__ out)
{
    const int t = threadIdx.x;
    const int per = (NN + gridDim.x - 1) / gridDim.x;
    size_t r0 = (size_t)blockIdx.x * per;
    size_t r1 = r0 + per; if (r1 > NN) r1 = NN;
    float s = 0.f;
    for (size_t r = r0; r < r1; ++r) s += ldS(Km, r * DH + t);
    atomicAdd(&out[t], s);
}

// ---------------- CSR build ----------------
__global__ __launch_bounds__(256) void count_kernel(const int* __restrict__ ei, int* __restrict__ cnt,
                                                    const int* __restrict__ flags)
{
    int e = blockIdx.x * 256 + threadIdx.x;
    if (e >= NE) return;
    int d = ld_dst(ei, e, flags[1]);
    if ((unsigned)d < NN) atomicAdd(&cnt[d], 1);
}

__global__ __launch_bounds__(256) void scan_block_kernel(const int* __restrict__ cnt,
                                                         int* __restrict__ pre, int* __restrict__ bsum)
{
    __shared__ int s[256];
    int i = blockIdx.x * 256 + threadIdx.x;
    int v = (i < NN) ? cnt[i] : 0;
    s[threadIdx.x] = v;
    __syncthreads();
    for (int off = 1; off < 256; off <<= 1) {
        int t = (threadIdx.x >= off) ? s[threadIdx.x - off] : 0;
        __syncthreads();
        s[threadIdx.x] += t;
        __syncthreads();
    }
    if (i < NN) pre[i] = s[threadIdx.x] - v;
    if (threadIdx.x == 255) bsum[blockIdx.x] = s[255];
}

__global__ __launch_bounds__(512) void scan_partial_kernel(int* __restrict__ bsum, int nb)
{
    __shared__ int s[512];
    int t = threadIdx.x;
    int v = (t < nb) ? bsum[t] : 0;
    s[t] = v;
    __syncthreads();
    for (int off = 1; off < 512; off <<= 1) {
        int u = (t >= off) ? s[t - off] : 0;
        __syncthreads();
        s[t] += u;
        __syncthreads();
    }
    if (t < nb) bsum[t] = s[t] - v;
}

__global__ __launch_bounds__(256) void finalize_kernel(int* __restrict__ base, const int* __restrict__ bsum,
                                                       const int* __restrict__ cnt, int* __restrict__ cursor,
                                                       float* __restrict__ dinv)
{
    int i = blockIdx.x * 256 + threadIdx.x;
    if (i >= NN) return;
    int b = base[i] + bsum[blockIdx.x];
    base[i] = b;
    cursor[i] = b;
    dinv[i] = rsqrtf((float)cnt[i] + 1.0f);
}

__global__ __launch_bounds__(256) void scatter_kernel(const int* __restrict__ ei, int* __restrict__ cursor,
                                                      int* __restrict__ srcs, const int* __restrict__ flags)
{
    int e = blockIdx.x * 256 + threadIdx.x;
    if (e >= NE) return;
    int i64 = flags[1];
    int s = ld_src(ei, e, i64), d = ld_dst(ei, e, i64);
    if ((unsigned)s >= NN || (unsigned)d >= NN) return;
    int pos = atomicAdd(&cursor[d], 1);
    srcs[pos] = s;
}

// ---------------- FUSED CSR gather + GCN epilogue: one wave per node ----------------
// MODE 0: out = relu((agg + own*di^2 + b) * bn_g/sqrt(1+eps) + bn_b)
// MODE 1: out = 0.8*(agg + own*di^2 + b) + 0.2*Ht
template <typename ST, int MODE>
__global__ __launch_bounds__(256) void fgather_kernel(
    const ST* __restrict__ Hs, const ST* __restrict__ Ht,
    const int* __restrict__ base, const int* __restrict__ cnt,
    const int* __restrict__ srcs, const float* __restrict__ dinv,
    const void* __restrict__ bias, const void* __restrict__ bng, const void* __restrict__ bnb,
    const int* __restrict__ flags, ST* __restrict__ out)
{
    const int isbf = flags[0];
    int node = blockIdx.x * 4 + (threadIdx.x >> 6);
    int lane = threadIdx.x & 63;
    if (node >= NN) return;
    int b0 = base[node], deg = cnt[node];
    float dd = dinv[node];
    float4 a0 = make_float4(0.f, 0.f, 0.f, 0.f);
    float4 a1 = make_float4(0.f, 0.f, 0.f, 0.f);
    int j = 0;
    for (; j + 2 <= deg; j += 2) {          // 2-way unroll: two row-loads in flight
        int s0 = srcs[b0 + j], s1 = srcs[b0 + j + 1];
        float n0 = dd * dinv[s0], n1 = dd * dinv[s1];
        float4 h0 = ld4S(&Hs[(size_t)s0 * DH + lane * 4]);
        float4 h1 = ld4S(&Hs[(size_t)s1 * DH + lane * 4]);
        a0.x += h0.x * n0; a0.y += h0.y * n0; a0.z += h0.z * n0; a0.w += h0.w * n0;
        a1.x += h1.x * n1; a1.y += h1.y * n1; a1.z += h1.z * n1; a1.w += h1.w * n1;
    }
    if (j < deg) {
        int s0 = srcs[b0 + j];
        float n0 = dd * dinv[s0];
        float4 h0 = ld4S(&Hs[(size_t)s0 * DH + lane * 4]);
        a0.x += h0.x * n0; a0.y += h0.y * n0; a0.z += h0.z * n0; a0.w += h0.w * n0;
    }
    const size_t obase = (size_t)node * DH + lane * 4;
    float4 own = ld4S(&Hs[obase]);
    float di2 = dd * dd;
    int c = lane * 4;
    float4 v;
    v.x = a0.x + a1.x + own.x * di2 + ldf(bias, c + 0, isbf);
    v.y = a0.y + a1.y + own.y * di2 + ldf(bias, c + 1, isbf);
    v.z = a0.z + a1.z + own.z * di2 + ldf(bias, c + 2, isbf);
    v.w = a0.w + a1.w + own.w * di2 + ldf(bias, c + 3, isbf);
    if (MODE == 0) {
        const float bnscale = 0.99999500003749981f;  // 1/sqrt(1+1e-5)
        v.x = fmaxf(v.x * (ldf(bng, c + 0, isbf) * bnscale) + ldf(bnb, c + 0, isbf), 0.f);
        v.y = fmaxf(v.y * (ldf(bng, c + 1, isbf) * bnscale) + ldf(bnb, c + 1, isbf), 0.f);
        v.z = fmaxf(v.z * (ldf(bng, c + 2, isbf) * bnscale) + ldf(bnb, c + 2, isbf), 0.f);
        v.w = fmaxf(v.w * (ldf(bng, c + 3, isbf) * bnscale) + ldf(bnb, c + 3, isbf), 0.f);
    } else {
        float4 t = ld4S(&Ht[obase]);
        v.x = 0.8f * v.x + 0.2f * t.x;
        v.y = 0.8f * v.y + 0.2f * t.y;
        v.z = 0.8f * v.z + 0.2f * t.z;
        v.w = 0.8f * v.w + 0.2f * t.w;
    }
    st4S(&out[obase], v);
}

// ---------------- fallback (atomic) GCN pieces ----------------
__global__ __launch_bounds__(256) void deg_kernel(const int* __restrict__ ei, float* __restrict__ deg,
                                                  const int* __restrict__ flags)
{
    int i64 = flags[1];
    int e = blockIdx.x * 256 + threadIdx.x;
    if (e >= NE) return;
    int d = ld_dst(ei, e, i64);
    if ((unsigned)d < NN) atomicAdd(&deg[d], 1.0f);
}

__global__ __launch_bounds__(256) void dinv_kernel(float* __restrict__ deg)
{
    int i = blockIdx.x * 256 + threadIdx.x;
    if (i < NN) deg[i] = rsqrtf(deg[i] + 1.0f);
}

template <typename ST>
__global__ __launch_bounds__(256) void agg_kernel(
    const ST* __restrict__ Hs, const int* __restrict__ ei,
    const float* __restrict__ dinv, float* __restrict__ lo, float* __restrict__ hi,
    const int* __restrict__ flags)
{
    int i64 = flags[1];
    int e = blockIdx.x * 4 + (threadIdx.x >> 6);
    int lane = threadIdx.x & 63;
    if (e >= NE) return;
    int s = ld_src(ei, e, i64), d = ld_dst(ei, e, i64);
    if ((unsigned)s >= NN || (unsigned)d >= NN) return;
    float nrm = dinv[s] * dinv[d];
    const float4 h4 = ld4S(&Hs[(size_t)s * DH + lane * 4]);
    float* o = (d < NSPL ? &lo[(size_t)d * DH] : &hi[(size_t)(d - NSPL) * DH]) + lane * 4;
    atomicAdd(o + 0, h4.x * nrm);
    atomicAdd(o + 1, h4.y * nrm);
    atomicAdd(o + 2, h4.z * nrm);
    atomicAdd(o + 3, h4.w * nrm);
}

// self-loop + bias + BN(eval) + relu
template <typename ST>
__global__ __launch_bounds__(256) void gcn_epi1_kernel(
    const float* __restrict__ lo, const float* __restrict__ hi,
    const ST* __restrict__ h1, const float* __restrict__ dinv,
    const void* __restrict__ b0, const void* __restrict__ bng, const void* __restrict__ bnb,
    const int* __restrict__ flags, ST* __restrict__ out)
{
    const int isbf = flags[0];
    size_t idx = (size_t)blockIdx.x * 256 + threadIdx.x;
    if (idx >= (size_t)NN * DH) return;
    int i = (int)(idx >> 8), c = (int)(idx & 255);
    float aggv = (i < NSPL) ? lo[idx] : hi[idx - NSO];
    float di = dinv[i];
    float v = aggv + ldS(h1, idx) * di * di + ldf(b0, c, isbf);
    const float bnscale = 0.99999500003749981f;  // 1/sqrt(1+1e-5)
    v = v * (ldf(bng, c, isbf) * bnscale) + ldf(bnb, c, isbf);
    stS(out, idx, fmaxf(v, 0.f));
}

// self-loop + bias + combine: emb = 0.8*(agg + self + b1) + 0.2*x_trans
template <typename ST>
__global__ __launch_bounds__(256) void gcn_epi2_kernel(
    const float* __restrict__ lo, const float* __restrict__ hi,
    const ST* __restrict__ h2, const ST* __restrict__ Ht, const float* __restrict__ dinv,
    const void* __restrict__ b1, const int* __restrict__ flags, ST* __restrict__ out)
{
    const int isbf = flags[0];
    size_t idx = (size_t)blockIdx.x * 256 + threadIdx.x;
    if (idx >= (size_t)NN * DH) return;
    int i = (int)(idx >> 8), c = (int)(idx & 255);
    float aggv = (i < NSPL) ? lo[idx] : hi[idx - NSO];
    float di = dinv[i];
    float g = aggv + ldS(h2, idx) * di * di + ldf(b1, c, isbf);
    stS(out, idx, 0.8f * g + 0.2f * ldS(Ht, idx));
}

// ---------------- diagnostic ----------------
__global__ __launch_bounds__(256) void diag_kernel(float* out, size_t n, float val)
{
    size_t i = (size_t)blockIdx.x * 256 + threadIdx.x;
    if (i < n) out[i] = val;
}

// ---------------- pipeline ----------------
template <typename ST>
static void run_pipeline(void* const* d_in, void* d_out, char* wsb, hipStream_t stream, int use_csr)
{
    const void* x      = d_in[0];
    const int*  ei     = (const int*)d_in[1];
    const void* fc0_w  = d_in[2];  const void* fc0_b  = d_in[3];
    const void* ln0_g  = d_in[4];  const void* ln0_b  = d_in[5];
    const void* wq0_w  = d_in[6];  const void* wq0_b  = d_in[7];
    const void* wk0_w  = d_in[8];  const void* wk0_b  = d_in[9];
    const void* wv0_w  = d_in[10]; const void* wv0_b  = d_in[11];
    const void* ln1_g  = d_in[12]; const void* ln1_b  = d_in[13];
    const void* wq1_w  = d_in[14]; const void* wq1_b  = d_in[15];
    const void* wk1_w  = d_in[16]; const void* wk1_b  = d_in[17];
    const void* wv1_w  = d_in[18]; const void* wv1_b  = d_in[19];
    const void* ln2_g  = d_in[20]; const void* ln2_b  = d_in[21];
    const void* gcn_w0 = d_in[22]; const void* gcn_b0 = d_in[23];
    const void* bn_g   = d_in[24]; const void* bn_b   = d_in[25];
    const void* gcn_w1 = d_in[26]; const void* gcn_b1 = d_in[27];
    const void* fc_w   = d_in[28]; const void* fc_b   = d_in[29];

    const size_t stN = (size_t)NN * DH * sizeof(ST);
    ST* H  = (ST*)(wsb);
    ST* Qb = (ST*)(wsb + stN);
    ST* Kb = (ST*)(wsb + 2 * stN);
    ST* Vb = (ST*)(wsb + 3 * stN);
    float* aux = (float*)(wsb + 4 * stN);
    float* kvs    = aux;
    float* ks_sum = aux + 65536;
    float* qss    = aux + 65792;
    float* kss    = aux + 65793;
    float* dinv   = aux + 65808;
    int*   flags  = (int*)(aux + 65808 + NN);
    int* cnt    = (int*)(aux + 65808 + NN + 16);
    int* base   = cnt + NN;
    int* cursor = base + NN;
    int* bsum   = cursor + NN;       // 512
    int* srcs   = bsum + 512;        // NE
    // dinv region (NN floats = 400KB) is dead until the GCN branch; borrow 128KB
    // of it for the bf16 copy of kvsT during the attention layers.
    unsigned short* kvsb = (unsigned short*)dinv;

    const int asel = (sizeof(ST) == 2) ? 1 : 0;
    dim3 mfmaGrid((NN + 127) / 128, DH / 64);
    const size_t NELEM = (size_t)NN * DH;

    detect_kernel<<<1, 256, 0, stream>>>(x, ei, flags);

    // ---- TransConv input layer ----
    gemm_mfma<ST><<<mfmaGrid, 512, 0, stream>>>(x, fc0_w, fc0_b, Qb, NN, DH, flags, 2);
    ln_kernel<ST><<<(NN + 3) / 4, 256, 0, stream>>>(Qb, (const ST*)nullptr, 1.f, 0.f, ln0_g, ln0_b, H, 1, flags);

    // ---- two attention layers ----
    for (int layer = 0; layer < 2; ++layer) {
        const void *qw, *qb, *kw, *kb, *vw, *vb, *lg, *lb;
        if (layer == 0) { qw = wq0_w; qb = wq0_b; kw = wk0_w; kb = wk0_b; vw = wv0_w; vb = wv0_b; lg = ln1_g; lb = ln1_b; }
        else            { qw = wq1_w; qb = wq1_b; kw = wk1_w; kb = wk1_b; vw = wv1_w; vb = wv1_b; lg = ln2_g; lb = ln2_b; }
        gemm_mfma<ST><<<mfmaGrid, 512, 0, stream>>>(H, qw, qb, Qb, NN, DH, flags, asel);
        gemm_mfma<ST><<<mfmaGrid, 512, 0, stream>>>(H, kw, kb, Kb, NN, DH, flags, asel);
        gemm_mfma<ST><<<mfmaGrid, 512, 0, stream>>>(H, vw, vb, Vb, NN, DH, flags, asel);
        hipMemsetAsync(aux, 0, (65536 + 256 + 2) * sizeof(float), stream);
        sumsq_kernel<ST><<<2048, 256, 0, stream>>>(Qb, NELEM, qss);
        sumsq_kernel<ST><<<2048, 256, 0, stream>>>(Kb, NELEM, kss);
        // kvs stored TRANSPOSED: kvs[j][i] = sum_n V[n][j] K[n][i]
        kvs_mfma<ST><<<dim3(4, 4, 64), 256, 0, stream>>>(Vb, Kb, kvs);
        colsum_kernel<ST><<<800, 256, 0, stream>>>(Kb, ks_sum);
        kvs2b_kernel<<<32, 256, 0, stream>>>(kvs, kvsb);
        attn_mfma<ST><<<dim3((NN + 63) / 64, 2), 256, 0, stream>>>(Qb, Vb, kvsb, ks_sum, qss, kss, Kb);
        ln_kernel<ST><<<(NN + 3) / 4, 256, 0, stream>>>(Kb, H, 0.5f, 0.5f, lg, lb, H, 0, flags);
    }

    // ---- GCN branch ----
    if (use_csr) {
        hipMemsetAsync(cnt, 0, NN * sizeof(int), stream);
        count_kernel<<<(NE + 255) / 256, 256, 0, stream>>>(ei, cnt, flags);
        scan_block_kernel<<<NBLK, 256, 0, stream>>>(cnt, base, bsum);
        scan_partial_kernel<<<1, 512, 0, stream>>>(bsum, NBLK);
        finalize_kernel<<<NBLK, 256, 0, stream>>>(base, bsum, cnt, cursor, dinv);
        scatter_kernel<<<(NE + 255) / 256, 256, 0, stream>>>(ei, cursor, srcs, flags);

        // fused path: h1 -> Qb; fused gather+BN+relu -> Kb; h2 -> Vb;
        // fused gather+combine -> Qb (emb); classifier reads Qb.
        gemm_mfma<ST><<<mfmaGrid, 512, 0, stream>>>(x, gcn_w0, nullptr, Qb, NN, DH, flags, 2);
        fgather_kernel<ST, 0><<<(NN + 3) / 4, 256, 0, stream>>>(
            Qb, (const ST*)nullptr, base, cnt, srcs, dinv, gcn_b0, bn_g, bn_b, flags, Kb);
        gemm_mfma<ST><<<mfmaGrid, 512, 0, stream>>>(Kb, gcn_w1, nullptr, Vb, NN, DH, flags, asel);
        fgather_kernel<ST, 1><<<(NN + 3) / 4, 256, 0, stream>>>(
            Vb, H, base, cnt, srcs, dinv, gcn_b1, nullptr, nullptr, flags, Qb);

        gemm_mfma<float><<<dim3((NN + 127) / 128, 1), 512, 0, stream>>>(Qb, fc_w, fc_b, (float*)d_out, NN, DOUT, flags, asel);
    } else {
        float* a1lo = (float*)(wsb + 2 * stN);
        float* a1hi = a1lo + NSO;
        ST* h2; float *a2lo, *a2hi;
        if (sizeof(ST) == 4) { h2 = Vb; a2lo = (float*)(wsb + 2 * stN); a2hi = a2lo + NSO; }
        else                 { h2 = Kb; a2lo = (float*)(wsb + stN);     a2hi = (float*)(wsb + 3 * stN); }

        hipMemsetAsync(dinv, 0, NN * sizeof(float), stream);
        deg_kernel<<<(NE + 255) / 256, 256, 0, stream>>>(ei, dinv, flags);
        dinv_kernel<<<(NN + 255) / 256, 256, 0, stream>>>(dinv);

        gemm_mfma<ST><<<mfmaGrid, 512, 0, stream>>>(x, gcn_w0, nullptr, Qb, NN, DH, flags, 2);
        hipMemsetAsync(a1lo, 0, NELEM * sizeof(float), stream);
        agg_kernel<ST><<<(NE + 3) / 4, 256, 0, stream>>>(Qb, ei, dinv, a1lo, a1hi, flags);
        gcn_epi1_kernel<ST><<<(NELEM + 255) / 256, 256, 0, stream>>>(a1lo, a1hi, Qb, dinv, gcn_b0, bn_g, bn_b, flags, Qb);

        gemm_mfma<ST><<<mfmaGrid, 512, 0, stream>>>(Qb, gcn_w1, nullptr, h2, NN, DH, flags, asel);
        hipMemsetAsync(a2lo, 0, NSO * sizeof(float), stream);
        hipMemsetAsync(a2hi, 0, NSO * sizeof(float), stream);
        agg_kernel<ST><<<(NE + 3) / 4, 256, 0, stream>>>(h2, ei, dinv, a2lo, a2hi, flags);
        gcn_epi2_kernel<ST><<<(NELEM + 255) / 256, 256, 0, stream>>>(a2lo, a2hi, h2, H, dinv, gcn_b1, flags, h2);

        gemm_mfma<float><<<dim3((NN + 127) / 128, 1), 512, 0, stream>>>(h2, fc_w, fc_b, (float*)d_out, NN, DOUT, flags, asel);
    }
}

extern "C" void kernel_launch(void* const* d_in, const int* in_sizes, int n_in,
                              void* d_out, int out_size, void* d_ws, size_t ws_size,
                              hipStream_t stream)
{
    char* wsb = (char*)d_ws;
    const size_t AUXF  = 65808 + NN + 16;
    const size_t CSRI  = 3 * (size_t)NN + 512 + NE;
    const size_t AUXB  = AUXF * sizeof(float);
    const size_t AUXB2 = AUXB + CSRI * sizeof(int);
    const size_t needA  = 4 * ((size_t)NN * DH * 4) + AUXB;
    const size_t needA2 = 4 * ((size_t)NN * DH * 4) + AUXB2;
    const size_t needB  = 4 * ((size_t)NN * DH * 2) + AUXB;
    const size_t needB2 = 4 * ((size_t)NN * DH * 2) + AUXB2;

    if (ws_size >= needA) {
        run_pipeline<float>(d_in, d_out, wsb, stream, ws_size >= needA2);
    } else if (ws_size >= needB) {
        run_pipeline<bf16>(d_in, d_out, wsb, stream, ws_size >= needB2);
    } else {
        float mb = (float)(ws_size >> 20);
        size_t n = (size_t)out_size;
        diag_kernel<<<(n + 255) / 256, 256, 0, stream>>>((float*)d_out, n, mb);
    }
}

// Round 6
// 1941.826 us; speedup vs baseline: 1.5242x; 1.0061x over previous
//
#include <hip/hip_runtime.h>
#include <hip/hip_bf16.h>

#define NN 100000
#define NE 800000
#define DH 256
#define DOUT 64
#define NSPL 50000                      // GCN agg row split
#define NSO ((size_t)NSPL * DH)        // elems per half
#define NBLK 391                       // ceil(NN/256)

using bf16 = __hip_bfloat16;
typedef __attribute__((ext_vector_type(8))) short bf16x8;
typedef __attribute__((ext_vector_type(4))) float f32x4;

// ---------------- dtype helpers ----------------
__device__ __forceinline__ float bits2f(unsigned short h) {
    union { unsigned int u; float f; } c; c.u = ((unsigned int)h) << 16; return c.f;
}
__device__ __forceinline__ unsigned short f2b(float v) {
    union { float f; unsigned int u; } c; c.f = v;
    unsigned int u = c.u;
    return (unsigned short)((u + 0x7FFFu + ((u >> 16) & 1u)) >> 16);  // RNE
}
__device__ __forceinline__ unsigned short tob(float v) { return f2b(v); }
__device__ __forceinline__ unsigned short tob(bf16 v) {
    union { bf16 b; unsigned short u; } c; c.b = v; return c.u;
}
__device__ __forceinline__ float ldf(const void* p, size_t i, int isbf) {
    if (isbf) return bits2f(((const unsigned short*)p)[i]);
    return ((const float*)p)[i];
}
__device__ __forceinline__ float ldS(const float* p, size_t i) { return p[i]; }
__device__ __forceinline__ float ldS(const bf16* p, size_t i) { return __bfloat162float(p[i]); }
__device__ __forceinline__ void stS(float* p, size_t i, float v) { p[i] = v; }
__device__ __forceinline__ void stS(bf16* p, size_t i, float v) { p[i] = __float2bfloat16(v); }
__device__ __forceinline__ float4 ld4S(const float* p) { return *(const float4*)p; }
__device__ __forceinline__ float4 ld4S(const bf16* p) {
    ushort4 u = *(const ushort4*)(const void*)p;
    return make_float4(bits2f(u.x), bits2f(u.y), bits2f(u.z), bits2f(u.w));
}
__device__ __forceinline__ void st4S(float* p, float4 v) { *(float4*)p = v; }
__device__ __forceinline__ void st4S(bf16* p, float4 v) {
    *(ushort4*)(void*)p = make_ushort4(f2b(v.x), f2b(v.y), f2b(v.z), f2b(v.w));
}
// load 8 consecutive elems (16B-aligned) as bf16 bit patterns from f32 or bf16 source
__device__ __forceinline__ void ld8(const void* p, size_t idx, int isbf, ushort4& o0, ushort4& o1) {
    if (isbf) {
        const ushort4* q = (const ushort4*)((const unsigned short*)p + idx);
        o0 = q[0]; o1 = q[1];
    } else {
        const float4* q = (const float4*)((const float*)p + idx);
        float4 a = q[0], b = q[1];
        o0 = make_ushort4(f2b(a.x), f2b(a.y), f2b(a.z), f2b(a.w));
        o1 = make_ushort4(f2b(b.x), f2b(b.y), f2b(b.z), f2b(b.w));
    }
}
__device__ __forceinline__ void ld8S(const bf16* p, size_t idx, ushort4& o0, ushort4& o1) {
    const ushort4* q = (const ushort4*)((const unsigned short*)p + idx);
    o0 = q[0]; o1 = q[1];
}
__device__ __forceinline__ void ld8S(const float* p, size_t idx, ushort4& o0, ushort4& o1) {
    const float4* q = (const float4*)(p + idx);
    float4 a = q[0], b = q[1];
    o0 = make_ushort4(f2b(a.x), f2b(a.y), f2b(a.z), f2b(a.w));
    o1 = make_ushort4(f2b(b.x), f2b(b.y), f2b(b.z), f2b(b.w));
}
__device__ __forceinline__ int ld_src(const int* ei, int e, int i64) {
    return i64 ? ei[2 * (size_t)e] : ei[e];
}
__device__ __forceinline__ int ld_dst(const int* ei, int e, int i64) {
    return i64 ? ei[2 * ((size_t)NE + e)] : ei[NE + e];
}

// ---------------- dtype detector (sampled) ----------------
__global__ __launch_bounds__(256) void detect_kernel(const void* x, const int* ei, int* flags)
{
    __shared__ int s_sane[4], s_nz[4];
    int t = threadIdx.x;
    const unsigned short* xu = (const unsigned short*)x;
    int sane = 0;
    for (int i = t; i < 2048; i += 256) {
        float v = bits2f(xu[2 * i]);
        float a = fabsf(v);
        if (v == v && a > 1e-3f && a < 100.f) sane++;
    }
    int nz = 0;
    for (int i = t; i < 4096; i += 256) {
        if (ei[2 * (i * 122) + 1] != 0) nz++;
    }
#pragma unroll
    for (int off = 32; off > 0; off >>= 1) { sane += __shfl_down(sane, off); nz += __shfl_down(nz, off); }
    if ((t & 63) == 0) { s_sane[t >> 6] = sane; s_nz[t >> 6] = nz; }
    __syncthreads();
    if (t == 0) {
        flags[0] = ((s_sane[0] + s_sane[1] + s_sane[2] + s_sane[3]) > 1024) ? 1 : 0;
        flags[1] = ((s_nz[0] + s_nz[1] + s_nz[2] + s_nz[3]) == 0) ? 1 : 0;
    }
}

// ---------------- MFMA GEMM: C[M,Nc] = A[M,256] @ W[256,Nc] (+bias) ----------------
// 512 threads / 128 rows per block: B (W^T) staged to LDS ONCE, A fragments read
// direct from global. Zero inner-loop barriers.
template <typename ST>
__global__ __launch_bounds__(512) void gemm_mfma(
    const void* __restrict__ A, const void* __restrict__ W,
    const void* __restrict__ bias, ST* __restrict__ C,
    int M, int Nc, const int* __restrict__ flags, int a_sel)
{
    __shared__ unsigned short Bs[64][264];   // W^T tile: Bs[n][k], all K
    const int isbf = flags[0];
    const int abf = (a_sel == 2) ? isbf : a_sel;
    const int tid = threadIdx.x;
    const int wave = tid >> 6, lane = tid & 63;
    const int quad = lane >> 4, nl = lane & 15;
    const int m0 = blockIdx.x * 128;
    const int n0 = blockIdx.y * 64;

#pragma unroll
    for (int it = 0; it < 4; ++it) {
        int p8 = it * 512 + tid;
        int k = p8 >> 3, nb = p8 & 7;
        ushort4 w0, w1;
        ld8(W, (size_t)k * Nc + n0 + nb * 8, isbf, w0, w1);
        int nbase = nb * 8;
        Bs[nbase + 0][k] = w0.x; Bs[nbase + 1][k] = w0.y;
        Bs[nbase + 2][k] = w0.z; Bs[nbase + 3][k] = w0.w;
        Bs[nbase + 4][k] = w1.x; Bs[nbase + 5][k] = w1.y;
        Bs[nbase + 6][k] = w1.z; Bs[nbase + 7][k] = w1.w;
    }
    __syncthreads();

    const int arow = m0 + wave * 16 + nl;         // A row this lane supplies
    const int av = (arow < M);
    const size_t abase = (size_t)arow * DH + quad * 8;
    f32x4 acc[4] = {{0.f,0.f,0.f,0.f},{0.f,0.f,0.f,0.f},{0.f,0.f,0.f,0.f},{0.f,0.f,0.f,0.f}};

#pragma unroll
    for (int k0 = 0; k0 < DH; k0 += 32) {
        ushort4 a0, a1;
        if (av) ld8(A, abase + k0, abf, a0, a1);
        else { a0 = make_ushort4(0,0,0,0); a1 = a0; }
        bf16x8 af;
        ((ushort4*)&af)[0] = a0; ((ushort4*)&af)[1] = a1;
#pragma unroll
        for (int ct = 0; ct < 4; ++ct) {
            bf16x8 bfg = *(const bf16x8*)&Bs[ct * 16 + nl][k0 + quad * 8];
            acc[ct] = __builtin_amdgcn_mfma_f32_16x16x32_bf16(af, bfg, acc[ct], 0, 0, 0);
        }
    }

#pragma unroll
    for (int ct = 0; ct < 4; ++ct) {
        int n = n0 + ct * 16 + nl;
        float bv = bias ? ldf(bias, n, isbf) : 0.f;
#pragma unroll
        for (int r = 0; r < 4; ++r) {
            int m = m0 + wave * 16 + quad * 4 + r;
            if (m < M) stS(C, (size_t)m * Nc + n, acc[ct][r] + bv);
        }
    }
}

// ---------------- MFMA kvs: D[256,256] = A^T @ B over N (split-N, atomic f32) ----------------
// call with (Vm, Km, kvs): D[j][i] = sum_n V[n][j]*K[n][i]  == kvs transposed, row-major
template <typename ST>
__global__ __launch_bounds__(256) void kvs_mfma(
    const ST* __restrict__ Am, const ST* __restrict__ Bm, float* __restrict__ D)
{
    __shared__ unsigned short Ast[64][36];
    __shared__ unsigned short Bst[64][36];
    const int tid = threadIdx.x;
    const int wave = tid >> 6, lane = tid & 63;
    const int quad = lane >> 4, nl = lane & 15;
    const int i0 = blockIdx.x * 64, j0 = blockIdx.y * 64;   // i0: D rows (A cols), j0: D cols (B cols)
    const int S = gridDim.z;
    const int chunk = (NN + S - 1) / S;
    const int ns = blockIdx.z * chunk;
    const int ne = min(ns + chunk, NN);
    const int nn = tid >> 3;          // row within 32-row chunk (0..31)
    const int c0 = (tid & 7) * 8;     // col offset within 64-col tile (0,8,...,56)
    f32x4 acc[4] = {{0.f,0.f,0.f,0.f},{0.f,0.f,0.f,0.f},{0.f,0.f,0.f,0.f},{0.f,0.f,0.f,0.f}};

    for (int n0 = ns; n0 < ne; n0 += 32) {
        int n = n0 + nn;
        ushort4 a0, a1, b0, b1;
        if (n < ne) {
            ld8S(Am, (size_t)n * DH + i0 + c0, a0, a1);
            ld8S(Bm, (size_t)n * DH + j0 + c0, b0, b1);
        } else {
            a0 = make_ushort4(0, 0, 0, 0); a1 = a0; b0 = a0; b1 = a0;
        }
        __syncthreads();   // previous chunk's frag reads done; loads above stay in flight
        Ast[c0 + 0][nn] = a0.x; Ast[c0 + 1][nn] = a0.y;
        Ast[c0 + 2][nn] = a0.z; Ast[c0 + 3][nn] = a0.w;
        Ast[c0 + 4][nn] = a1.x; Ast[c0 + 5][nn] = a1.y;
        Ast[c0 + 6][nn] = a1.z; Ast[c0 + 7][nn] = a1.w;
        Bst[c0 + 0][nn] = b0.x; Bst[c0 + 1][nn] = b0.y;
        Bst[c0 + 2][nn] = b0.z; Bst[c0 + 3][nn] = b0.w;
        Bst[c0 + 4][nn] = b1.x; Bst[c0 + 5][nn] = b1.y;
        Bst[c0 + 6][nn] = b1.z; Bst[c0 + 7][nn] = b1.w;
        __syncthreads();
        bf16x8 af = *(const bf16x8*)&Ast[wave * 16 + nl][quad * 8];
#pragma unroll
        for (int ct = 0; ct < 4; ++ct) {
            bf16x8 bfg = *(const bf16x8*)&Bst[ct * 16 + nl][quad * 8];
            acc[ct] = __builtin_amdgcn_mfma_f32_16x16x32_bf16(af, bfg, acc[ct], 0, 0, 0);
        }
    }
#pragma unroll
    for (int ct = 0; ct < 4; ++ct)
#pragma unroll
        for (int r = 0; r < 4; ++r)
            atomicAdd(&D[(size_t)(i0 + wave * 16 + quad * 4 + r) * DH + j0 + ct * 16 + nl], acc[ct][r]);
}

// ---------------- kvs f32 -> bf16 convert (once; attn re-reads it 1563x) ----------------
__global__ __launch_bounds__(256) void kvs2b_kernel(const float* __restrict__ kvs,
                                                    unsigned short* __restrict__ kvsb)
{
    int i = blockIdx.x * 256 + threadIdx.x;      // 8192 threads x 8 elems = 65536
    size_t o = (size_t)i * 8;
    float4 a = *(const float4*)(kvs + o);
    float4 b = *(const float4*)(kvs + o + 4);
    *(ushort4*)(kvsb + o)     = make_ushort4(f2b(a.x), f2b(a.y), f2b(a.z), f2b(a.w));
    *(ushort4*)(kvsb + o + 4) = make_ushort4(f2b(b.x), f2b(b.y), f2b(b.z), f2b(b.w));
}

// ---------------- MFMA attention: out = (Q@kvs*scale + N*V) / (Q.ks_sum*scale + N) ----------------
// kvsb: kvs transposed, bf16, row-major [256][256] (L2-resident, 128KB).
// Col-split: gridDim.y=2, each block does 64 rows x 128 cols -> acc[8] (32 VGPRs);
// Q logical re-read is 2x (L3-served) while occupancy stays ~6 waves/SIMD.
template <typename ST>
__global__ __launch_bounds__(256) void attn_mfma(
    const ST* __restrict__ Q, const ST* __restrict__ V,
    const unsigned short* __restrict__ kvsb, const float* __restrict__ ks_sum,
    const float* __restrict__ qss, const float* __restrict__ kss,
    ST* __restrict__ out)
{
    __shared__ float ks_s[DH];
    __shared__ float nrm_s[64];
    const int tid = threadIdx.x;
    const int wave = tid >> 6, lane = tid & 63;
    const int quad = lane >> 4, nl = lane & 15;
    const int m0 = blockIdx.x * 64;
    const int j0 = blockIdx.y * 128;

    ks_s[tid] = ks_sum[tid];
    __syncthreads();

    const int arow = m0 + wave * 16 + nl;
    const int av = (arow < NN);
    const size_t abase = (size_t)arow * DH + quad * 8;
    f32x4 acc[8];
#pragma unroll
    for (int i = 0; i < 8; ++i) acc[i] = (f32x4){0.f, 0.f, 0.f, 0.f};
    float nrm = 0.f;

#pragma unroll 2
    for (int k0 = 0; k0 < DH; k0 += 32) {
        ushort4 a0, a1;
        if (av) ld8S(Q, abase + k0, a0, a1);
        else { a0 = make_ushort4(0,0,0,0); a1 = a0; }
        bf16x8 af;
        ((ushort4*)&af)[0] = a0; ((ushort4*)&af)[1] = a1;
#pragma unroll
        for (int j = 0; j < 8; ++j)
            nrm += bits2f(((const unsigned short*)&af)[j]) * ks_s[k0 + quad * 8 + j];
        const unsigned short* kb = kvsb + (size_t)(j0 + nl) * DH + k0 + quad * 8;
#pragma unroll
        for (int ct = 0; ct < 8; ++ct) {
            bf16x8 bfg = *(const bf16x8*)(kb + (size_t)ct * 16 * DH);
            acc[ct] = __builtin_amdgcn_mfma_f32_16x16x32_bf16(af, bfg, acc[ct], 0, 0, 0);
        }
    }
    nrm += __shfl_xor(nrm, 16);
    nrm += __shfl_xor(nrm, 32);
    if (lane < 16) nrm_s[wave * 16 + lane] = nrm;
    __syncthreads();
    const float scale = rsqrtf(*qss) * rsqrtf(*kss);
#pragma unroll
    for (int r = 0; r < 4; ++r) {
        int row = m0 + wave * 16 + quad * 4 + r;
        if (row >= NN) continue;
        float den = nrm_s[wave * 16 + quad * 4 + r] * scale + (float)NN;
#pragma unroll
        for (int ct = 0; ct < 8; ++ct) {
            int col = j0 + ct * 16 + nl;
            float v = ldS(V, (size_t)row * DH + col);
            float numv = acc[ct][r] * scale + (float)NN * v;
            stS(out, (size_t)row * DH + col, numv / den);
        }
    }
}

// ---------------- LayerNorm over D=256: one wave per row, 4 rows/block ----------------
template <typename ST>
__global__ __launch_bounds__(256) void ln_kernel(
    const ST* __restrict__ A, const ST* __restrict__ B,
    float alpha, float beta,
    const void* __restrict__ g, const void* __restrict__ b,
    ST* __restrict__ out, int relu, const int* __restrict__ flags)
{
    const int isbf = flags[0];
    const int wave = threadIdx.x >> 6, lane = threadIdx.x & 63;
    const int row = blockIdx.x * 4 + wave;
    if (row >= NN) return;
    const size_t base = (size_t)row * DH + lane * 4;
    float4 v = ld4S(&A[base]);
    v.x *= alpha; v.y *= alpha; v.z *= alpha; v.w *= alpha;
    if (B) {
        float4 w = ld4S(&B[base]);
        v.x += beta * w.x; v.y += beta * w.y; v.z += beta * w.z; v.w += beta * w.w;
    }
    float s = v.x + v.y + v.z + v.w;
    float s2 = v.x * v.x + v.y * v.y + v.z * v.z + v.w * v.w;
#pragma unroll
    for (int off = 32; off > 0; off >>= 1) {
        s += __shfl_xor(s, off);
        s2 += __shfl_xor(s2, off);
    }
    float mean = s * (1.f / DH);
    float var = s2 * (1.f / DH) - mean * mean;
    float rstd = rsqrtf(var + 1e-5f);
    float4 o;
    o.x = (v.x - mean) * rstd * ldf(g, lane * 4 + 0, isbf) + ldf(b, lane * 4 + 0, isbf);
    o.y = (v.y - mean) * rstd * ldf(g, lane * 4 + 1, isbf) + ldf(b, lane * 4 + 1, isbf);
    o.z = (v.z - mean) * rstd * ldf(g, lane * 4 + 2, isbf) + ldf(b, lane * 4 + 2, isbf);
    o.w = (v.w - mean) * rstd * ldf(g, lane * 4 + 3, isbf) + ldf(b, lane * 4 + 3, isbf);
    if (relu) {
        o.x = fmaxf(o.x, 0.f); o.y = fmaxf(o.y, 0.f);
        o.z = fmaxf(o.z, 0.f); o.w = fmaxf(o.w, 0.f);
    }
    st4S(&out[base], o);
}

// ---------------- sum of squares ----------------
template <typename ST>
__global__ __launch_bounds__(256) void sumsq_kernel(
    const ST* __restrict__ A, size_t n, float* __restrict__ out)
{
    __shared__ float ps[4];
    size_t i = (size_t)blockIdx.x * blockDim.x + threadIdx.x;
    size_t stride = (size_t)gridDim.x * blockDim.x;
    float s = 0.f;
    for (; i < n; i += stride) { float v = ldS(A, i); s += v * v; }
#pragma unroll
    for (int off = 32; off > 0; off >>= 1) s += __shfl_down(s, off);
    if ((threadIdx.x & 63) == 0) ps[threadIdx.x >> 6] = s;
    __syncthreads();
    if (threadIdx.x == 0) atomicAdd(out, ps[0] + ps[1] + ps[2] + ps[3]);
}

// ---------------- ks_sum[j] = sum_n K[n][j] (rows-per-block from gridDim) ----------------
template <typename ST>
__global__ __launch_bounds__(256) void colsum_kernel(
    const ST* __restrict__ Km, float* __restrict__ out)
{
    const int t = threadIdx.x;
    const int per = (NN + gridDim.x - 1) / gridDim.x;
    size_t r0 = (size_t)blockIdx.x * per;
    size_t r1 = r0 + per; if (r1 > NN) r1 = NN;
    float s = 0.f;
    for (size_t r = r0; r < r1; ++r) s += ldS(Km, r * DH + t);
    atomicAdd(&out[t], s);
}

// ---------------- CSR build ----------------
__global__ __launch_bounds__(256) void count_kernel(const int* __restrict__ ei, int* __restrict__ cnt,
                                                    const int* __restrict__ flags)
{
    int e = blockIdx.x * 256 + threadIdx.x;
    if (e >= NE) return;
    int d = ld_dst(ei, e, flags[1]);
    if ((unsigned)d < NN) atomicAdd(&cnt[d], 1);
}

__global__ __launch_bounds__(256) void scan_block_kernel(const int* __restrict__ cnt,
                                                         int* __restrict__ pre, int* __restrict__ bsum)
{
    __shared__ int s[256];
    int i = blockIdx.x * 256 + threadIdx.x;
    int v = (i < NN) ? cnt[i] : 0;
    s[threadIdx.x] = v;
    __syncthreads();
    for (int off = 1; off < 256; off <<= 1) {
        int t = (threadIdx.x >= off) ? s[threadIdx.x - off] : 0;
        __syncthreads();
        s[threadIdx.x] += t;
        __syncthreads();
    }
    if (i < NN) pre[i] = s[threadIdx.x] - v;
    if (threadIdx.x == 255) bsum[blockIdx.x] = s[255];
}

__global__ __launch_bounds__(512) void scan_partial_kernel(int* __restrict__ bsum, int nb)
{
    __shared__ int s[512];
    int t = threadIdx.x;
    int v = (t < nb) ? bsum[t] : 0;
    s[t] = v;
    __syncthreads();
    for (int off = 1; off < 512; off <<= 1) {
        int u = (t >= off) ? s[t - off] : 0;
        __syncthreads();
        s[t] += u;
        __syncthreads();
    }
    if (t < nb) bsum[t] = s[t] - v;
}

__global__ __launch_bounds__(256) void finalize_kernel(int* __restrict__ base, const int* __restrict__ bsum,
                                                       const int* __restrict__ cnt, int* __restrict__ cursor,
                                                       float* __restrict__ dinv)
{
    int i = blockIdx.x * 256 + threadIdx.x;
    if (i >= NN) return;
    int b = base[i] + bsum[blockIdx.x];
    base[i] = b;
    cursor[i] = b;
    dinv[i] = rsqrtf((float)cnt[i] + 1.0f);
}

__global__ __launch_bounds__(256) void scatter_kernel(const int* __restrict__ ei, int* __restrict__ cursor,
                                                      int* __restrict__ srcs, const int* __restrict__ flags)
{
    int e = blockIdx.x * 256 + threadIdx.x;
    if (e >= NE) return;
    int i64 = flags[1];
    int s = ld_src(ei, e, i64), d = ld_dst(ei, e, i64);
    if ((unsigned)s >= NN || (unsigned)d >= NN) return;
    int pos = atomicAdd(&cursor[d], 1);
    srcs[pos] = s;
}

// ---------------- FUSED CSR gather + GCN epilogue: one wave per node ----------------
// MODE 0: out = relu((agg + own*di^2 + b) * bn_g/sqrt(1+eps) + bn_b)
// MODE 1: out = 0.8*(agg + own*di^2 + b) + 0.2*Ht
// 4-way unrolled: 4 independent {src,dinv,row} chains in flight per wave for MLP.
template <typename ST, int MODE>
__global__ __launch_bounds__(256) void fgather_kernel(
    const ST* __restrict__ Hs, const ST* __restrict__ Ht,
    const int* __restrict__ base, const int* __restrict__ cnt,
    const int* __restrict__ srcs, const float* __restrict__ dinv,
    const void* __restrict__ bias, const void* __restrict__ bng, const void* __restrict__ bnb,
    const int* __restrict__ flags, ST* __restrict__ out)
{
    const int isbf = flags[0];
    int node = blockIdx.x * 4 + (threadIdx.x >> 6);
    int lane = threadIdx.x & 63;
    if (node >= NN) return;
    int b0 = base[node], deg = cnt[node];
    float dd = dinv[node];
    float4 a0 = make_float4(0.f, 0.f, 0.f, 0.f);
    float4 a1 = make_float4(0.f, 0.f, 0.f, 0.f);
    int j = 0;
    for (; j + 4 <= deg; j += 4) {      // 4 independent row-chains in flight
        int s0 = srcs[b0 + j + 0], s1 = srcs[b0 + j + 1];
        int s2 = srcs[b0 + j + 2], s3 = srcs[b0 + j + 3];
        float n0 = dd * dinv[s0], n1 = dd * dinv[s1];
        float n2 = dd * dinv[s2], n3 = dd * dinv[s3];
        float4 h0 = ld4S(&Hs[(size_t)s0 * DH + lane * 4]);
        float4 h1 = ld4S(&Hs[(size_t)s1 * DH + lane * 4]);
        float4 h2 = ld4S(&Hs[(size_t)s2 * DH + lane * 4]);
        float4 h3 = ld4S(&Hs[(size_t)s3 * DH + lane * 4]);
        a0.x += h0.x * n0; a0.y += h0.y * n0; a0.z += h0.z * n0; a0.w += h0.w * n0;
        a1.x += h1.x * n1; a1.y += h1.y * n1; a1.z += h1.z * n1; a1.w += h1.w * n1;
        a0.x += h2.x * n2; a0.y += h2.y * n2; a0.z += h2.z * n2; a0.w += h2.w * n2;
        a1.x += h3.x * n3; a1.y += h3.y * n3; a1.z += h3.z * n3; a1.w += h3.w * n3;
    }
    for (; j < deg; ++j) {
        int s0 = srcs[b0 + j];
        float n0 = dd * dinv[s0];
        float4 h0 = ld4S(&Hs[(size_t)s0 * DH + lane * 4]);
        a0.x += h0.x * n0; a0.y += h0.y * n0; a0.z += h0.z * n0; a0.w += h0.w * n0;
    }
    const size_t obase = (size_t)node * DH + lane * 4;
    float4 own = ld4S(&Hs[obase]);
    float di2 = dd * dd;
    int c = lane * 4;
    float4 v;
    v.x = a0.x + a1.x + own.x * di2 + ldf(bias, c + 0, isbf);
    v.y = a0.y + a1.y + own.y * di2 + ldf(bias, c + 1, isbf);
    v.z = a0.z + a1.z + own.z * di2 + ldf(bias, c + 2, isbf);
    v.w = a0.w + a1.w + own.w * di2 + ldf(bias, c + 3, isbf);
    if (MODE == 0) {
        const float bnscale = 0.99999500003749981f;  // 1/sqrt(1+1e-5)
        v.x = fmaxf(v.x * (ldf(bng, c + 0, isbf) * bnscale) + ldf(bnb, c + 0, isbf), 0.f);
        v.y = fmaxf(v.y * (ldf(bng, c + 1, isbf) * bnscale) + ldf(bnb, c + 1, isbf), 0.f);
        v.z = fmaxf(v.z * (ldf(bng, c + 2, isbf) * bnscale) + ldf(bnb, c + 2, isbf), 0.f);
        v.w = fmaxf(v.w * (ldf(bng, c + 3, isbf) * bnscale) + ldf(bnb, c + 3, isbf), 0.f);
    } else {
        float4 t = ld4S(&Ht[obase]);
        v.x = 0.8f * v.x + 0.2f * t.x;
        v.y = 0.8f * v.y + 0.2f * t.y;
        v.z = 0.8f * v.z + 0.2f * t.z;
        v.w = 0.8f * v.w + 0.2f * t.w;
    }
    st4S(&out[obase], v);
}

// ---------------- fallback (atomic) GCN pieces ----------------
__global__ __launch_bounds__(256) void deg_kernel(const int* __restrict__ ei, float* __restrict__ deg,
                                                  const int* __restrict__ flags)
{
    int i64 = flags[1];
    int e = blockIdx.x * 256 + threadIdx.x;
    if (e >= NE) return;
    int d = ld_dst(ei, e, i64);
    if ((unsigned)d < NN) atomicAdd(&deg[d], 1.0f);
}

__global__ __launch_bounds__(256) void dinv_kernel(float* __restrict__ deg)
{
    int i = blockIdx.x * 256 + threadIdx.x;
    if (i < NN) deg[i] = rsqrtf(deg[i] + 1.0f);
}

template <typename ST>
__global__ __launch_bounds__(256) void agg_kernel(
    const ST* __restrict__ Hs, const int* __restrict__ ei,
    const float* __restrict__ dinv, float* __restrict__ lo, float* __restrict__ hi,
    const int* __restrict__ flags)
{
    int i64 = flags[1];
    int e = blockIdx.x * 4 + (threadIdx.x >> 6);
    int lane = threadIdx.x & 63;
    if (e >= NE) return;
    int s = ld_src(ei, e, i64), d = ld_dst(ei, e, i64);
    if ((unsigned)s >= NN || (unsigned)d >= NN) return;
    float nrm = dinv[s] * dinv[d];
    const float4 h4 = ld4S(&Hs[(size_t)s * DH + lane * 4]);
    float* o = (d < NSPL ? &lo[(size_t)d * DH] : &hi[(size_t)(d - NSPL) * DH]) + lane * 4;
    atomicAdd(o + 0, h4.x * nrm);
    atomicAdd(o + 1, h4.y * nrm);
    atomicAdd(o + 2, h4.z * nrm);
    atomicAdd(o + 3, h4.w * nrm);
}

// self-loop + bias + BN(eval) + relu
template <typename ST>
__global__ __launch_bounds__(256) void gcn_epi1_kernel(
    const float* __restrict__ lo, const float* __restrict__ hi,
    const ST* __restrict__ h1, const float* __restrict__ dinv,
    const void* __restrict__ b0, const void* __restrict__ bng, const void* __restrict__ bnb,
    const int* __restrict__ flags, ST* __restrict__ out)
{
    const int isbf = flags[0];
    size_t idx = (size_t)blockIdx.x * 256 + threadIdx.x;
    if (idx >= (size_t)NN * DH) return;
    int i = (int)(idx >> 8), c = (int)(idx & 255);
    float aggv = (i < NSPL) ? lo[idx] : hi[idx - NSO];
    float di = dinv[i];
    float v = aggv + ldS(h1, idx) * di * di + ldf(b0, c, isbf);
    const float bnscale = 0.99999500003749981f;  // 1/sqrt(1+1e-5)
    v = v * (ldf(bng, c, isbf) * bnscale) + ldf(bnb, c, isbf);
    stS(out, idx, fmaxf(v, 0.f));
}

// self-loop + bias + combine: emb = 0.8*(agg + self + b1) + 0.2*x_trans
template <typename ST>
__global__ __launch_bounds__(256) void gcn_epi2_kernel(
    const float* __restrict__ lo, const float* __restrict__ hi,
    const ST* __restrict__ h2, const ST* __restrict__ Ht, const float* __restrict__ dinv,
    const void* __restrict__ b1, const int* __restrict__ flags, ST* __restrict__ out)
{
    const int isbf = flags[0];
    size_t idx = (size_t)blockIdx.x * 256 + threadIdx.x;
    if (idx >= (size_t)NN * DH) return;
    int i = (int)(idx >> 8), c = (int)(idx & 255);
    float aggv = (i < NSPL) ? lo[idx] : hi[idx - NSO];
    float di = dinv[i];
    float g = aggv + ldS(h2, idx) * di * di + ldf(b1, c, isbf);
    stS(out, idx, 0.8f * g + 0.2f * ldS(Ht, idx));
}

// ---------------- diagnostic ----------------
__global__ __launch_bounds__(256) void diag_kernel(float* out, size_t n, float val)
{
    size_t i = (size_t)blockIdx.x * 256 + threadIdx.x;
    if (i < n) out[i] = val;
}

// ---------------- pipeline ----------------
template <typename ST>
static void run_pipeline(void* const* d_in, void* d_out, char* wsb, hipStream_t stream, int use_csr)
{
    const void* x      = d_in[0];
    const int*  ei     = (const int*)d_in[1];
    const void* fc0_w  = d_in[2];  const void* fc0_b  = d_in[3];
    const void* ln0_g  = d_in[4];  const void* ln0_b  = d_in[5];
    const void* wq0_w  = d_in[6];  const void* wq0_b  = d_in[7];
    const void* wk0_w  = d_in[8];  const void* wk0_b  = d_in[9];
    const void* wv0_w  = d_in[10]; const void* wv0_b  = d_in[11];
    const void* ln1_g  = d_in[12]; const void* ln1_b  = d_in[13];
    const void* wq1_w  = d_in[14]; const void* wq1_b  = d_in[15];
    const void* wk1_w  = d_in[16]; const void* wk1_b  = d_in[17];
    const void* wv1_w  = d_in[18]; const void* wv1_b  = d_in[19];
    const void* ln2_g  = d_in[20]; const void* ln2_b  = d_in[21];
    const void* gcn_w0 = d_in[22]; const void* gcn_b0 = d_in[23];
    const void* bn_g   = d_in[24]; const void* bn_b   = d_in[25];
    const void* gcn_w1 = d_in[26]; const void* gcn_b1 = d_in[27];
    const void* fc_w   = d_in[28]; const void* fc_b   = d_in[29];

    const size_t stN = (size_t)NN * DH * sizeof(ST);
    ST* H  = (ST*)(wsb);
    ST* Qb = (ST*)(wsb + stN);
    ST* Kb = (ST*)(wsb + 2 * stN);
    ST* Vb = (ST*)(wsb + 3 * stN);
    float* aux = (float*)(wsb + 4 * stN);
    float* kvs    = aux;
    float* ks_sum = aux + 65536;
    float* qss    = aux + 65792;
    float* kss    = aux + 65793;
    float* dinv   = aux + 65808;
    int*   flags  = (int*)(aux + 65808 + NN);
    int* cnt    = (int*)(aux + 65808 + NN + 16);
    int* base   = cnt + NN;
    int* cursor = base + NN;
    int* bsum   = cursor + NN;       // 512
    int* srcs   = bsum + 512;        // NE
    // dinv region (NN floats = 400KB) is dead until the GCN branch; borrow 128KB
    // of it for the bf16 copy of kvsT during the attention layers.
    unsigned short* kvsb = (unsigned short*)dinv;

    const int asel = (sizeof(ST) == 2) ? 1 : 0;
    dim3 mfmaGrid((NN + 127) / 128, DH / 64);
    const size_t NELEM = (size_t)NN * DH;

    detect_kernel<<<1, 256, 0, stream>>>(x, ei, flags);

    // ---- TransConv input layer ----
    gemm_mfma<ST><<<mfmaGrid, 512, 0, stream>>>(x, fc0_w, fc0_b, Qb, NN, DH, flags, 2);
    ln_kernel<ST><<<(NN + 3) / 4, 256, 0, stream>>>(Qb, (const ST*)nullptr, 1.f, 0.f, ln0_g, ln0_b, H, 1, flags);

    // ---- two attention layers ----
    for (int layer = 0; layer < 2; ++layer) {
        const void *qw, *qb, *kw, *kb, *vw, *vb, *lg, *lb;
        if (layer == 0) { qw = wq0_w; qb = wq0_b; kw = wk0_w; kb = wk0_b; vw = wv0_w; vb = wv0_b; lg = ln1_g; lb = ln1_b; }
        else            { qw = wq1_w; qb = wq1_b; kw = wk1_w; kb = wk1_b; vw = wv1_w; vb = wv1_b; lg = ln2_g; lb = ln2_b; }
        gemm_mfma<ST><<<mfmaGrid, 512, 0, stream>>>(H, qw, qb, Qb, NN, DH, flags, asel);
        gemm_mfma<ST><<<mfmaGrid, 512, 0, stream>>>(H, kw, kb, Kb, NN, DH, flags, asel);
        gemm_mfma<ST><<<mfmaGrid, 512, 0, stream>>>(H, vw, vb, Vb, NN, DH, flags, asel);
        hipMemsetAsync(aux, 0, (65536 + 256 + 2) * sizeof(float), stream);
        sumsq_kernel<ST><<<2048, 256, 0, stream>>>(Qb, NELEM, qss);
        sumsq_kernel<ST><<<2048, 256, 0, stream>>>(Kb, NELEM, kss);
        // kvs stored TRANSPOSED: kvs[j][i] = sum_n V[n][j] K[n][i]
        kvs_mfma<ST><<<dim3(4, 4, 128), 256, 0, stream>>>(Vb, Kb, kvs);
        colsum_kernel<ST><<<800, 256, 0, stream>>>(Kb, ks_sum);
        kvs2b_kernel<<<32, 256, 0, stream>>>(kvs, kvsb);
        attn_mfma<ST><<<dim3((NN + 63) / 64, 2), 256, 0, stream>>>(Qb, Vb, kvsb, ks_sum, qss, kss, Kb);
        ln_kernel<ST><<<(NN + 3) / 4, 256, 0, stream>>>(Kb, H, 0.5f, 0.5f, lg, lb, H, 0, flags);
    }

    // ---- GCN branch ----
    if (use_csr) {
        hipMemsetAsync(cnt, 0, NN * sizeof(int), stream);
        count_kernel<<<(NE + 255) / 256, 256, 0, stream>>>(ei, cnt, flags);
        scan_block_kernel<<<NBLK, 256, 0, stream>>>(cnt, base, bsum);
        scan_partial_kernel<<<1, 512, 0, stream>>>(bsum, NBLK);
        finalize_kernel<<<NBLK, 256, 0, stream>>>(base, bsum, cnt, cursor, dinv);
        scatter_kernel<<<(NE + 255) / 256, 256, 0, stream>>>(ei, cursor, srcs, flags);

        // fused path: h1 -> Qb; fused gather+BN+relu -> Kb; h2 -> Vb;
        // fused gather+combine -> Qb (emb); classifier reads Qb.
        gemm_mfma<ST><<<mfmaGrid, 512, 0, stream>>>(x, gcn_w0, nullptr, Qb, NN, DH, flags, 2);
        fgather_kernel<ST, 0><<<(NN + 3) / 4, 256, 0, stream>>>(
            Qb, (const ST*)nullptr, base, cnt, srcs, dinv, gcn_b0, bn_g, bn_b, flags, Kb);
        gemm_mfma<ST><<<mfmaGrid, 512, 0, stream>>>(Kb, gcn_w1, nullptr, Vb, NN, DH, flags, asel);
        fgather_kernel<ST, 1><<<(NN + 3) / 4, 256, 0, stream>>>(
            Vb, H, base, cnt, srcs, dinv, gcn_b1, nullptr, nullptr, flags, Qb);

        gemm_mfma<float><<<dim3((NN + 127) / 128, 1), 512, 0, stream>>>(Qb, fc_w, fc_b, (float*)d_out, NN, DOUT, flags, asel);
    } else {
        float* a1lo = (float*)(wsb + 2 * stN);
        float* a1hi = a1lo + NSO;
        ST* h2; float *a2lo, *a2hi;
        if (sizeof(ST) == 4) { h2 = Vb; a2lo = (float*)(wsb + 2 * stN); a2hi = a2lo + NSO; }
        else                 { h2 = Kb; a2lo = (float*)(wsb + stN);     a2hi = (float*)(wsb + 3 * stN); }

        hipMemsetAsync(dinv, 0, NN * sizeof(float), stream);
        deg_kernel<<<(NE + 255) / 256, 256, 0, stream>>>(ei, dinv, flags);
        dinv_kernel<<<(NN + 255) / 256, 256, 0, stream>>>(dinv);

        gemm_mfma<ST><<<mfmaGrid, 512, 0, stream>>>(x, gcn_w0, nullptr, Qb, NN, DH, flags, 2);
        hipMemsetAsync(a1lo, 0, NELEM * sizeof(float), stream);
        agg_kernel<ST><<<(NE + 3) / 4, 256, 0, stream>>>(Qb, ei, dinv, a1lo, a1hi, flags);
        gcn_epi1_kernel<ST><<<(NELEM + 255) / 256, 256, 0, stream>>>(a1lo, a1hi, Qb, dinv, gcn_b0, bn_g, bn_b, flags, Qb);

        gemm_mfma<ST><<<mfmaGrid, 512, 0, stream>>>(Qb, gcn_w1, nullptr, h2, NN, DH, flags, asel);
        hipMemsetAsync(a2lo, 0, NSO * sizeof(float), stream);
        hipMemsetAsync(a2hi, 0, NSO * sizeof(float), stream);
        agg_kernel<ST><<<(NE + 3) / 4, 256, 0, stream>>>(h2, ei, dinv, a2lo, a2hi, flags);
        gcn_epi2_kernel<ST><<<(NELEM + 255) / 256, 256, 0, stream>>>(a2lo, a2hi, h2, H, dinv, gcn_b1, flags, h2);

        gemm_mfma<float><<<dim3((NN + 127) / 128, 1), 512, 0, stream>>>(h2, fc_w, fc_b, (float*)d_out, NN, DOUT, flags, asel);
    }
}

extern "C" void kernel_launch(void* const* d_in, const int* in_sizes, int n_in,
                              void* d_out, int out_size, void* d_ws, size_t ws_size,
                              hipStream_t stream)
{
    char* wsb = (char*)d_ws;
    const size_t AUXF  = 65808 + NN + 16;
    const size_t CSRI  = 3 * (size_t)NN + 512 + NE;
    const size_t AUXB  = AUXF * sizeof(float);
    const size_t AUXB2 = AUXB + CSRI * sizeof(int);
    const size_t needA  = 4 * ((size_t)NN * DH * 4) + AUXB;
    const size_t needA2 = 4 * ((size_t)NN * DH * 4) + AUXB2;
    const size_t needB  = 4 * ((size_t)NN * DH * 2) + AUXB;
    const size_t needB2 = 4 * ((size_t)NN * DH * 2) + AUXB2;

    if (ws_size >= needA) {
        run_pipeline<float>(d_in, d_out, wsb, stream, ws_size >= needA2);
    } else if (ws_size >= needB) {
        run_pipeline<bf16>(d_in, d_out, wsb, stream, ws_size >= needB2);
    } else {
        float mb = (float)(ws_size >> 20);
        size_t n = (size_t)out_size;
        diag_kernel<<<(n + 255) / 256, 256, 0, stream>>>((float*)d_out, n, mb);
    }
}

// Round 7
// 1922.300 us; speedup vs baseline: 1.5397x; 1.0102x over previous
//
#include <hip/hip_runtime.h>
#include <hip/hip_bf16.h>

#define NN 100000
#define NE 800000
#define DH 256
#define DOUT 64
#define NSPL 50000                      // GCN agg row split
#define NSO ((size_t)NSPL * DH)        // elems per half
#define NBLK 391                       // ceil(NN/256)

using bf16 = __hip_bfloat16;
typedef __attribute__((ext_vector_type(8))) short bf16x8;
typedef __attribute__((ext_vector_type(4))) float f32x4;

// ---------------- dtype helpers ----------------
__device__ __forceinline__ float bits2f(unsigned short h) {
    union { unsigned int u; float f; } c; c.u = ((unsigned int)h) << 16; return c.f;
}
__device__ __forceinline__ unsigned short f2b(float v) {
    union { float f; unsigned int u; } c; c.f = v;
    unsigned int u = c.u;
    return (unsigned short)((u + 0x7FFFu + ((u >> 16) & 1u)) >> 16);  // RNE
}
__device__ __forceinline__ unsigned short tob(float v) { return f2b(v); }
__device__ __forceinline__ unsigned short tob(bf16 v) {
    union { bf16 b; unsigned short u; } c; c.b = v; return c.u;
}
__device__ __forceinline__ float ldf(const void* p, size_t i, int isbf) {
    if (isbf) return bits2f(((const unsigned short*)p)[i]);
    return ((const float*)p)[i];
}
__device__ __forceinline__ float ldS(const float* p, size_t i) { return p[i]; }
__device__ __forceinline__ float ldS(const bf16* p, size_t i) { return __bfloat162float(p[i]); }
__device__ __forceinline__ void stS(float* p, size_t i, float v) { p[i] = v; }
__device__ __forceinline__ void stS(bf16* p, size_t i, float v) { p[i] = __float2bfloat16(v); }
__device__ __forceinline__ float4 ld4S(const float* p) { return *(const float4*)p; }
__device__ __forceinline__ float4 ld4S(const bf16* p) {
    ushort4 u = *(const ushort4*)(const void*)p;
    return make_float4(bits2f(u.x), bits2f(u.y), bits2f(u.z), bits2f(u.w));
}
__device__ __forceinline__ void st4S(float* p, float4 v) { *(float4*)p = v; }
__device__ __forceinline__ void st4S(bf16* p, float4 v) {
    *(ushort4*)(void*)p = make_ushort4(f2b(v.x), f2b(v.y), f2b(v.z), f2b(v.w));
}
// load 8 consecutive elems (16B-aligned) as bf16 bit patterns from f32 or bf16 source
__device__ __forceinline__ void ld8(const void* p, size_t idx, int isbf, ushort4& o0, ushort4& o1) {
    if (isbf) {
        const ushort4* q = (const ushort4*)((const unsigned short*)p + idx);
        o0 = q[0]; o1 = q[1];
    } else {
        const float4* q = (const float4*)((const float*)p + idx);
        float4 a = q[0], b = q[1];
        o0 = make_ushort4(f2b(a.x), f2b(a.y), f2b(a.z), f2b(a.w));
        o1 = make_ushort4(f2b(b.x), f2b(b.y), f2b(b.z), f2b(b.w));
    }
}
__device__ __forceinline__ void ld8S(const bf16* p, size_t idx, ushort4& o0, ushort4& o1) {
    const ushort4* q = (const ushort4*)((const unsigned short*)p + idx);
    o0 = q[0]; o1 = q[1];
}
__device__ __forceinline__ void ld8S(const float* p, size_t idx, ushort4& o0, ushort4& o1) {
    const float4* q = (const float4*)(p + idx);
    float4 a = q[0], b = q[1];
    o0 = make_ushort4(f2b(a.x), f2b(a.y), f2b(a.z), f2b(a.w));
    o1 = make_ushort4(f2b(b.x), f2b(b.y), f2b(b.z), f2b(b.w));
}
__device__ __forceinline__ int ld_src(const int* ei, int e, int i64) {
    return i64 ? ei[2 * (size_t)e] : ei[e];
}
__device__ __forceinline__ int ld_dst(const int* ei, int e, int i64) {
    return i64 ? ei[2 * ((size_t)NE + e)] : ei[NE + e];
}

// ---------------- dtype detector (sampled) ----------------
__global__ __launch_bounds__(256) void detect_kernel(const void* x, const int* ei, int* flags)
{
    __shared__ int s_sane[4], s_nz[4];
    int t = threadIdx.x;
    const unsigned short* xu = (const unsigned short*)x;
    int sane = 0;
    for (int i = t; i < 2048; i += 256) {
        float v = bits2f(xu[2 * i]);
        float a = fabsf(v);
        if (v == v && a > 1e-3f && a < 100.f) sane++;
    }
    int nz = 0;
    for (int i = t; i < 4096; i += 256) {
        if (ei[2 * (i * 122) + 1] != 0) nz++;
    }
#pragma unroll
    for (int off = 32; off > 0; off >>= 1) { sane += __shfl_down(sane, off); nz += __shfl_down(nz, off); }
    if ((t & 63) == 0) { s_sane[t >> 6] = sane; s_nz[t >> 6] = nz; }
    __syncthreads();
    if (t == 0) {
        flags[0] = ((s_sane[0] + s_sane[1] + s_sane[2] + s_sane[3]) > 1024) ? 1 : 0;
        flags[1] = ((s_nz[0] + s_nz[1] + s_nz[2] + s_nz[3]) == 0) ? 1 : 0;
    }
}

// ---------------- MFMA GEMM: C[M,Nc] = A[M,256] @ W[256,Nc] (+bias) ----------------
// 512 threads / 128 rows per block. ALL 8 A-fragments prefetched into registers
// BEFORE the B-staging barrier: the barrier's vmcnt(0) drain doubles as the
// prefetch wait, so the K-loop is pure LDS+MFMA with zero global latency.
template <typename ST>
__global__ __launch_bounds__(512) void gemm_mfma(
    const void* __restrict__ A, const void* __restrict__ W,
    const void* __restrict__ bias, ST* __restrict__ C,
    int M, int Nc, const int* __restrict__ flags, int a_sel)
{
    __shared__ unsigned short Bs[64][264];   // W^T tile: Bs[n][k], all K
    const int isbf = flags[0];
    const int abf = (a_sel == 2) ? isbf : a_sel;
    const int tid = threadIdx.x;
    const int wave = tid >> 6, lane = tid & 63;
    const int quad = lane >> 4, nl = lane & 15;
    const int m0 = blockIdx.x * 128;
    const int n0 = blockIdx.y * 64;

    // -- prefetch all 8 A fragments (independent of LDS/barrier) --
    const int arow = m0 + wave * 16 + nl;         // A row this lane supplies
    const int av = (arow < M);
    const size_t abase = (size_t)arow * DH + quad * 8;
    ushort4 pa0[8], pa1[8];
#pragma unroll
    for (int s = 0; s < 8; ++s) {
        if (av) ld8(A, abase + s * 32, abf, pa0[s], pa1[s]);
        else { pa0[s] = make_ushort4(0, 0, 0, 0); pa1[s] = pa0[s]; }
    }

    // -- stage W^T tile into LDS --
#pragma unroll
    for (int it = 0; it < 4; ++it) {
        int p8 = it * 512 + tid;
        int k = p8 >> 3, nb = p8 & 7;
        ushort4 w0, w1;
        ld8(W, (size_t)k * Nc + n0 + nb * 8, isbf, w0, w1);
        int nbase = nb * 8;
        Bs[nbase + 0][k] = w0.x; Bs[nbase + 1][k] = w0.y;
        Bs[nbase + 2][k] = w0.z; Bs[nbase + 3][k] = w0.w;
        Bs[nbase + 4][k] = w1.x; Bs[nbase + 5][k] = w1.y;
        Bs[nbase + 6][k] = w1.z; Bs[nbase + 7][k] = w1.w;
    }
    __syncthreads();

    f32x4 acc[4] = {{0.f,0.f,0.f,0.f},{0.f,0.f,0.f,0.f},{0.f,0.f,0.f,0.f},{0.f,0.f,0.f,0.f}};

#pragma unroll
    for (int s = 0; s < 8; ++s) {
        const int k0 = s * 32;
        bf16x8 af;
        ((ushort4*)&af)[0] = pa0[s]; ((ushort4*)&af)[1] = pa1[s];
#pragma unroll
        for (int ct = 0; ct < 4; ++ct) {
            bf16x8 bfg = *(const bf16x8*)&Bs[ct * 16 + nl][k0 + quad * 8];
            acc[ct] = __builtin_amdgcn_mfma_f32_16x16x32_bf16(af, bfg, acc[ct], 0, 0, 0);
        }
    }

#pragma unroll
    for (int ct = 0; ct < 4; ++ct) {
        int n = n0 + ct * 16 + nl;
        float bv = bias ? ldf(bias, n, isbf) : 0.f;
#pragma unroll
        for (int r = 0; r < 4; ++r) {
            int m = m0 + wave * 16 + quad * 4 + r;
            if (m < M) stS(C, (size_t)m * Nc + n, acc[ct][r] + bv);
        }
    }
}

// ---------------- MFMA kvs: D[256,256] = A^T @ B over N (split-N, atomic f32) ----------------
// call with (Vm, Km, kvs): D[j][i] = sum_n V[n][j]*K[n][i]  == kvs transposed, row-major
template <typename ST>
__global__ __launch_bounds__(256) void kvs_mfma(
    const ST* __restrict__ Am, const ST* __restrict__ Bm, float* __restrict__ D)
{
    __shared__ unsigned short Ast[64][36];
    __shared__ unsigned short Bst[64][36];
    const int tid = threadIdx.x;
    const int wave = tid >> 6, lane = tid & 63;
    const int quad = lane >> 4, nl = lane & 15;
    const int i0 = blockIdx.x * 64, j0 = blockIdx.y * 64;   // i0: D rows (A cols), j0: D cols (B cols)
    const int S = gridDim.z;
    const int chunk = (NN + S - 1) / S;
    const int ns = blockIdx.z * chunk;
    const int ne = min(ns + chunk, NN);
    const int nn = tid >> 3;          // row within 32-row chunk (0..31)
    const int c0 = (tid & 7) * 8;     // col offset within 64-col tile (0,8,...,56)
    f32x4 acc[4] = {{0.f,0.f,0.f,0.f},{0.f,0.f,0.f,0.f},{0.f,0.f,0.f,0.f},{0.f,0.f,0.f,0.f}};

    for (int n0 = ns; n0 < ne; n0 += 32) {
        int n = n0 + nn;
        ushort4 a0, a1, b0, b1;
        if (n < ne) {
            ld8S(Am, (size_t)n * DH + i0 + c0, a0, a1);
            ld8S(Bm, (size_t)n * DH + j0 + c0, b0, b1);
        } else {
            a0 = make_ushort4(0, 0, 0, 0); a1 = a0; b0 = a0; b1 = a0;
        }
        __syncthreads();   // previous chunk's frag reads done; loads above stay in flight
        Ast[c0 + 0][nn] = a0.x; Ast[c0 + 1][nn] = a0.y;
        Ast[c0 + 2][nn] = a0.z; Ast[c0 + 3][nn] = a0.w;
        Ast[c0 + 4][nn] = a1.x; Ast[c0 + 5][nn] = a1.y;
        Ast[c0 + 6][nn] = a1.z; Ast[c0 + 7][nn] = a1.w;
        Bst[c0 + 0][nn] = b0.x; Bst[c0 + 1][nn] = b0.y;
        Bst[c0 + 2][nn] = b0.z; Bst[c0 + 3][nn] = b0.w;
        Bst[c0 + 4][nn] = b1.x; Bst[c0 + 5][nn] = b1.y;
        Bst[c0 + 6][nn] = b1.z; Bst[c0 + 7][nn] = b1.w;
        __syncthreads();
        bf16x8 af = *(const bf16x8*)&Ast[wave * 16 + nl][quad * 8];
#pragma unroll
        for (int ct = 0; ct < 4; ++ct) {
            bf16x8 bfg = *(const bf16x8*)&Bst[ct * 16 + nl][quad * 8];
            acc[ct] = __builtin_amdgcn_mfma_f32_16x16x32_bf16(af, bfg, acc[ct], 0, 0, 0);
        }
    }
#pragma unroll
    for (int ct = 0; ct < 4; ++ct)
#pragma unroll
        for (int r = 0; r < 4; ++r)
            atomicAdd(&D[(size_t)(i0 + wave * 16 + quad * 4 + r) * DH + j0 + ct * 16 + nl], acc[ct][r]);
}

// ---------------- kvs f32 -> bf16 convert (once; attn re-reads it 1563x) ----------------
__global__ __launch_bounds__(256) void kvs2b_kernel(const float* __restrict__ kvs,
                                                    unsigned short* __restrict__ kvsb)
{
    int i = blockIdx.x * 256 + threadIdx.x;      // 8192 threads x 8 elems = 65536
    size_t o = (size_t)i * 8;
    float4 a = *(const float4*)(kvs + o);
    float4 b = *(const float4*)(kvs + o + 4);
    *(ushort4*)(kvsb + o)     = make_ushort4(f2b(a.x), f2b(a.y), f2b(a.z), f2b(a.w));
    *(ushort4*)(kvsb + o + 4) = make_ushort4(f2b(b.x), f2b(b.y), f2b(b.z), f2b(b.w));
}

// ---------------- MFMA attention: out = (Q@kvs*scale + N*V) / (Q.ks_sum*scale + N) ----------------
// kvsb: kvs transposed, bf16, row-major [256][256] (L2-resident, 128KB).
// Col-split gridDim.y=2 (64 rows x 128 cols, acc[8]); ALL 8 Q-fragments
// prefetched into registers before the barrier -> K-loop has no HBM chain.
template <typename ST>
__global__ __launch_bounds__(256) void attn_mfma(
    const ST* __restrict__ Q, const ST* __restrict__ V,
    const unsigned short* __restrict__ kvsb, const float* __restrict__ ks_sum,
    const float* __restrict__ qss, const float* __restrict__ kss,
    ST* __restrict__ out)
{
    __shared__ float ks_s[DH];
    __shared__ float nrm_s[64];
    const int tid = threadIdx.x;
    const int wave = tid >> 6, lane = tid & 63;
    const int quad = lane >> 4, nl = lane & 15;
    const int m0 = blockIdx.x * 64;
    const int j0 = blockIdx.y * 128;

    // -- prefetch all 8 Q fragments first (independent of LDS/barrier) --
    const int arow = m0 + wave * 16 + nl;
    const int av = (arow < NN);
    const size_t abase = (size_t)arow * DH + quad * 8;
    ushort4 pq0[8], pq1[8];
#pragma unroll
    for (int s = 0; s < 8; ++s) {
        if (av) ld8S(Q, abase + s * 32, pq0[s], pq1[s]);
        else { pq0[s] = make_ushort4(0, 0, 0, 0); pq1[s] = pq0[s]; }
    }

    ks_s[tid] = ks_sum[tid];
    __syncthreads();

    f32x4 acc[8];
#pragma unroll
    for (int i = 0; i < 8; ++i) acc[i] = (f32x4){0.f, 0.f, 0.f, 0.f};
    float nrm = 0.f;

#pragma unroll
    for (int s = 0; s < 8; ++s) {
        const int k0 = s * 32;
        bf16x8 af;
        ((ushort4*)&af)[0] = pq0[s]; ((ushort4*)&af)[1] = pq1[s];
#pragma unroll
        for (int j = 0; j < 8; ++j)
            nrm += bits2f(((const unsigned short*)&af)[j]) * ks_s[k0 + quad * 8 + j];
        const unsigned short* kb = kvsb + (size_t)(j0 + nl) * DH + k0 + quad * 8;
#pragma unroll
        for (int ct = 0; ct < 8; ++ct) {
            bf16x8 bfg = *(const bf16x8*)(kb + (size_t)ct * 16 * DH);
            acc[ct] = __builtin_amdgcn_mfma_f32_16x16x32_bf16(af, bfg, acc[ct], 0, 0, 0);
        }
    }
    nrm += __shfl_xor(nrm, 16);
    nrm += __shfl_xor(nrm, 32);
    if (lane < 16) nrm_s[wave * 16 + lane] = nrm;
    __syncthreads();
    const float scale = rsqrtf(*qss) * rsqrtf(*kss);
#pragma unroll
    for (int r = 0; r < 4; ++r) {
        int row = m0 + wave * 16 + quad * 4 + r;
        if (row >= NN) continue;
        float den = nrm_s[wave * 16 + quad * 4 + r] * scale + (float)NN;
#pragma unroll
        for (int ct = 0; ct < 8; ++ct) {
            int col = j0 + ct * 16 + nl;
            float v = ldS(V, (size_t)row * DH + col);
            float numv = acc[ct][r] * scale + (float)NN * v;
            stS(out, (size_t)row * DH + col, numv / den);
        }
    }
}

// ---------------- LayerNorm over D=256: one wave per row, 4 rows/block ----------------
template <typename ST>
__global__ __launch_bounds__(256) void ln_kernel(
    const ST* __restrict__ A, const ST* __restrict__ B,
    float alpha, float beta,
    const void* __restrict__ g, const void* __restrict__ b,
    ST* __restrict__ out, int relu, const int* __restrict__ flags)
{
    const int isbf = flags[0];
    const int wave = threadIdx.x >> 6, lane = threadIdx.x & 63;
    const int row = blockIdx.x * 4 + wave;
    if (row >= NN) return;
    const size_t base = (size_t)row * DH + lane * 4;
    float4 v = ld4S(&A[base]);
    v.x *= alpha; v.y *= alpha; v.z *= alpha; v.w *= alpha;
    if (B) {
        float4 w = ld4S(&B[base]);
        v.x += beta * w.x; v.y += beta * w.y; v.z += beta * w.z; v.w += beta * w.w;
    }
    float s = v.x + v.y + v.z + v.w;
    float s2 = v.x * v.x + v.y * v.y + v.z * v.z + v.w * v.w;
#pragma unroll
    for (int off = 32; off > 0; off >>= 1) {
        s += __shfl_xor(s, off);
        s2 += __shfl_xor(s2, off);
    }
    float mean = s * (1.f / DH);
    float var = s2 * (1.f / DH) - mean * mean;
    float rstd = rsqrtf(var + 1e-5f);
    float4 o;
    o.x = (v.x - mean) * rstd * ldf(g, lane * 4 + 0, isbf) + ldf(b, lane * 4 + 0, isbf);
    o.y = (v.y - mean) * rstd * ldf(g, lane * 4 + 1, isbf) + ldf(b, lane * 4 + 1, isbf);
    o.z = (v.z - mean) * rstd * ldf(g, lane * 4 + 2, isbf) + ldf(b, lane * 4 + 2, isbf);
    o.w = (v.w - mean) * rstd * ldf(g, lane * 4 + 3, isbf) + ldf(b, lane * 4 + 3, isbf);
    if (relu) {
        o.x = fmaxf(o.x, 0.f); o.y = fmaxf(o.y, 0.f);
        o.z = fmaxf(o.z, 0.f); o.w = fmaxf(o.w, 0.f);
    }
    st4S(&out[base], o);
}

// ---------------- sum of squares ----------------
template <typename ST>
__global__ __launch_bounds__(256) void sumsq_kernel(
    const ST* __restrict__ A, size_t n, float* __restrict__ out)
{
    __shared__ float ps[4];
    size_t i = (size_t)blockIdx.x * blockDim.x + threadIdx.x;
    size_t stride = (size_t)gridDim.x * blockDim.x;
    float s = 0.f;
    for (; i < n; i += stride) { float v = ldS(A, i); s += v * v; }
#pragma unroll
    for (int off = 32; off > 0; off >>= 1) s += __shfl_down(s, off);
    if ((threadIdx.x & 63) == 0) ps[threadIdx.x >> 6] = s;
    __syncthreads();
    if (threadIdx.x == 0) atomicAdd(out, ps[0] + ps[1] + ps[2] + ps[3]);
}

// ---------------- ks_sum[j] = sum_n K[n][j] (rows-per-block from gridDim) ----------------
template <typename ST>
__global__ __launch_bounds__(256) void colsum_kernel(
    const ST* __restrict__ Km, float* __restrict__ out)
{
    const int t = threadIdx.x;
    const int per = (NN + gridDim.x - 1) / gridDim.x;
    size_t r0 = (size_t)blockIdx.x * per;
    size_t r1 = r0 + per; if (r1 > NN) r1 = NN;
    float s = 0.f;
    for (size_t r = r0; r < r1; ++r) s += ldS(Km, r * DH + t);
    atomicAdd(&out[t], s);
}

// ---------------- CSR build ----------------
__global__ __launch_bounds__(256) void count_kernel(const int* __restrict__ ei, int* __restrict__ cnt,
                                                    const int* __restrict__ flags)
{
    int e = blockIdx.x * 256 + threadIdx.x;
    if (e >= NE) return;
    int d = ld_dst(ei, e, flags[1]);
    if ((unsigned)d < NN) atomicAdd(&cnt[d], 1);
}

__global__ __launch_bounds__(256) void scan_block_kernel(const int* __restrict__ cnt,
                                                         int* __restrict__ pre, int* __restrict__ bsum)
{
    __shared__ int s[256];
    int i = blockIdx.x * 256 + threadIdx.x;
    int v = (i < NN) ? cnt[i] : 0;
    s[threadIdx.x] = v;
    __syncthreads();
    for (int off = 1; off < 256; off <<= 1) {
        int t = (threadIdx.x >= off) ? s[threadIdx.x - off] : 0;
        __syncthreads();
        s[threadIdx.x] += t;
        __syncthreads();
    }
    if (i < NN) pre[i] = s[threadIdx.x] - v;
    if (threadIdx.x == 255) bsum[blockIdx.x] = s[255];
}

__global__ __launch_bounds__(512) void scan_partial_kernel(int* __restrict__ bsum, int nb)
{
    __shared__ int s[512];
    int t = threadIdx.x;
    int v = (t < nb) ? bsum[t] : 0;
    s[t] = v;
    __syncthreads();
    for (int off = 1; off < 512; off <<= 1) {
        int u = (t >= off) ? s[t - off] : 0;
        __syncthreads();
        s[t] += u;
        __syncthreads();
    }
    if (t < nb) bsum[t] = s[t] - v;
}

__global__ __launch_bounds__(256) void finalize_kernel(int* __restrict__ base, const int* __restrict__ bsum,
                                                       const int* __restrict__ cnt, int* __restrict__ cursor,
                                                       float* __restrict__ dinv)
{
    int i = blockIdx.x * 256 + threadIdx.x;
    if (i >= NN) return;
    int b = base[i] + bsum[blockIdx.x];
    base[i] = b;
    cursor[i] = b;
    dinv[i] = rsqrtf((float)cnt[i] + 1.0f);
}

__global__ __launch_bounds__(256) void scatter_kernel(const int* __restrict__ ei, int* __restrict__ cursor,
                                                      int* __restrict__ srcs, const int* __restrict__ flags)
{
    int e = blockIdx.x * 256 + threadIdx.x;
    if (e >= NE) return;
    int i64 = flags[1];
    int s = ld_src(ei, e, i64), d = ld_dst(ei, e, i64);
    if ((unsigned)s >= NN || (unsigned)d >= NN) return;
    int pos = atomicAdd(&cursor[d], 1);
    srcs[pos] = s;
}

// ---------------- FUSED CSR gather + GCN epilogue: one wave per node ----------------
// MODE 0: out = relu((agg + own*di^2 + b) * bn_g/sqrt(1+eps) + bn_b)
// MODE 1: out = 0.8*(agg + own*di^2 + b) + 0.2*Ht
// 4-way unrolled: 4 independent {src,dinv,row} chains in flight per wave for MLP.
template <typename ST, int MODE>
__global__ __launch_bounds__(256) void fgather_kernel(
    const ST* __restrict__ Hs, const ST* __restrict__ Ht,
    const int* __restrict__ base, const int* __restrict__ cnt,
    const int* __restrict__ srcs, const float* __restrict__ dinv,
    const void* __restrict__ bias, const void* __restrict__ bng, const void* __restrict__ bnb,
    const int* __restrict__ flags, ST* __restrict__ out)
{
    const int isbf = flags[0];
    int node = blockIdx.x * 4 + (threadIdx.x >> 6);
    int lane = threadIdx.x & 63;
    if (node >= NN) return;
    int b0 = base[node], deg = cnt[node];
    float dd = dinv[node];
    float4 a0 = make_float4(0.f, 0.f, 0.f, 0.f);
    float4 a1 = make_float4(0.f, 0.f, 0.f, 0.f);
    int j = 0;
    for (; j + 4 <= deg; j += 4) {      // 4 independent row-chains in flight
        int s0 = srcs[b0 + j + 0], s1 = srcs[b0 + j + 1];
        int s2 = srcs[b0 + j + 2], s3 = srcs[b0 + j + 3];
        float n0 = dd * dinv[s0], n1 = dd * dinv[s1];
        float n2 = dd * dinv[s2], n3 = dd * dinv[s3];
        float4 h0 = ld4S(&Hs[(size_t)s0 * DH + lane * 4]);
        float4 h1 = ld4S(&Hs[(size_t)s1 * DH + lane * 4]);
        float4 h2 = ld4S(&Hs[(size_t)s2 * DH + lane * 4]);
        float4 h3 = ld4S(&Hs[(size_t)s3 * DH + lane * 4]);
        a0.x += h0.x * n0; a0.y += h0.y * n0; a0.z += h0.z * n0; a0.w += h0.w * n0;
        a1.x += h1.x * n1; a1.y += h1.y * n1; a1.z += h1.z * n1; a1.w += h1.w * n1;
        a0.x += h2.x * n2; a0.y += h2.y * n2; a0.z += h2.z * n2; a0.w += h2.w * n2;
        a1.x += h3.x * n3; a1.y += h3.y * n3; a1.z += h3.z * n3; a1.w += h3.w * n3;
    }
    for (; j < deg; ++j) {
        int s0 = srcs[b0 + j];
        float n0 = dd * dinv[s0];
        float4 h0 = ld4S(&Hs[(size_t)s0 * DH + lane * 4]);
        a0.x += h0.x * n0; a0.y += h0.y * n0; a0.z += h0.z * n0; a0.w += h0.w * n0;
    }
    const size_t obase = (size_t)node * DH + lane * 4;
    float4 own = ld4S(&Hs[obase]);
    float di2 = dd * dd;
    int c = lane * 4;
    float4 v;
    v.x = a0.x + a1.x + own.x * di2 + ldf(bias, c + 0, isbf);
    v.y = a0.y + a1.y + own.y * di2 + ldf(bias, c + 1, isbf);
    v.z = a0.z + a1.z + own.z * di2 + ldf(bias, c + 2, isbf);
    v.w = a0.w + a1.w + own.w * di2 + ldf(bias, c + 3, isbf);
    if (MODE == 0) {
        const float bnscale = 0.99999500003749981f;  // 1/sqrt(1+1e-5)
        v.x = fmaxf(v.x * (ldf(bng, c + 0, isbf) * bnscale) + ldf(bnb, c + 0, isbf), 0.f);
        v.y = fmaxf(v.y * (ldf(bng, c + 1, isbf) * bnscale) + ldf(bnb, c + 1, isbf), 0.f);
        v.z = fmaxf(v.z * (ldf(bng, c + 2, isbf) * bnscale) + ldf(bnb, c + 2, isbf), 0.f);
        v.w = fmaxf(v.w * (ldf(bng, c + 3, isbf) * bnscale) + ldf(bnb, c + 3, isbf), 0.f);
    } else {
        float4 t = ld4S(&Ht[obase]);
        v.x = 0.8f * v.x + 0.2f * t.x;
        v.y = 0.8f * v.y + 0.2f * t.y;
        v.z = 0.8f * v.z + 0.2f * t.z;
        v.w = 0.8f * v.w + 0.2f * t.w;
    }
    st4S(&out[obase], v);
}

// ---------------- fallback (atomic) GCN pieces ----------------
__global__ __launch_bounds__(256) void deg_kernel(const int* __restrict__ ei, float* __restrict__ deg,
                                                  const int* __restrict__ flags)
{
    int i64 = flags[1];
    int e = blockIdx.x * 256 + threadIdx.x;
    if (e >= NE) return;
    int d = ld_dst(ei, e, i64);
    if ((unsigned)d < NN) atomicAdd(&deg[d], 1.0f);
}

__global__ __launch_bounds__(256) void dinv_kernel(float* __restrict__ deg)
{
    int i = blockIdx.x * 256 + threadIdx.x;
    if (i < NN) deg[i] = rsqrtf(deg[i] + 1.0f);
}

template <typename ST>
__global__ __launch_bounds__(256) void agg_kernel(
    const ST* __restrict__ Hs, const int* __restrict__ ei,
    const float* __restrict__ dinv, float* __restrict__ lo, float* __restrict__ hi,
    const int* __restrict__ flags)
{
    int i64 = flags[1];
    int e = blockIdx.x * 4 + (threadIdx.x >> 6);
    int lane = threadIdx.x & 63;
    if (e >= NE) return;
    int s = ld_src(ei, e, i64), d = ld_dst(ei, e, i64);
    if ((unsigned)s >= NN || (unsigned)d >= NN) return;
    float nrm = dinv[s] * dinv[d];
    const float4 h4 = ld4S(&Hs[(size_t)s * DH + lane * 4]);
    float* o = (d < NSPL ? &lo[(size_t)d * DH] : &hi[(size_t)(d - NSPL) * DH]) + lane * 4;
    atomicAdd(o + 0, h4.x * nrm);
    atomicAdd(o + 1, h4.y * nrm);
    atomicAdd(o + 2, h4.z * nrm);
    atomicAdd(o + 3, h4.w * nrm);
}

// self-loop + bias + BN(eval) + relu
template <typename ST>
__global__ __launch_bounds__(256) void gcn_epi1_kernel(
    const float* __restrict__ lo, const float* __restrict__ hi,
    const ST* __restrict__ h1, const float* __restrict__ dinv,
    const void* __restrict__ b0, const void* __restrict__ bng, const void* __restrict__ bnb,
    const int* __restrict__ flags, ST* __restrict__ out)
{
    const int isbf = flags[0];
    size_t idx = (size_t)blockIdx.x * 256 + threadIdx.x;
    if (idx >= (size_t)NN * DH) return;
    int i = (int)(idx >> 8), c = (int)(idx & 255);
    float aggv = (i < NSPL) ? lo[idx] : hi[idx - NSO];
    float di = dinv[i];
    float v = aggv + ldS(h1, idx) * di * di + ldf(b0, c, isbf);
    const float bnscale = 0.99999500003749981f;  // 1/sqrt(1+1e-5)
    v = v * (ldf(bng, c, isbf) * bnscale) + ldf(bnb, c, isbf);
    stS(out, idx, fmaxf(v, 0.f));
}

// self-loop + bias + combine: emb = 0.8*(agg + self + b1) + 0.2*x_trans
template <typename ST>
__global__ __launch_bounds__(256) void gcn_epi2_kernel(
    const float* __restrict__ lo, const float* __restrict__ hi,
    const ST* __restrict__ h2, const ST* __restrict__ Ht, const float* __restrict__ dinv,
    const void* __restrict__ b1, const int* __restrict__ flags, ST* __restrict__ out)
{
    const int isbf = flags[0];
    size_t idx = (size_t)blockIdx.x * 256 + threadIdx.x;
    if (idx >= (size_t)NN * DH) return;
    int i = (int)(idx >> 8), c = (int)(idx & 255);
    float aggv = (i < NSPL) ? lo[idx] : hi[idx - NSO];
    float di = dinv[i];
    float g = aggv + ldS(h2, idx) * di * di + ldf(b1, c, isbf);
    stS(out, idx, 0.8f * g + 0.2f * ldS(Ht, idx));
}

// ---------------- diagnostic ----------------
__global__ __launch_bounds__(256) void diag_kernel(float* out, size_t n, float val)
{
    size_t i = (size_t)blockIdx.x * 256 + threadIdx.x;
    if (i < n) out[i] = val;
}

// ---------------- pipeline ----------------
template <typename ST>
static void run_pipeline(void* const* d_in, void* d_out, char* wsb, hipStream_t stream, int use_csr)
{
    const void* x      = d_in[0];
    const int*  ei     = (const int*)d_in[1];
    const void* fc0_w  = d_in[2];  const void* fc0_b  = d_in[3];
    const void* ln0_g  = d_in[4];  const void* ln0_b  = d_in[5];
    const void* wq0_w  = d_in[6];  const void* wq0_b  = d_in[7];
    const void* wk0_w  = d_in[8];  const void* wk0_b  = d_in[9];
    const void* wv0_w  = d_in[10]; const void* wv0_b  = d_in[11];
    const void* ln1_g  = d_in[12]; const void* ln1_b  = d_in[13];
    const void* wq1_w  = d_in[14]; const void* wq1_b  = d_in[15];
    const void* wk1_w  = d_in[16]; const void* wk1_b  = d_in[17];
    const void* wv1_w  = d_in[18]; const void* wv1_b  = d_in[19];
    const void* ln2_g  = d_in[20]; const void* ln2_b  = d_in[21];
    const void* gcn_w0 = d_in[22]; const void* gcn_b0 = d_in[23];
    const void* bn_g   = d_in[24]; const void* bn_b   = d_in[25];
    const void* gcn_w1 = d_in[26]; const void* gcn_b1 = d_in[27];
    const void* fc_w   = d_in[28]; const void* fc_b   = d_in[29];

    const size_t stN = (size_t)NN * DH * sizeof(ST);
    ST* H  = (ST*)(wsb);
    ST* Qb = (ST*)(wsb + stN);
    ST* Kb = (ST*)(wsb + 2 * stN);
    ST* Vb = (ST*)(wsb + 3 * stN);
    float* aux = (float*)(wsb + 4 * stN);
    float* kvs    = aux;
    float* ks_sum = aux + 65536;
    float* qss    = aux + 65792;
    float* kss    = aux + 65793;
    float* dinv   = aux + 65808;
    int*   flags  = (int*)(aux + 65808 + NN);
    int* cnt    = (int*)(aux + 65808 + NN + 16);
    int* base   = cnt + NN;
    int* cursor = base + NN;
    int* bsum   = cursor + NN;       // 512
    int* srcs   = bsum + 512;        // NE
    // dinv region (NN floats = 400KB) is dead until the GCN branch; borrow 128KB
    // of it for the bf16 copy of kvsT during the attention layers.
    unsigned short* kvsb = (unsigned short*)dinv;

    const int asel = (sizeof(ST) == 2) ? 1 : 0;
    dim3 mfmaGrid((NN + 127) / 128, DH / 64);
    const size_t NELEM = (size_t)NN * DH;

    detect_kernel<<<1, 256, 0, stream>>>(x, ei, flags);

    // ---- TransConv input layer ----
    gemm_mfma<ST><<<mfmaGrid, 512, 0, stream>>>(x, fc0_w, fc0_b, Qb, NN, DH, flags, 2);
    ln_kernel<ST><<<(NN + 3) / 4, 256, 0, stream>>>(Qb, (const ST*)nullptr, 1.f, 0.f, ln0_g, ln0_b, H, 1, flags);

    // ---- two attention layers ----
    for (int layer = 0; layer < 2; ++layer) {
        const void *qw, *qb, *kw, *kb, *vw, *vb, *lg, *lb;
        if (layer == 0) { qw = wq0_w; qb = wq0_b; kw = wk0_w; kb = wk0_b; vw = wv0_w; vb = wv0_b; lg = ln1_g; lb = ln1_b; }
        else            { qw = wq1_w; qb = wq1_b; kw = wk1_w; kb = wk1_b; vw = wv1_w; vb = wv1_b; lg = ln2_g; lb = ln2_b; }
        gemm_mfma<ST><<<mfmaGrid, 512, 0, stream>>>(H, qw, qb, Qb, NN, DH, flags, asel);
        gemm_mfma<ST><<<mfmaGrid, 512, 0, stream>>>(H, kw, kb, Kb, NN, DH, flags, asel);
        gemm_mfma<ST><<<mfmaGrid, 512, 0, stream>>>(H, vw, vb, Vb, NN, DH, flags, asel);
        hipMemsetAsync(aux, 0, (65536 + 256 + 2) * sizeof(float), stream);
        sumsq_kernel<ST><<<2048, 256, 0, stream>>>(Qb, NELEM, qss);
        sumsq_kernel<ST><<<2048, 256, 0, stream>>>(Kb, NELEM, kss);
        // kvs stored TRANSPOSED: kvs[j][i] = sum_n V[n][j] K[n][i]
        kvs_mfma<ST><<<dim3(4, 4, 128), 256, 0, stream>>>(Vb, Kb, kvs);
        colsum_kernel<ST><<<800, 256, 0, stream>>>(Kb, ks_sum);
        kvs2b_kernel<<<32, 256, 0, stream>>>(kvs, kvsb);
        attn_mfma<ST><<<dim3((NN + 63) / 64, 2), 256, 0, stream>>>(Qb, Vb, kvsb, ks_sum, qss, kss, Kb);
        ln_kernel<ST><<<(NN + 3) / 4, 256, 0, stream>>>(Kb, H, 0.5f, 0.5f, lg, lb, H, 0, flags);
    }

    // ---- GCN branch ----
    if (use_csr) {
        hipMemsetAsync(cnt, 0, NN * sizeof(int), stream);
        count_kernel<<<(NE + 255) / 256, 256, 0, stream>>>(ei, cnt, flags);
        scan_block_kernel<<<NBLK, 256, 0, stream>>>(cnt, base, bsum);
        scan_partial_kernel<<<1, 512, 0, stream>>>(bsum, NBLK);
        finalize_kernel<<<NBLK, 256, 0, stream>>>(base, bsum, cnt, cursor, dinv);
        scatter_kernel<<<(NE + 255) / 256, 256, 0, stream>>>(ei, cursor, srcs, flags);

        // fused path: h1 -> Qb; fused gather+BN+relu -> Kb; h2 -> Vb;
        // fused gather+combine -> Qb (emb); classifier reads Qb.
        gemm_mfma<ST><<<mfmaGrid, 512, 0, stream>>>(x, gcn_w0, nullptr, Qb, NN, DH, flags, 2);
        fgather_kernel<ST, 0><<<(NN + 3) / 4, 256, 0, stream>>>(
            Qb, (const ST*)nullptr, base, cnt, srcs, dinv, gcn_b0, bn_g, bn_b, flags, Kb);
        gemm_mfma<ST><<<mfmaGrid, 512, 0, stream>>>(Kb, gcn_w1, nullptr, Vb, NN, DH, flags, asel);
        fgather_kernel<ST, 1><<<(NN + 3) / 4, 256, 0, stream>>>(
            Vb, H, base, cnt, srcs, dinv, gcn_b1, nullptr, nullptr, flags, Qb);

        gemm_mfma<float><<<dim3((NN + 127) / 128, 1), 512, 0, stream>>>(Qb, fc_w, fc_b, (float*)d_out, NN, DOUT, flags, asel);
    } else {
        float* a1lo = (float*)(wsb + 2 * stN);
        float* a1hi = a1lo + NSO;
        ST* h2; float *a2lo, *a2hi;
        if (sizeof(ST) == 4) { h2 = Vb; a2lo = (float*)(wsb + 2 * stN); a2hi = a2lo + NSO; }
        else                 { h2 = Kb; a2lo = (float*)(wsb + stN);     a2hi = (float*)(wsb + 3 * stN); }

        hipMemsetAsync(dinv, 0, NN * sizeof(float), stream);
        deg_kernel<<<(NE + 255) / 256, 256, 0, stream>>>(ei, dinv, flags);
        dinv_kernel<<<(NN + 255) / 256, 256, 0, stream>>>(dinv);

        gemm_mfma<ST><<<mfmaGrid, 512, 0, stream>>>(x, gcn_w0, nullptr, Qb, NN, DH, flags, 2);
        hipMemsetAsync(a1lo, 0, NELEM * sizeof(float), stream);
        agg_kernel<ST><<<(NE + 3) / 4, 256, 0, stream>>>(Qb, ei, dinv, a1lo, a1hi, flags);
        gcn_epi1_kernel<ST><<<(NELEM + 255) / 256, 256, 0, stream>>>(a1lo, a1hi, Qb, dinv, gcn_b0, bn_g, bn_b, flags, Qb);

        gemm_mfma<ST><<<mfmaGrid, 512, 0, stream>>>(Qb, gcn_w1, nullptr, h2, NN, DH, flags, asel);
        hipMemsetAsync(a2lo, 0, NSO * sizeof(float), stream);
        hipMemsetAsync(a2hi, 0, NSO * sizeof(float), stream);
        agg_kernel<ST><<<(NE + 3) / 4, 256, 0, stream>>>(h2, ei, dinv, a2lo, a2hi, flags);
        gcn_epi2_kernel<ST><<<(NELEM + 255) / 256, 256, 0, stream>>>(a2lo, a2hi, h2, H, dinv, gcn_b1, flags, h2);

        gemm_mfma<float><<<dim3((NN + 127) / 128, 1), 512, 0, stream>>>(h2, fc_w, fc_b, (float*)d_out, NN, DOUT, flags, asel);
    }
}

extern "C" void kernel_launch(void* const* d_in, const int* in_sizes, int n_in,
                              void* d_out, int out_size, void* d_ws, size_t ws_size,
                              hipStream_t stream)
{
    char* wsb = (char*)d_ws;
    const size_t AUXF  = 65808 + NN + 16;
    const size_t CSRI  = 3 * (size_t)NN + 512 + NE;
    const size_t AUXB  = AUXF * sizeof(float);
    const size_t AUXB2 = AUXB + CSRI * sizeof(int);
    const size_t needA  = 4 * ((size_t)NN * DH * 4) + AUXB;
    const size_t needA2 = 4 * ((size_t)NN * DH * 4) + AUXB2;
    const size_t needB  = 4 * ((size_t)NN * DH * 2) + AUXB;
    const size_t needB2 = 4 * ((size_t)NN * DH * 2) + AUXB2;

    if (ws_size >= needA) {
        run_pipeline<float>(d_in, d_out, wsb, stream, ws_size >= needA2);
    } else if (ws_size >= needB) {
        run_pipeline<bf16>(d_in, d_out, wsb, stream, ws_size >= needB2);
    } else {
        float mb = (float)(ws_size >> 20);
        size_t n = (size_t)out_size;
        diag_kernel<<<(n + 255) / 256, 256, 0, stream>>>((float*)d_out, n, mb);
    }
}

// Round 8
// 1888.950 us; speedup vs baseline: 1.5669x; 1.0177x over previous
//
#include <hip/hip_runtime.h>
#include <hip/hip_bf16.h>

#define NN 100000
#define NE 800000
#define DH 256
#define DOUT 64
#define NSPL 50000                      // GCN agg row split
#define NSO ((size_t)NSPL * DH)        // elems per half
#define NBLK 391                       // ceil(NN/256)

using bf16 = __hip_bfloat16;
typedef __attribute__((ext_vector_type(8))) short bf16x8;
typedef __attribute__((ext_vector_type(4))) float f32x4;

// ---------------- dtype helpers ----------------
__device__ __forceinline__ float bits2f(unsigned short h) {
    union { unsigned int u; float f; } c; c.u = ((unsigned int)h) << 16; return c.f;
}
__device__ __forceinline__ unsigned short f2b(float v) {
    union { float f; unsigned int u; } c; c.f = v;
    unsigned int u = c.u;
    return (unsigned short)((u + 0x7FFFu + ((u >> 16) & 1u)) >> 16);  // RNE
}
__device__ __forceinline__ unsigned short tob(float v) { return f2b(v); }
__device__ __forceinline__ unsigned short tob(bf16 v) {
    union { bf16 b; unsigned short u; } c; c.b = v; return c.u;
}
__device__ __forceinline__ float ldf(const void* p, size_t i, int isbf) {
    if (isbf) return bits2f(((const unsigned short*)p)[i]);
    return ((const float*)p)[i];
}
__device__ __forceinline__ float ldS(const float* p, size_t i) { return p[i]; }
__device__ __forceinline__ float ldS(const bf16* p, size_t i) { return __bfloat162float(p[i]); }
__device__ __forceinline__ void stS(float* p, size_t i, float v) { p[i] = v; }
__device__ __forceinline__ void stS(bf16* p, size_t i, float v) { p[i] = __float2bfloat16(v); }
// value as it will be read back from the output buffer (for fused reductions)
template <typename ST> __device__ __forceinline__ float storedS(float v);
template <> __device__ __forceinline__ float storedS<float>(float v) { return v; }
template <> __device__ __forceinline__ float storedS<bf16>(float v) { return bits2f(f2b(v)); }
__device__ __forceinline__ float4 ld4S(const float* p) { return *(const float4*)p; }
__device__ __forceinline__ float4 ld4S(const bf16* p) {
    ushort4 u = *(const ushort4*)(const void*)p;
    return make_float4(bits2f(u.x), bits2f(u.y), bits2f(u.z), bits2f(u.w));
}
__device__ __forceinline__ void st4S(float* p, float4 v) { *(float4*)p = v; }
__device__ __forceinline__ void st4S(bf16* p, float4 v) {
    *(ushort4*)(void*)p = make_ushort4(f2b(v.x), f2b(v.y), f2b(v.z), f2b(v.w));
}
// load 8 consecutive elems (16B-aligned) as bf16 bit patterns from f32 or bf16 source
__device__ __forceinline__ void ld8(const void* p, size_t idx, int isbf, ushort4& o0, ushort4& o1) {
    if (isbf) {
        const ushort4* q = (const ushort4*)((const unsigned short*)p + idx);
        o0 = q[0]; o1 = q[1];
    } else {
        const float4* q = (const float4*)((const float*)p + idx);
        float4 a = q[0], b = q[1];
        o0 = make_ushort4(f2b(a.x), f2b(a.y), f2b(a.z), f2b(a.w));
        o1 = make_ushort4(f2b(b.x), f2b(b.y), f2b(b.z), f2b(b.w));
    }
}
__device__ __forceinline__ void ld8S(const bf16* p, size_t idx, ushort4& o0, ushort4& o1) {
    const ushort4* q = (const ushort4*)((const unsigned short*)p + idx);
    o0 = q[0]; o1 = q[1];
}
__device__ __forceinline__ void ld8S(const float* p, size_t idx, ushort4& o0, ushort4& o1) {
    const float4* q = (const float4*)(p + idx);
    float4 a = q[0], b = q[1];
    o0 = make_ushort4(f2b(a.x), f2b(a.y), f2b(a.z), f2b(a.w));
    o1 = make_ushort4(f2b(b.x), f2b(b.y), f2b(b.z), f2b(b.w));
}
__device__ __forceinline__ int ld_src(const int* ei, int e, int i64) {
    return i64 ? ei[2 * (size_t)e] : ei[e];
}
__device__ __forceinline__ int ld_dst(const int* ei, int e, int i64) {
    return i64 ? ei[2 * ((size_t)NE + e)] : ei[NE + e];
}

// ---------------- dtype detector (sampled) ----------------
__global__ __launch_bounds__(256) void detect_kernel(const void* x, const int* ei, int* flags)
{
    __shared__ int s_sane[4], s_nz[4];
    int t = threadIdx.x;
    const unsigned short* xu = (const unsigned short*)x;
    int sane = 0;
    for (int i = t; i < 2048; i += 256) {
        float v = bits2f(xu[2 * i]);
        float a = fabsf(v);
        if (v == v && a > 1e-3f && a < 100.f) sane++;
    }
    int nz = 0;
    for (int i = t; i < 4096; i += 256) {
        if (ei[2 * (i * 122) + 1] != 0) nz++;
    }
#pragma unroll
    for (int off = 32; off > 0; off >>= 1) { sane += __shfl_down(sane, off); nz += __shfl_down(nz, off); }
    if ((t & 63) == 0) { s_sane[t >> 6] = sane; s_nz[t >> 6] = nz; }
    __syncthreads();
    if (t == 0) {
        flags[0] = ((s_sane[0] + s_sane[1] + s_sane[2] + s_sane[3]) > 1024) ? 1 : 0;
        flags[1] = ((s_nz[0] + s_nz[1] + s_nz[2] + s_nz[3]) == 0) ? 1 : 0;
    }
}

// ---------------- MFMA GEMM: C[M,Nc] = A[M,256] @ W[256,Nc] (+bias) ----------------
// 512 threads, 4 M-subtiles of 128 rows per block (512 rows total): B (W^T)
// staged to LDS ONCE and reused 4x; A fragments for subtile t+1 issued BEFORE
// subtile t's MFMAs+stores so HBM latency hides under compute of the previous
// tile. Optional fused reductions over the STORED (rounded) output values:
//   ssq  != null -> atomicAdd sum of squares (replaces sumsq_kernel)
//   csum != null -> atomicAdd per-column sums (replaces colsum_kernel)
template <typename ST>
__global__ __launch_bounds__(512) void gemm_mfma(
    const void* __restrict__ A, const void* __restrict__ W,
    const void* __restrict__ bias, ST* __restrict__ C,
    int M, int Nc, const int* __restrict__ flags, int a_sel,
    float* __restrict__ ssq, float* __restrict__ csum)
{
    __shared__ unsigned short Bs[64][264];   // W^T tile: Bs[n][k], all K
    __shared__ float cs_s[64];
    const int isbf = flags[0];
    const int abf = (a_sel == 2) ? isbf : a_sel;
    const int tid = threadIdx.x;
    const int wave = tid >> 6, lane = tid & 63;
    const int quad = lane >> 4, nl = lane & 15;
    const int m0 = blockIdx.x * 512;
    const int n0 = blockIdx.y * 64;

#pragma unroll
    for (int it = 0; it < 4; ++it) {
        int p8 = it * 512 + tid;
        int k = p8 >> 3, nb = p8 & 7;
        ushort4 w0, w1;
        ld8(W, (size_t)k * Nc + n0 + nb * 8, isbf, w0, w1);
        int nbase = nb * 8;
        Bs[nbase + 0][k] = w0.x; Bs[nbase + 1][k] = w0.y;
        Bs[nbase + 2][k] = w0.z; Bs[nbase + 3][k] = w0.w;
        Bs[nbase + 4][k] = w1.x; Bs[nbase + 5][k] = w1.y;
        Bs[nbase + 6][k] = w1.z; Bs[nbase + 7][k] = w1.w;
    }
    if (csum != nullptr && tid < 64) cs_s[tid] = 0.f;
    __syncthreads();

    const int lrow = wave * 16 + nl;       // lane's row within a 128-row subtile
    float bv[4];
#pragma unroll
    for (int ct = 0; ct < 4; ++ct)
        bv[ct] = bias ? ldf(bias, n0 + ct * 16 + nl, isbf) : 0.f;

    float myssq = 0.f;
    float mycs[4] = {0.f, 0.f, 0.f, 0.f};

    // prefetch subtile 0 A-fragments
    ushort4 c0[8], c1[8], nx0[8], nx1[8];
    {
        int arow = m0 + lrow;
        int av = (arow < M);
        size_t ab = (size_t)arow * DH + quad * 8;
#pragma unroll
        for (int s = 0; s < 8; ++s) {
            if (av) ld8(A, ab + s * 32, abf, c0[s], c1[s]);
            else { c0[s] = make_ushort4(0, 0, 0, 0); c1[s] = c0[s]; }
        }
    }

#pragma unroll
    for (int t = 0; t < 4; ++t) {
        // issue next subtile's loads first -> overlap with this tile's MFMAs
        if (t < 3) {
            int arow = m0 + (t + 1) * 128 + lrow;
            int av = (arow < M);
            size_t ab = (size_t)arow * DH + quad * 8;
#pragma unroll
            for (int s = 0; s < 8; ++s) {
                if (av) ld8(A, ab + s * 32, abf, nx0[s], nx1[s]);
                else { nx0[s] = make_ushort4(0, 0, 0, 0); nx1[s] = nx0[s]; }
            }
        }
        f32x4 acc[4] = {{0.f,0.f,0.f,0.f},{0.f,0.f,0.f,0.f},{0.f,0.f,0.f,0.f},{0.f,0.f,0.f,0.f}};
#pragma unroll
        for (int s = 0; s < 8; ++s) {
            bf16x8 af;
            ((ushort4*)&af)[0] = c0[s]; ((ushort4*)&af)[1] = c1[s];
#pragma unroll
            for (int ct = 0; ct < 4; ++ct) {
                bf16x8 bfg = *(const bf16x8*)&Bs[ct * 16 + nl][s * 32 + quad * 8];
                acc[ct] = __builtin_amdgcn_mfma_f32_16x16x32_bf16(af, bfg, acc[ct], 0, 0, 0);
            }
        }
#pragma unroll
        for (int ct = 0; ct < 4; ++ct) {
            int n = n0 + ct * 16 + nl;
#pragma unroll
            for (int r = 0; r < 4; ++r) {
                int m = m0 + t * 128 + wave * 16 + quad * 4 + r;
                if (m < M) {
                    float v = acc[ct][r] + bv[ct];
                    stS(C, (size_t)m * Nc + n, v);
                    float sv = storedS<ST>(v);
                    myssq += sv * sv;
                    mycs[ct] += sv;
                }
            }
        }
        if (t < 3) {
#pragma unroll
            for (int s = 0; s < 8; ++s) { c0[s] = nx0[s]; c1[s] = nx1[s]; }
        }
    }

    if (ssq != nullptr) {
        float s = myssq;
        s += __shfl_xor(s, 1);  s += __shfl_xor(s, 2);  s += __shfl_xor(s, 4);
        s += __shfl_xor(s, 8);  s += __shfl_xor(s, 16); s += __shfl_xor(s, 32);
        if (lane == 0) atomicAdd(ssq, s);
    }
    if (csum != nullptr) {
#pragma unroll
        for (int ct = 0; ct < 4; ++ct)
            atomicAdd(&cs_s[ct * 16 + nl], mycs[ct]);
        __syncthreads();
        if (tid < 64) atomicAdd(&csum[n0 + tid], cs_s[tid]);
    }
}

// ---------------- MFMA kvs: D[256,256] = A^T @ B over N (split-N, atomic f32) ----------------
// call with (Vm, Km, kvs): D[j][i] = sum_n V[n][j]*K[n][i]  == kvs transposed, row-major
template <typename ST>
__global__ __launch_bounds__(256) void kvs_mfma(
    const ST* __restrict__ Am, const ST* __restrict__ Bm, float* __restrict__ D)
{
    __shared__ unsigned short Ast[64][36];
    __shared__ unsigned short Bst[64][36];
    const int tid = threadIdx.x;
    const int wave = tid >> 6, lane = tid & 63;
    const int quad = lane >> 4, nl = lane & 15;
    const int i0 = blockIdx.x * 64, j0 = blockIdx.y * 64;   // i0: D rows (A cols), j0: D cols (B cols)
    const int S = gridDim.z;
    const int chunk = (NN + S - 1) / S;
    const int ns = blockIdx.z * chunk;
    const int ne = min(ns + chunk, NN);
    const int nn = tid >> 3;          // row within 32-row chunk (0..31)
    const int c0 = (tid & 7) * 8;     // col offset within 64-col tile (0,8,...,56)
    f32x4 acc[4] = {{0.f,0.f,0.f,0.f},{0.f,0.f,0.f,0.f},{0.f,0.f,0.f,0.f},{0.f,0.f,0.f,0.f}};

    for (int n0 = ns; n0 < ne; n0 += 32) {
        int n = n0 + nn;
        ushort4 a0, a1, b0, b1;
        if (n < ne) {
            ld8S(Am, (size_t)n * DH + i0 + c0, a0, a1);
            ld8S(Bm, (size_t)n * DH + j0 + c0, b0, b1);
        } else {
            a0 = make_ushort4(0, 0, 0, 0); a1 = a0; b0 = a0; b1 = a0;
        }
        __syncthreads();   // previous chunk's frag reads done; loads above stay in flight
        Ast[c0 + 0][nn] = a0.x; Ast[c0 + 1][nn] = a0.y;
        Ast[c0 + 2][nn] = a0.z; Ast[c0 + 3][nn] = a0.w;
        Ast[c0 + 4][nn] = a1.x; Ast[c0 + 5][nn] = a1.y;
        Ast[c0 + 6][nn] = a1.z; Ast[c0 + 7][nn] = a1.w;
        Bst[c0 + 0][nn] = b0.x; Bst[c0 + 1][nn] = b0.y;
        Bst[c0 + 2][nn] = b0.z; Bst[c0 + 3][nn] = b0.w;
        Bst[c0 + 4][nn] = b1.x; Bst[c0 + 5][nn] = b1.y;
        Bst[c0 + 6][nn] = b1.z; Bst[c0 + 7][nn] = b1.w;
        __syncthreads();
        bf16x8 af = *(const bf16x8*)&Ast[wave * 16 + nl][quad * 8];
#pragma unroll
        for (int ct = 0; ct < 4; ++ct) {
            bf16x8 bfg = *(const bf16x8*)&Bst[ct * 16 + nl][quad * 8];
            acc[ct] = __builtin_amdgcn_mfma_f32_16x16x32_bf16(af, bfg, acc[ct], 0, 0, 0);
        }
    }
#pragma unroll
    for (int ct = 0; ct < 4; ++ct)
#pragma unroll
        for (int r = 0; r < 4; ++r)
            atomicAdd(&D[(size_t)(i0 + wave * 16 + quad * 4 + r) * DH + j0 + ct * 16 + nl], acc[ct][r]);
}

// ---------------- kvs f32 -> bf16 convert (once; attn re-reads it 1563x) ----------------
__global__ __launch_bounds__(256) void kvs2b_kernel(const float* __restrict__ kvs,
                                                    unsigned short* __restrict__ kvsb)
{
    int i = blockIdx.x * 256 + threadIdx.x;      // 8192 threads x 8 elems = 65536
    size_t o = (size_t)i * 8;
    float4 a = *(const float4*)(kvs + o);
    float4 b = *(const float4*)(kvs + o + 4);
    *(ushort4*)(kvsb + o)     = make_ushort4(f2b(a.x), f2b(a.y), f2b(a.z), f2b(a.w));
    *(ushort4*)(kvsb + o + 4) = make_ushort4(f2b(b.x), f2b(b.y), f2b(b.z), f2b(b.w));
}

// ---------------- MFMA attention: out = (Q@kvs*scale + N*V) / (Q.ks_sum*scale + N) ----------------
// kvsb: kvs transposed, bf16, row-major [256][256] (L2-resident, 128KB).
// Col-split: gridDim.y=2, each block does 64 rows x 128 cols -> acc[8] (32 VGPRs);
// in-loop fragment loads (measured best variant: 121.7us, occ 39%).
template <typename ST>
__global__ __launch_bounds__(256) void attn_mfma(
    const ST* __restrict__ Q, const ST* __restrict__ V,
    const unsigned short* __restrict__ kvsb, const float* __restrict__ ks_sum,
    const float* __restrict__ qss, const float* __restrict__ kss,
    ST* __restrict__ out)
{
    __shared__ float ks_s[DH];
    __shared__ float nrm_s[64];
    const int tid = threadIdx.x;
    const int wave = tid >> 6, lane = tid & 63;
    const int quad = lane >> 4, nl = lane & 15;
    const int m0 = blockIdx.x * 64;
    const int j0 = blockIdx.y * 128;

    ks_s[tid] = ks_sum[tid];
    __syncthreads();

    const int arow = m0 + wave * 16 + nl;
    const int av = (arow < NN);
    const size_t abase = (size_t)arow * DH + quad * 8;
    f32x4 acc[8];
#pragma unroll
    for (int i = 0; i < 8; ++i) acc[i] = (f32x4){0.f, 0.f, 0.f, 0.f};
    float nrm = 0.f;

#pragma unroll 2
    for (int k0 = 0; k0 < DH; k0 += 32) {
        ushort4 a0, a1;
        if (av) ld8S(Q, abase + k0, a0, a1);
        else { a0 = make_ushort4(0,0,0,0); a1 = a0; }
        bf16x8 af;
        ((ushort4*)&af)[0] = a0; ((ushort4*)&af)[1] = a1;
#pragma unroll
        for (int j = 0; j < 8; ++j)
            nrm += bits2f(((const unsigned short*)&af)[j]) * ks_s[k0 + quad * 8 + j];
        const unsigned short* kb = kvsb + (size_t)(j0 + nl) * DH + k0 + quad * 8;
#pragma unroll
        for (int ct = 0; ct < 8; ++ct) {
            bf16x8 bfg = *(const bf16x8*)(kb + (size_t)ct * 16 * DH);
            acc[ct] = __builtin_amdgcn_mfma_f32_16x16x32_bf16(af, bfg, acc[ct], 0, 0, 0);
        }
    }
    nrm += __shfl_xor(nrm, 16);
    nrm += __shfl_xor(nrm, 32);
    if (lane < 16) nrm_s[wave * 16 + lane] = nrm;
    __syncthreads();
    const float scale = rsqrtf(*qss) * rsqrtf(*kss);
#pragma unroll
    for (int r = 0; r < 4; ++r) {
        int row = m0 + wave * 16 + quad * 4 + r;
        if (row >= NN) continue;
        float den = nrm_s[wave * 16 + quad * 4 + r] * scale + (float)NN;
#pragma unroll
        for (int ct = 0; ct < 8; ++ct) {
            int col = j0 + ct * 16 + nl;
            float v = ldS(V, (size_t)row * DH + col);
            float numv = acc[ct][r] * scale + (float)NN * v;
            stS(out, (size_t)row * DH + col, numv / den);
        }
    }
}

// ---------------- LayerNorm over D=256: one wave per row, 4 rows/block ----------------
template <typename ST>
__global__ __launch_bounds__(256) void ln_kernel(
    const ST* __restrict__ A, const ST* __restrict__ B,
    float alpha, float beta,
    const void* __restrict__ g, const void* __restrict__ b,
    ST* __restrict__ out, int relu, const int* __restrict__ flags)
{
    const int isbf = flags[0];
    const int wave = threadIdx.x >> 6, lane = threadIdx.x & 63;
    const int row = blockIdx.x * 4 + wave;
    if (row >= NN) return;
    const size_t base = (size_t)row * DH + lane * 4;
    float4 v = ld4S(&A[base]);
    v.x *= alpha; v.y *= alpha; v.z *= alpha; v.w *= alpha;
    if (B) {
        float4 w = ld4S(&B[base]);
        v.x += beta * w.x; v.y += beta * w.y; v.z += beta * w.z; v.w += beta * w.w;
    }
    float s = v.x + v.y + v.z + v.w;
    float s2 = v.x * v.x + v.y * v.y + v.z * v.z + v.w * v.w;
#pragma unroll
    for (int off = 32; off > 0; off >>= 1) {
        s += __shfl_xor(s, off);
        s2 += __shfl_xor(s2, off);
    }
    float mean = s * (1.f / DH);
    float var = s2 * (1.f / DH) - mean * mean;
    float rstd = rsqrtf(var + 1e-5f);
    float4 o;
    o.x = (v.x - mean) * rstd * ldf(g, lane * 4 + 0, isbf) + ldf(b, lane * 4 + 0, isbf);
    o.y = (v.y - mean) * rstd * ldf(g, lane * 4 + 1, isbf) + ldf(b, lane * 4 + 1, isbf);
    o.z = (v.z - mean) * rstd * ldf(g, lane * 4 + 2, isbf) + ldf(b, lane * 4 + 2, isbf);
    o.w = (v.w - mean) * rstd * ldf(g, lane * 4 + 3, isbf) + ldf(b, lane * 4 + 3, isbf);
    if (relu) {
        o.x = fmaxf(o.x, 0.f); o.y = fmaxf(o.y, 0.f);
        o.z = fmaxf(o.z, 0.f); o.w = fmaxf(o.w, 0.f);
    }
    st4S(&out[base], o);
}

// ---------------- CSR build ----------------
__global__ __launch_bounds__(256) void count_kernel(const int* __restrict__ ei, int* __restrict__ cnt,
                                                    const int* __restrict__ flags)
{
    int e = blockIdx.x * 256 + threadIdx.x;
    if (e >= NE) return;
    int d = ld_dst(ei, e, flags[1]);
    if ((unsigned)d < NN) atomicAdd(&cnt[d], 1);
}

__global__ __launch_bounds__(256) void scan_block_kernel(const int* __restrict__ cnt,
                                                         int* __restrict__ pre, int* __restrict__ bsum)
{
    __shared__ int s[256];
    int i = blockIdx.x * 256 + threadIdx.x;
    int v = (i < NN) ? cnt[i] : 0;
    s[threadIdx.x] = v;
    __syncthreads();
    for (int off = 1; off < 256; off <<= 1) {
        int t = (threadIdx.x >= off) ? s[threadIdx.x - off] : 0;
        __syncthreads();
        s[threadIdx.x] += t;
        __syncthreads();
    }
    if (i < NN) pre[i] = s[threadIdx.x] - v;
    if (threadIdx.x == 255) bsum[blockIdx.x] = s[255];
}

__global__ __launch_bounds__(512) void scan_partial_kernel(int* __restrict__ bsum, int nb)
{
    __shared__ int s[512];
    int t = threadIdx.x;
    int v = (t < nb) ? bsum[t] : 0;
    s[t] = v;
    __syncthreads();
    for (int off = 1; off < 512; off <<= 1) {
        int u = (t >= off) ? s[t - off] : 0;
        __syncthreads();
        s[t] += u;
        __syncthreads();
    }
    if (t < nb) bsum[t] = s[t] - v;
}

__global__ __launch_bounds__(256) void finalize_kernel(int* __restrict__ base, const int* __restrict__ bsum,
                                                       const int* __restrict__ cnt, int* __restrict__ cursor,
                                                       float* __restrict__ dinv)
{
    int i = blockIdx.x * 256 + threadIdx.x;
    if (i >= NN) return;
    int b = base[i] + bsum[blockIdx.x];
    base[i] = b;
    cursor[i] = b;
    dinv[i] = rsqrtf((float)cnt[i] + 1.0f);
}

__global__ __launch_bounds__(256) void scatter_kernel(const int* __restrict__ ei, int* __restrict__ cursor,
                                                      int* __restrict__ srcs, const int* __restrict__ flags)
{
    int e = blockIdx.x * 256 + threadIdx.x;
    if (e >= NE) return;
    int i64 = flags[1];
    int s = ld_src(ei, e, i64), d = ld_dst(ei, e, i64);
    if ((unsigned)s >= NN || (unsigned)d >= NN) return;
    int pos = atomicAdd(&cursor[d], 1);
    srcs[pos] = s;
}

// ---------------- FUSED CSR gather + GCN epilogue: one wave per node ----------------
// MODE 0: out = relu((agg + own*di^2 + b) * bn_g/sqrt(1+eps) + bn_b)
// MODE 1: out = 0.8*(agg + own*di^2 + b) + 0.2*Ht
// 4-way unrolled: 4 independent {src,dinv,row} chains in flight per wave for MLP.
template <typename ST, int MODE>
__global__ __launch_bounds__(256) void fgather_kernel(
    const ST* __restrict__ Hs, const ST* __restrict__ Ht,
    const int* __restrict__ base, const int* __restrict__ cnt,
    const int* __restrict__ srcs, const float* __restrict__ dinv,
    const void* __restrict__ bias, const void* __restrict__ bng, const void* __restrict__ bnb,
    const int* __restrict__ flags, ST* __restrict__ out)
{
    const int isbf = flags[0];
    int node = blockIdx.x * 4 + (threadIdx.x >> 6);
    int lane = threadIdx.x & 63;
    if (node >= NN) return;
    int b0 = base[node], deg = cnt[node];
    float dd = dinv[node];
    float4 a0 = make_float4(0.f, 0.f, 0.f, 0.f);
    float4 a1 = make_float4(0.f, 0.f, 0.f, 0.f);
    int j = 0;
    for (; j + 4 <= deg; j += 4) {      // 4 independent row-chains in flight
        int s0 = srcs[b0 + j + 0], s1 = srcs[b0 + j + 1];
        int s2 = srcs[b0 + j + 2], s3 = srcs[b0 + j + 3];
        float n0 = dd * dinv[s0], n1 = dd * dinv[s1];
        float n2 = dd * dinv[s2], n3 = dd * dinv[s3];
        float4 h0 = ld4S(&Hs[(size_t)s0 * DH + lane * 4]);
        float4 h1 = ld4S(&Hs[(size_t)s1 * DH + lane * 4]);
        float4 h2 = ld4S(&Hs[(size_t)s2 * DH + lane * 4]);
        float4 h3 = ld4S(&Hs[(size_t)s3 * DH + lane * 4]);
        a0.x += h0.x * n0; a0.y += h0.y * n0; a0.z += h0.z * n0; a0.w += h0.w * n0;
        a1.x += h1.x * n1; a1.y += h1.y * n1; a1.z += h1.z * n1; a1.w += h1.w * n1;
        a0.x += h2.x * n2; a0.y += h2.y * n2; a0.z += h2.z * n2; a0.w += h2.w * n2;
        a1.x += h3.x * n3; a1.y += h3.y * n3; a1.z += h3.z * n3; a1.w += h3.w * n3;
    }
    for (; j < deg; ++j) {
        int s0 = srcs[b0 + j];
        float n0 = dd * dinv[s0];
        float4 h0 = ld4S(&Hs[(size_t)s0 * DH + lane * 4]);
        a0.x += h0.x * n0; a0.y += h0.y * n0; a0.z += h0.z * n0; a0.w += h0.w * n0;
    }
    const size_t obase = (size_t)node * DH + lane * 4;
    float4 own = ld4S(&Hs[obase]);
    float di2 = dd * dd;
    int c = lane * 4;
    float4 v;
    v.x = a0.x + a1.x + own.x * di2 + ldf(bias, c + 0, isbf);
    v.y = a0.y + a1.y + own.y * di2 + ldf(bias, c + 1, isbf);
    v.z = a0.z + a1.z + own.z * di2 + ldf(bias, c + 2, isbf);
    v.w = a0.w + a1.w + own.w * di2 + ldf(bias, c + 3, isbf);
    if (MODE == 0) {
        const float bnscale = 0.99999500003749981f;  // 1/sqrt(1+1e-5)
        v.x = fmaxf(v.x * (ldf(bng, c + 0, isbf) * bnscale) + ldf(bnb, c + 0, isbf), 0.f);
        v.y = fmaxf(v.y * (ldf(bng, c + 1, isbf) * bnscale) + ldf(bnb, c + 1, isbf), 0.f);
        v.z = fmaxf(v.z * (ldf(bng, c + 2, isbf) * bnscale) + ldf(bnb, c + 2, isbf), 0.f);
        v.w = fmaxf(v.w * (ldf(bng, c + 3, isbf) * bnscale) + ldf(bnb, c + 3, isbf), 0.f);
    } else {
        float4 t = ld4S(&Ht[obase]);
        v.x = 0.8f * v.x + 0.2f * t.x;
        v.y = 0.8f * v.y + 0.2f * t.y;
        v.z = 0.8f * v.z + 0.2f * t.z;
        v.w = 0.8f * v.w + 0.2f * t.w;
    }
    st4S(&out[obase], v);
}

// ---------------- fallback (atomic) GCN pieces ----------------
__global__ __launch_bounds__(256) void deg_kernel(const int* __restrict__ ei, float* __restrict__ deg,
                                                  const int* __restrict__ flags)
{
    int i64 = flags[1];
    int e = blockIdx.x * 256 + threadIdx.x;
    if (e >= NE) return;
    int d = ld_dst(ei, e, i64);
    if ((unsigned)d < NN) atomicAdd(&deg[d], 1.0f);
}

__global__ __launch_bounds__(256) void dinv_kernel(float* __restrict__ deg)
{
    int i = blockIdx.x * 256 + threadIdx.x;
    if (i < NN) deg[i] = rsqrtf(deg[i] + 1.0f);
}

template <typename ST>
__global__ __launch_bounds__(256) void agg_kernel(
    const ST* __restrict__ Hs, const int* __restrict__ ei,
    const float* __restrict__ dinv, float* __restrict__ lo, float* __restrict__ hi,
    const int* __restrict__ flags)
{
    int i64 = flags[1];
    int e = blockIdx.x * 4 + (threadIdx.x >> 6);
    int lane = threadIdx.x & 63;
    if (e >= NE) return;
    int s = ld_src(ei, e, i64), d = ld_dst(ei, e, i64);
    if ((unsigned)s >= NN || (unsigned)d >= NN) return;
    float nrm = dinv[s] * dinv[d];
    const float4 h4 = ld4S(&Hs[(size_t)s * DH + lane * 4]);
    float* o = (d < NSPL ? &lo[(size_t)d * DH] : &hi[(size_t)(d - NSPL) * DH]) + lane * 4;
    atomicAdd(o + 0, h4.x * nrm);
    atomicAdd(o + 1, h4.y * nrm);
    atomicAdd(o + 2, h4.z * nrm);
    atomicAdd(o + 3, h4.w * nrm);
}

// self-loop + bias + BN(eval) + relu
template <typename ST>
__global__ __launch_bounds__(256) void gcn_epi1_kernel(
    const float* __restrict__ lo, const float* __restrict__ hi,
    const ST* __restrict__ h1, const float* __restrict__ dinv,
    const void* __restrict__ b0, const void* __restrict__ bng, const void* __restrict__ bnb,
    const int* __restrict__ flags, ST* __restrict__ out)
{
    const int isbf = flags[0];
    size_t idx = (size_t)blockIdx.x * 256 + threadIdx.x;
    if (idx >= (size_t)NN * DH) return;
    int i = (int)(idx >> 8), c = (int)(idx & 255);
    float aggv = (i < NSPL) ? lo[idx] : hi[idx - NSO];
    float di = dinv[i];
    float v = aggv + ldS(h1, idx) * di * di + ldf(b0, c, isbf);
    const float bnscale = 0.99999500003749981f;  // 1/sqrt(1+1e-5)
    v = v * (ldf(bng, c, isbf) * bnscale) + ldf(bnb, c, isbf);
    stS(out, idx, fmaxf(v, 0.f));
}

// self-loop + bias + combine: emb = 0.8*(agg + self + b1) + 0.2*x_trans
template <typename ST>
__global__ __launch_bounds__(256) void gcn_epi2_kernel(
    const float* __restrict__ lo, const float* __restrict__ hi,
    const ST* __restrict__ h2, const ST* __restrict__ Ht, const float* __restrict__ dinv,
    const void* __restrict__ b1, const int* __restrict__ flags, ST* __restrict__ out)
{
    const int isbf = flags[0];
    size_t idx = (size_t)blockIdx.x * 256 + threadIdx.x;
    if (idx >= (size_t)NN * DH) return;
    int i = (int)(idx >> 8), c = (int)(idx & 255);
    float aggv = (i < NSPL) ? lo[idx] : hi[idx - NSO];
    float di = dinv[i];
    float g = aggv + ldS(h2, idx) * di * di + ldf(b1, c, isbf);
    stS(out, idx, 0.8f * g + 0.2f * ldS(Ht, idx));
}

// ---------------- diagnostic ----------------
__global__ __launch_bounds__(256) void diag_kernel(float* out, size_t n, float val)
{
    size_t i = (size_t)blockIdx.x * 256 + threadIdx.x;
    if (i < n) out[i] = val;
}

// ---------------- pipeline ----------------
template <typename ST>
static void run_pipeline(void* const* d_in, void* d_out, char* wsb, hipStream_t stream, int use_csr)
{
    const void* x      = d_in[0];
    const int*  ei     = (const int*)d_in[1];
    const void* fc0_w  = d_in[2];  const void* fc0_b  = d_in[3];
    const void* ln0_g  = d_in[4];  const void* ln0_b  = d_in[5];
    const void* wq0_w  = d_in[6];  const void* wq0_b  = d_in[7];
    const void* wk0_w  = d_in[8];  const void* wk0_b  = d_in[9];
    const void* wv0_w  = d_in[10]; const void* wv0_b  = d_in[11];
    const void* ln1_g  = d_in[12]; const void* ln1_b  = d_in[13];
    const void* wq1_w  = d_in[14]; const void* wq1_b  = d_in[15];
    const void* wk1_w  = d_in[16]; const void* wk1_b  = d_in[17];
    const void* wv1_w  = d_in[18]; const void* wv1_b  = d_in[19];
    const void* ln2_g  = d_in[20]; const void* ln2_b  = d_in[21];
    const void* gcn_w0 = d_in[22]; const void* gcn_b0 = d_in[23];
    const void* bn_g   = d_in[24]; const void* bn_b   = d_in[25];
    const void* gcn_w1 = d_in[26]; const void* gcn_b1 = d_in[27];
    const void* fc_w   = d_in[28]; const void* fc_b   = d_in[29];

    const size_t stN = (size_t)NN * DH * sizeof(ST);
    ST* H  = (ST*)(wsb);
    ST* Qb = (ST*)(wsb + stN);
    ST* Kb = (ST*)(wsb + 2 * stN);
    ST* Vb = (ST*)(wsb + 3 * stN);
    float* aux = (float*)(wsb + 4 * stN);
    float* kvs    = aux;
    float* ks_sum = aux + 65536;
    float* qss    = aux + 65792;
    float* kss    = aux + 65793;
    float* dinv   = aux + 65808;
    int*   flags  = (int*)(aux + 65808 + NN);
    int* cnt    = (int*)(aux + 65808 + NN + 16);
    int* base   = cnt + NN;
    int* cursor = base + NN;
    int* bsum   = cursor + NN;       // 512
    int* srcs   = bsum + 512;        // NE
    // dinv region (NN floats = 400KB) is dead until the GCN branch; borrow 128KB
    // of it for the bf16 copy of kvsT during the attention layers.
    unsigned short* kvsb = (unsigned short*)dinv;

    const int asel = (sizeof(ST) == 2) ? 1 : 0;
    dim3 gemmGrid((NN + 511) / 512, DH / 64);      // 196 x 4
    const size_t NELEM = (size_t)NN * DH;

    detect_kernel<<<1, 256, 0, stream>>>(x, ei, flags);

    // ---- TransConv input layer ----
    gemm_mfma<ST><<<gemmGrid, 512, 0, stream>>>(x, fc0_w, fc0_b, Qb, NN, DH, flags, 2, nullptr, nullptr);
    ln_kernel<ST><<<(NN + 3) / 4, 256, 0, stream>>>(Qb, (const ST*)nullptr, 1.f, 0.f, ln0_g, ln0_b, H, 1, flags);

    // ---- two attention layers ----
    for (int layer = 0; layer < 2; ++layer) {
        const void *qw, *qb, *kw, *kb, *vw, *vb, *lg, *lb;
        if (layer == 0) { qw = wq0_w; qb = wq0_b; kw = wk0_w; kb = wk0_b; vw = wv0_w; vb = wv0_b; lg = ln1_g; lb = ln1_b; }
        else            { qw = wq1_w; qb = wq1_b; kw = wk1_w; kb = wk1_b; vw = wv1_w; vb = wv1_b; lg = ln2_g; lb = ln2_b; }
        // zero kvs / ks_sum / qss / kss BEFORE the fused-reduction gemms
        hipMemsetAsync(aux, 0, (65536 + 256 + 2) * sizeof(float), stream);
        gemm_mfma<ST><<<gemmGrid, 512, 0, stream>>>(H, qw, qb, Qb, NN, DH, flags, asel, qss, nullptr);
        gemm_mfma<ST><<<gemmGrid, 512, 0, stream>>>(H, kw, kb, Kb, NN, DH, flags, asel, kss, ks_sum);
        gemm_mfma<ST><<<gemmGrid, 512, 0, stream>>>(H, vw, vb, Vb, NN, DH, flags, asel, nullptr, nullptr);
        // kvs stored TRANSPOSED: kvs[j][i] = sum_n V[n][j] K[n][i]
        kvs_mfma<ST><<<dim3(4, 4, 128), 256, 0, stream>>>(Vb, Kb, kvs);
        kvs2b_kernel<<<32, 256, 0, stream>>>(kvs, kvsb);
        attn_mfma<ST><<<dim3((NN + 63) / 64, 2), 256, 0, stream>>>(Qb, Vb, kvsb, ks_sum, qss, kss, Kb);
        ln_kernel<ST><<<(NN + 3) / 4, 256, 0, stream>>>(Kb, H, 0.5f, 0.5f, lg, lb, H, 0, flags);
    }

    // ---- GCN branch ----
    if (use_csr) {
        hipMemsetAsync(cnt, 0, NN * sizeof(int), stream);
        count_kernel<<<(NE + 255) / 256, 256, 0, stream>>>(ei, cnt, flags);
        scan_block_kernel<<<NBLK, 256, 0, stream>>>(cnt, base, bsum);
        scan_partial_kernel<<<1, 512, 0, stream>>>(bsum, NBLK);
        finalize_kernel<<<NBLK, 256, 0, stream>>>(base, bsum, cnt, cursor, dinv);
        scatter_kernel<<<(NE + 255) / 256, 256, 0, stream>>>(ei, cursor, srcs, flags);

        // fused path: h1 -> Qb; fused gather+BN+relu -> Kb; h2 -> Vb;
        // fused gather+combine -> Qb (emb); classifier reads Qb.
        gemm_mfma<ST><<<gemmGrid, 512, 0, stream>>>(x, gcn_w0, nullptr, Qb, NN, DH, flags, 2, nullptr, nullptr);
        fgather_kernel<ST, 0><<<(NN + 3) / 4, 256, 0, stream>>>(
            Qb, (const ST*)nullptr, base, cnt, srcs, dinv, gcn_b0, bn_g, bn_b, flags, Kb);
        gemm_mfma<ST><<<gemmGrid, 512, 0, stream>>>(Kb, gcn_w1, nullptr, Vb, NN, DH, flags, asel, nullptr, nullptr);
        fgather_kernel<ST, 1><<<(NN + 3) / 4, 256, 0, stream>>>(
            Vb, H, base, cnt, srcs, dinv, gcn_b1, nullptr, nullptr, flags, Qb);

        gemm_mfma<float><<<dim3((NN + 511) / 512, 1), 512, 0, stream>>>(Qb, fc_w, fc_b, (float*)d_out, NN, DOUT, flags, asel, nullptr, nullptr);
    } else {
        float* a1lo = (float*)(wsb + 2 * stN);
        float* a1hi = a1lo + NSO;
        ST* h2; float *a2lo, *a2hi;
        if (sizeof(ST) == 4) { h2 = Vb; a2lo = (float*)(wsb + 2 * stN); a2hi = a2lo + NSO; }
        else                 { h2 = Kb; a2lo = (float*)(wsb + stN);     a2hi = (float*)(wsb + 3 * stN); }

        hipMemsetAsync(dinv, 0, NN * sizeof(float), stream);
        deg_kernel<<<(NE + 255) / 256, 256, 0, stream>>>(ei, dinv, flags);
        dinv_kernel<<<(NN + 255) / 256, 256, 0, stream>>>(dinv);

        gemm_mfma<ST><<<gemmGrid, 512, 0, stream>>>(x, gcn_w0, nullptr, Qb, NN, DH, flags, 2, nullptr, nullptr);
        hipMemsetAsync(a1lo, 0, NELEM * sizeof(float), stream);
        agg_kernel<ST><<<(NE + 3) / 4, 256, 0, stream>>>(Qb, ei, dinv, a1lo, a1hi, flags);
        gcn_epi1_kernel<ST><<<(NELEM + 255) / 256, 256, 0, stream>>>(a1lo, a1hi, Qb, dinv, gcn_b0, bn_g, bn_b, flags, Qb);

        gemm_mfma<ST><<<gemmGrid, 512, 0, stream>>>(Qb, gcn_w1, nullptr, h2, NN, DH, flags, asel, nullptr, nullptr);
        hipMemsetAsync(a2lo, 0, NSO * sizeof(float), stream);
        hipMemsetAsync(a2hi, 0, NSO * sizeof(float), stream);
        agg_kernel<ST><<<(NE + 3) / 4, 256, 0, stream>>>(h2, ei, dinv, a2lo, a2hi, flags);
        gcn_epi2_kernel<ST><<<(NELEM + 255) / 256, 256, 0, stream>>>(a2lo, a2hi, h2, H, dinv, gcn_b1, flags, h2);

        gemm_mfma<float><<<dim3((NN + 511) / 512, 1), 512, 0, stream>>>(h2, fc_w, fc_b, (float*)d_out, NN, DOUT, flags, asel, nullptr, nullptr);
    }
}

extern "C" void kernel_launch(void* const* d_in, const int* in_sizes, int n_in,
                              void* d_out, int out_size, void* d_ws, size_t ws_size,
                              hipStream_t stream)
{
    char* wsb = (char*)d_ws;
    const size_t AUXF  = 65808 + NN + 16;
    const size_t CSRI  = 3 * (size_t)NN + 512 + NE;
    const size_t AUXB  = AUXF * sizeof(float);
    const size_t AUXB2 = AUXB + CSRI * sizeof(int);
    const size_t needA  = 4 * ((size_t)NN * DH * 4) + AUXB;
    const size_t needA2 = 4 * ((size_t)NN * DH * 4) + AUXB2;
    const size_t needB  = 4 * ((size_t)NN * DH * 2) + AUXB;
    const size_t needB2 = 4 * ((size_t)NN * DH * 2) + AUXB2;

    if (ws_size >= needA) {
        run_pipeline<float>(d_in, d_out, wsb, stream, ws_size >= needA2);
    } else if (ws_size >= needB) {
        run_pipeline<bf16>(d_in, d_out, wsb, stream, ws_size >= needB2);
    } else {
        float mb = (float)(ws_size >> 20);
        size_t n = (size_t)out_size;
        diag_kernel<<<(n + 255) / 256, 256, 0, stream>>>((float*)d_out, n, mb);
    }
}